// Round 8
// baseline (1680.649 us; speedup 1.0000x reference)
//
#include <hip/hip_runtime.h>

#define B_ 4
#define N_ 40000
#define E_ 240000
#define NB_SCAN ((N_ + 255) / 256)   // 157 scan blocks

typedef unsigned short u16;
typedef unsigned int u32;
typedef __attribute__((ext_vector_type(8))) short bf16x8;
typedef __attribute__((ext_vector_type(4))) float f32x4;

__device__ __forceinline__ float b2f(u16 h) {
    u32 u = ((u32)h) << 16;
    return __uint_as_float(u);
}
__device__ __forceinline__ u16 f2b(float f) {
    u32 u = __float_as_uint(f);
    u32 r = (u + 0x7fffu + ((u >> 16) & 1u)) >> 16;
    return (u16)r;
}
// load 8 consecutive f32 from global, round to bf16x8 in registers
__device__ __forceinline__ bf16x8 ld8f(const float* p) {
    float4 v0 = *(const float4*)p;
    float4 v1 = *(const float4*)(p + 4);
    union { bf16x8 v; u16 s[8]; } u;
    u.s[0] = f2b(v0.x); u.s[1] = f2b(v0.y); u.s[2] = f2b(v0.z); u.s[3] = f2b(v0.w);
    u.s[4] = f2b(v1.x); u.s[5] = f2b(v1.y); u.s[6] = f2b(v1.z); u.s[7] = f2b(v1.w);
    return u.v;
}

// ---------------- first linear: x = x_in @ w_first + b_first (bf16 out, 8 c/thread) ----------------
__global__ __launch_bounds__(256) void first_linear_kern(
    const float* __restrict__ x_in, const float* __restrict__ w,
    const float* __restrict__ bias, u16* __restrict__ xout, int M)
{
    __shared__ float sw[6 * 128];
    __shared__ float sb[128];
    int t = threadIdx.x;
    for (int i = t; i < 768; i += 256) sw[i] = w[i];
    if (t < 128) sb[t] = bias[t];
    __syncthreads();
    int idx = blockIdx.x * 256 + t;   // = row*16 + cg
    int row = idx >> 4;
    int cg = (idx & 15) * 8;
    if (row >= M) return;
    const float* xr = x_in + (size_t)row * 6;
    float xv[6];
#pragma unroll
    for (int j = 0; j < 6; j++) xv[j] = xr[j];
    float acc[8];
#pragma unroll
    for (int i = 0; i < 8; i++) acc[i] = sb[cg + i];
#pragma unroll
    for (int j = 0; j < 6; j++)
#pragma unroll
        for (int i = 0; i < 8; i++) acc[i] += xv[j] * sw[j * 128 + cg + i];
    ushort4 h0, h1;
    h0.x = f2b(acc[0]); h0.y = f2b(acc[1]); h0.z = f2b(acc[2]); h0.w = f2b(acc[3]);
    h1.x = f2b(acc[4]); h1.y = f2b(acc[5]); h1.z = f2b(acc[6]); h1.w = f2b(acc[7]);
    uint4 pk;
    pk.x = (u32)h0.x | ((u32)h0.y << 16);
    pk.y = (u32)h0.z | ((u32)h0.w << 16);
    pk.z = (u32)h1.x | ((u32)h1.y << 16);
    pk.w = (u32)h1.z | ((u32)h1.w << 16);
    *(uint4*)(xout + (size_t)row * 128 + cg) = pk;
}

// ------------- weight pack: dst[n][k] = bf16(src[k][n]), per block i = blockIdx.z -------------
__global__ __launch_bounds__(256) void pack_w_kern(
    const float* __restrict__ src, u16* __restrict__ dst, int K)
{
    int i = blockIdx.z;
    src += (size_t)i * K * 128;
    dst += (size_t)i * K * 128;
    int idx = blockIdx.x * 256 + threadIdx.x;  // = n*K + k
    int n = idx / K;
    int k = idx % K;
    dst[idx] = f2b(src[(size_t)k * 128 + n]);
}

// ------------- rotation weight pack: WR1[n][k256] = [Are; -Aim]^T, WR2 = [Are; Aim]^T -------------
__global__ __launch_bounds__(256) void pack_rot_kern(
    const float* __restrict__ Are, const float* __restrict__ Aim,
    u16* __restrict__ WR1, u16* __restrict__ WR2)
{
    int i = blockIdx.z;
    const float* are = Are + (size_t)i * 16384;
    const float* aim = Aim + (size_t)i * 16384;
    int idx = blockIdx.x * 256 + threadIdx.x;  // 0..32767 = n*256 + k
    int n = idx >> 8;
    int k = idx & 255;
    float v1, v2;
    if (k < 128) { float a = are[(size_t)k * 128 + n]; v1 = a; v2 = a; }
    else         { float a = aim[(size_t)(k - 128) * 128 + n]; v1 = -a; v2 = a; }
    WR1[(size_t)i * 32768 + idx] = f2b(v1);
    WR2[(size_t)i * 32768 + idx] = f2b(v2);
}

// ------------- CSR build: histogram -> 3-phase parallel scan -> scatter idx -> gather vals -------------
__global__ __launch_bounds__(256) void hist_kern(const int* __restrict__ rows, int* count)
{
    int e = blockIdx.x * 256 + threadIdx.x;
    if (e < E_) atomicAdd(&count[rows[e]], 1);
}

// inclusive scan across a 256-thread block (4 waves, shfl-based)
__device__ __forceinline__ int block_incl_scan_256(int v, int t)
{
    __shared__ int wsum[4];
    int lane = t & 63;
    int wid = t >> 6;
    int x = v;
#pragma unroll
    for (int off = 1; off < 64; off <<= 1) {
        int y = __shfl_up(x, off);
        if (lane >= off) x += y;
    }
    if (lane == 63) wsum[wid] = x;
    __syncthreads();
    if (t == 0) {
        int s = 0;
#pragma unroll
        for (int i = 0; i < 4; i++) { int tm = wsum[i]; wsum[i] = s; s += tm; }
    }
    __syncthreads();
    return x + wsum[wid];
}

// phase 1: per-block exclusive scan of counts -> rowptr (partial), block totals
__global__ __launch_bounds__(256) void scan1_kern(
    const int* __restrict__ count, int* __restrict__ excl_out,
    int* __restrict__ blockTotals)
{
    int t = threadIdx.x;
    int g = blockIdx.x * 256 + t;
    int v = (g < N_) ? count[g] : 0;
    int incl = block_incl_scan_256(v, t);
    if (g < N_) excl_out[g] = incl - v;
    if (t == 255) blockTotals[blockIdx.x] = incl;
}

// phase 2: single-block scan of 157 block totals -> exclusive block offsets + grand total
__global__ __launch_bounds__(256) void scan2_kern(
    const int* __restrict__ blockTotals, int* __restrict__ blockOffs,
    int* __restrict__ totalOut)
{
    int t = threadIdx.x;
    int v = (t < NB_SCAN) ? blockTotals[t] : 0;
    int incl = block_incl_scan_256(v, t);
    if (t < NB_SCAN) blockOffs[t] = incl - v;
    if (t == 255) *totalOut = incl;   // = E_, written to rowptr[N_]
}

// phase 3: add block offsets; materialize rowptr + nextp cursors
__global__ __launch_bounds__(256) void scan3_kern(
    int* __restrict__ rowptr, int* __restrict__ nextp,
    const int* __restrict__ blockOffs)
{
    int t = threadIdx.x;
    int g = blockIdx.x * 256 + t;
    if (g >= N_) return;
    int v = rowptr[g] + blockOffs[blockIdx.x];
    rowptr[g] = v;
    nextp[g] = v;
}

// scatter only indices (2 scattered u32 writes per edge)
__global__ __launch_bounds__(256) void scatter_idx_kern(
    const int* __restrict__ rows, const int* __restrict__ cols,
    int* nextp, int* __restrict__ scols, int* __restrict__ sperm)
{
    int e = blockIdx.x * 256 + threadIdx.x;
    if (e >= E_) return;
    int r = rows[e];
    int pos = atomicAdd(&nextp[r], 1);
    scols[pos] = cols[e];
    sperm[pos] = e;
}

// gather values: coalesced writes, L2-cached random reads
__global__ __launch_bounds__(256) void gather_vals_kern(
    const int* __restrict__ sperm,
    const float* __restrict__ gvx, const float* __restrict__ gvy,
    float* __restrict__ svx, float* __restrict__ svy)
{
    int pos = blockIdx.x * 256 + threadIdx.x;
    if (pos >= E_) return;
    int e = sperm[pos];
#pragma unroll
    for (int b = 0; b < B_; b++) {
        svx[(size_t)b * E_ + pos] = gvx[(size_t)b * E_ + e];
        svy[(size_t)b * E_ + pos] = gvy[(size_t)b * E_ + e];
    }
}

// ------------- CSR dual spMM (all batches via z), bf16 packed out, edge-unrolled x2 -------------
__global__ __launch_bounds__(256) void spmm_csr_kern(
    const int* __restrict__ rowptr, const int* __restrict__ scols,
    const float* __restrict__ svx, const float* __restrict__ svy,
    const u16* __restrict__ xd, u16* __restrict__ gXY0, u16* __restrict__ gXY1)
{
    const size_t NZ = (size_t)N_ * 128;
    int z = blockIdx.z;
    const float* svx_b = svx + (size_t)z * E_;
    const float* svy_b = svy + (size_t)z * E_;
    const u16* xd_b = xd + (size_t)z * NZ;
    u16* base = (z < 2) ? (gXY0 + (size_t)z * 2 * NZ) : (gXY1 + (size_t)(z - 2) * 2 * NZ);
    u16* gXh = base;
    u16* gYh = base + NZ;

    int t = threadIdx.x;
    int r = blockIdx.x * 4 + (t >> 6);
    int c2 = (t & 63) * 2;
    int beg = rowptr[r], end = rowptr[r + 1];
    float ax0 = 0.f, ax1 = 0.f, ay0 = 0.f, ay1 = 0.f;
    int j = beg;
    for (; j + 1 < end; j += 2) {
        int ca = scols[j], cb = scols[j + 1];
        u32 xwa = *(const u32*)(xd_b + (size_t)ca * 128 + c2);
        u32 xwb = *(const u32*)(xd_b + (size_t)cb * 128 + c2);
        float vxa = svx_b[j], vya = svy_b[j];
        float vxb = svx_b[j + 1], vyb = svy_b[j + 1];
        float xa0 = b2f((u16)(xwa & 0xffffu)), xa1 = b2f((u16)(xwa >> 16));
        float xb0 = b2f((u16)(xwb & 0xffffu)), xb1 = b2f((u16)(xwb >> 16));
        ax0 += vxa * xa0; ax1 += vxa * xa1;
        ay0 += vya * xa0; ay1 += vya * xa1;
        ax0 += vxb * xb0; ax1 += vxb * xb1;
        ay0 += vyb * xb0; ay1 += vyb * xb1;
    }
    if (j < end) {
        int col = scols[j];
        u32 xw = *(const u32*)(xd_b + (size_t)col * 128 + c2);
        float x0 = b2f((u16)(xw & 0xffffu));
        float x1 = b2f((u16)(xw >> 16));
        float vx = svx_b[j], vy = svy_b[j];
        ax0 += vx * x0; ax1 += vx * x1;
        ay0 += vy * x0; ay1 += vy * x1;
    }
    u32 px = (u32)f2b(ax0) | ((u32)f2b(ax1) << 16);
    u32 py = (u32)f2b(ay0) | ((u32)f2b(ay1) << 16);
    *(u32*)(gXh + (size_t)r * 128 + c2) = px;
    *(u32*)(gYh + (size_t)r * 128 + c2) = py;
}

// ------------- spectral projection stage 1: MFMA over transposed LDS tiles -------------
__global__ __launch_bounds__(256) void spec_stage1_mfma_kern(
    const u16* __restrict__ x, const float* __restrict__ mass,
    const float* __restrict__ evecs, float* __restrict__ partials)
{
    __shared__ __align__(16) u16 sEVh[128][40];
    __shared__ __align__(16) u16 sEVl[128][40];
    __shared__ __align__(16) u16 sXM[128][40];
    int b = blockIdx.y;
    int pb = blockIdx.x;
    const u16* xb = x + (size_t)b * N_ * 128;
    const float* mb = mass + (size_t)b * N_;
    const float* eb = evecs + (size_t)b * N_ * 128;
    float* dst = partials + ((size_t)b * 128 + pb) * 16384;

    int t = threadIdx.x;
    int wv = t >> 6;
    int lane = t & 63;
    int quad = lane >> 4;
    int r16 = lane & 15;
    int kb = wv * 32;
    int kc = (t & 63) * 2;
    int nh = wv;

    f32x4 acc[2][8];
#pragma unroll
    for (int i = 0; i < 2; i++)
#pragma unroll
        for (int j = 0; j < 8; j++) acc[i][j] = (f32x4){0.f, 0.f, 0.f, 0.f};

    for (int ch = pb; ch < N_ / 32; ch += 128) {
        int nbase = ch * 32 + nh * 8;
        float4 m0 = *(const float4*)(mb + nbase);
        float4 m1 = *(const float4*)(mb + nbase + 4);
        float mm[8] = {m0.x, m0.y, m0.z, m0.w, m1.x, m1.y, m1.z, m1.w};
        u32 eh0[4], eh1[4], el0[4], el1[4], xq0[4], xq1[4];
#pragma unroll
        for (int jp = 0; jp < 4; jp++) {
            eh0[jp] = 0; eh1[jp] = 0; el0[jp] = 0;
            el1[jp] = 0; xq0[jp] = 0; xq1[jp] = 0;
        }
#pragma unroll
        for (int j = 0; j < 8; j++) {
            float2 e = *(const float2*)(eb + (size_t)(nbase + j) * 128 + kc);
            u32 xw = *(const u32*)(xb + (size_t)(nbase + j) * 128 + kc);
            u16 h0 = f2b(e.x);
            u16 h1 = f2b(e.y);
            u16 l0 = f2b(e.x - b2f(h0));
            u16 l1 = f2b(e.y - b2f(h1));
            u16 q0 = f2b(b2f((u16)(xw & 0xffffu)) * mm[j]);
            u16 q1 = f2b(b2f((u16)(xw >> 16)) * mm[j]);
            int sh = (j & 1) * 16;
            int jp = j >> 1;
            eh0[jp] |= ((u32)h0) << sh; eh1[jp] |= ((u32)h1) << sh;
            el0[jp] |= ((u32)l0) << sh; el1[jp] |= ((u32)l1) << sh;
            xq0[jp] |= ((u32)q0) << sh; xq1[jp] |= ((u32)q1) << sh;
        }
        __syncthreads();
        *(uint4*)&sEVh[kc][nh * 8]     = make_uint4(eh0[0], eh0[1], eh0[2], eh0[3]);
        *(uint4*)&sEVh[kc + 1][nh * 8] = make_uint4(eh1[0], eh1[1], eh1[2], eh1[3]);
        *(uint4*)&sEVl[kc][nh * 8]     = make_uint4(el0[0], el0[1], el0[2], el0[3]);
        *(uint4*)&sEVl[kc + 1][nh * 8] = make_uint4(el1[0], el1[1], el1[2], el1[3]);
        *(uint4*)&sXM[kc][nh * 8]      = make_uint4(xq0[0], xq0[1], xq0[2], xq0[3]);
        *(uint4*)&sXM[kc + 1][nh * 8]  = make_uint4(xq1[0], xq1[1], xq1[2], xq1[3]);
        __syncthreads();

        bf16x8 ah0 = *(const bf16x8*)&sEVh[kb + r16][quad * 8];
        bf16x8 ah1 = *(const bf16x8*)&sEVh[kb + 16 + r16][quad * 8];
        bf16x8 al0 = *(const bf16x8*)&sEVl[kb + r16][quad * 8];
        bf16x8 al1 = *(const bf16x8*)&sEVl[kb + 16 + r16][quad * 8];
#pragma unroll
        for (int nt = 0; nt < 8; nt++) {
            bf16x8 bx = *(const bf16x8*)&sXM[nt * 16 + r16][quad * 8];
            acc[0][nt] = __builtin_amdgcn_mfma_f32_16x16x32_bf16(ah0, bx, acc[0][nt], 0, 0, 0);
            acc[1][nt] = __builtin_amdgcn_mfma_f32_16x16x32_bf16(ah1, bx, acc[1][nt], 0, 0, 0);
            acc[0][nt] = __builtin_amdgcn_mfma_f32_16x16x32_bf16(al0, bx, acc[0][nt], 0, 0, 0);
            acc[1][nt] = __builtin_amdgcn_mfma_f32_16x16x32_bf16(al1, bx, acc[1][nt], 0, 0, 0);
        }
    }

#pragma unroll
    for (int mt = 0; mt < 2; mt++)
#pragma unroll
        for (int nt = 0; nt < 8; nt++)
#pragma unroll
            for (int reg = 0; reg < 4; reg++) {
                int kk = kb + mt * 16 + quad * 4 + reg;
                int cc = nt * 16 + r16;
                dst[(size_t)kk * 128 + cc] = acc[mt][nt][reg];
            }
}

// ------------- stage 2 + coefficients, TRANSPOSED bf16 out: ys_t[b][c][k] -------------
__global__ __launch_bounds__(128) void spec_stage2_coef_kern(
    const float* __restrict__ partials, const float* __restrict__ evals,
    const float* __restrict__ dt, u16* __restrict__ ys_t)
{
    int b = blockIdx.x >> 7;
    int k = blockIdx.x & 127;
    int c = threadIdx.x;
    const float* p = partials + (size_t)b * 128 * 16384 + (size_t)k * 128 + c;
    float s = 0.f;
#pragma unroll 8
    for (int pb = 0; pb < 128; pb++) s += p[(size_t)pb * 16384];
    float co = expf(-evals[b * 128 + k] * dt[c]);
    ys_t[((size_t)b * 128 + c) * 128 + k] = f2b(s * co);
}

// ------------- diffuse GEMM: xd[m,:] = evecs[m,:K=128] @ ys_t — no LDS, no barriers -------------
// A fragments: evecs f32 -> bf16 in regs; B fragments: ys_t direct (128 KB, L2-resident)
__global__ __launch_bounds__(256) void diffuse_gemm_kern(
    const float* __restrict__ evecs, const u16* __restrict__ ys_t,
    u16* __restrict__ xd)
{
    const size_t NZ = (size_t)N_ * 128;
    int z = blockIdx.z;
    const float* eb = evecs + (size_t)z * NZ;
    const u16* yb = ys_t + (size_t)z * 16384;
    u16* ob = xd + (size_t)z * NZ;

    int t = threadIdx.x;
    int m0 = blockIdx.x * 64;
    int wv = t >> 6;
    int lane = t & 63;
    int quad = lane >> 4;
    int r16 = lane & 15;
    int mw = (wv & 1) * 32;
    int nw = (wv >> 1) * 64;

    f32x4 acc[2][4];
#pragma unroll
    for (int i = 0; i < 2; i++)
#pragma unroll
        for (int j = 0; j < 4; j++) acc[i][j] = (f32x4){0.f, 0.f, 0.f, 0.f};

#pragma unroll
    for (int kt = 0; kt < 2; kt++) {
#pragma unroll
        for (int ks = 0; ks < 2; ks++) {
            int ko = kt * 64 + ks * 32 + quad * 8;
            bf16x8 a0 = ld8f(eb + (size_t)(m0 + mw + r16) * 128 + ko);
            bf16x8 a1 = ld8f(eb + (size_t)(m0 + mw + 16 + r16) * 128 + ko);
            bf16x8 b0 = *(const bf16x8*)(yb + (size_t)(nw + r16) * 128 + ko);
            bf16x8 b1 = *(const bf16x8*)(yb + (size_t)(nw + 16 + r16) * 128 + ko);
            bf16x8 b2v = *(const bf16x8*)(yb + (size_t)(nw + 32 + r16) * 128 + ko);
            bf16x8 b3v = *(const bf16x8*)(yb + (size_t)(nw + 48 + r16) * 128 + ko);
            acc[0][0] = __builtin_amdgcn_mfma_f32_16x16x32_bf16(a0, b0, acc[0][0], 0, 0, 0);
            acc[0][1] = __builtin_amdgcn_mfma_f32_16x16x32_bf16(a0, b1, acc[0][1], 0, 0, 0);
            acc[0][2] = __builtin_amdgcn_mfma_f32_16x16x32_bf16(a0, b2v, acc[0][2], 0, 0, 0);
            acc[0][3] = __builtin_amdgcn_mfma_f32_16x16x32_bf16(a0, b3v, acc[0][3], 0, 0, 0);
            acc[1][0] = __builtin_amdgcn_mfma_f32_16x16x32_bf16(a1, b0, acc[1][0], 0, 0, 0);
            acc[1][1] = __builtin_amdgcn_mfma_f32_16x16x32_bf16(a1, b1, acc[1][1], 0, 0, 0);
            acc[1][2] = __builtin_amdgcn_mfma_f32_16x16x32_bf16(a1, b2v, acc[1][2], 0, 0, 0);
            acc[1][3] = __builtin_amdgcn_mfma_f32_16x16x32_bf16(a1, b3v, acc[1][3], 0, 0, 0);
        }
    }

#pragma unroll
    for (int nt = 0; nt < 4; nt++) {
        int col = nw + nt * 16 + r16;
#pragma unroll
        for (int mt = 0; mt < 2; mt++) {
#pragma unroll
            for (int reg = 0; reg < 4; reg++) {
                int row = m0 + mw + mt * 16 + quad * 4 + reg;
                ob[(size_t)row * 128 + col] = f2b(acc[mt][nt][reg]);
            }
        }
    }
}

// ------------- FUSED rotation + tanh + MiniMLP; weights direct-from-global (L2) -------------
// LDS: only sGX/sGY (rotation A + gf) and sH (h1/h2) = 51 KB -> 3 blocks/CU x 8 waves = 6 waves/SIMD.
// Only 6 barriers per block (vs 24): weight staging eliminated entirely.
__global__ __launch_bounds__(512) void mlp_rot_fused_kern(
    const u16* __restrict__ xg, const u16* __restrict__ xdg,
    const u16* __restrict__ gXY0, const u16* __restrict__ gXY1,
    const u16* __restrict__ WR1, const u16* __restrict__ WR2,
    const u16* __restrict__ W0, const u16* __restrict__ W1, const u16* __restrict__ W2,
    const float* __restrict__ b0, const float* __restrict__ b1, const float* __restrict__ b2,
    u16* __restrict__ outp)
{
    __shared__ u16 sGX[64][136];
    __shared__ u16 sGY[64][136];
    __shared__ u16 sH[64][136];

    const size_t NZ = (size_t)N_ * 128;
    int z = blockIdx.z;                  // = batch
    const u16* gX = (z < 2) ? (gXY0 + (size_t)z * 2 * NZ) : (gXY1 + (size_t)(z - 2) * 2 * NZ);
    const u16* gY = gX + NZ;
    int m0n = blockIdx.x * 64;
    size_t growBase = ((size_t)z * N_ + m0n) * 128;

    int t = threadIdx.x;
    int wv = t >> 6;                     // 0..7
    int lane = t & 63;
    int quad = lane >> 4;
    int r16 = lane & 15;
    int mw = (wv & 1) * 32;              // 0 or 32
    int nw = (wv >> 1) * 32;             // 0,32,64,96

    // ---- stage gX, gY tiles ----
#pragma unroll
    for (int p = 0; p < 2; p++) {
        int idx = p * 512 + t;
        int row = idx >> 4;
        int seg = idx & 15;
        *(uint4*)&sGX[row][seg * 8] = *(const uint4*)(gX + (size_t)(m0n + row) * 128 + seg * 8);
        *(uint4*)&sGY[row][seg * 8] = *(const uint4*)(gY + (size_t)(m0n + row) * 128 + seg * 8);
    }
    __syncthreads();                     // (1) staging visible

    // ---- rotation: A from LDS, WR1/WR2 fragments direct from global (L2-hot) ----
    f32x4 accRe[2][2], accIm[2][2];
#pragma unroll
    for (int i = 0; i < 2; i++)
#pragma unroll
        for (int j = 0; j < 2; j++) {
            accRe[i][j] = (f32x4){0.f, 0.f, 0.f, 0.f};
            accIm[i][j] = (f32x4){0.f, 0.f, 0.f, 0.f};
        }

#pragma unroll
    for (int c = 0; c < 4; c++) {
        const u16 (*sRe)[136] = (c < 2) ? sGX : sGY;
        const u16 (*sIm)[136] = (c < 2) ? sGY : sGX;
        int kob = (c & 1) * 64;
#pragma unroll
        for (int ks = 0; ks < 2; ks++) {
            int ko = kob + ks * 32 + quad * 8;
            int wk = c * 64 + ks * 32 + quad * 8;
            bf16x8 aRe0 = *(const bf16x8*)&sRe[mw + r16][ko];
            bf16x8 aRe1 = *(const bf16x8*)&sRe[mw + 16 + r16][ko];
            bf16x8 aIm0 = *(const bf16x8*)&sIm[mw + r16][ko];
            bf16x8 aIm1 = *(const bf16x8*)&sIm[mw + 16 + r16][ko];
#pragma unroll
            for (int j = 0; j < 2; j++) {
                int n = nw + 16 * j + r16;
                bf16x8 w1f = *(const bf16x8*)(WR1 + (size_t)n * 256 + wk);
                bf16x8 w2f = *(const bf16x8*)(WR2 + (size_t)n * 256 + wk);
                accRe[0][j] = __builtin_amdgcn_mfma_f32_16x16x32_bf16(aRe0, w1f, accRe[0][j], 0, 0, 0);
                accRe[1][j] = __builtin_amdgcn_mfma_f32_16x16x32_bf16(aRe1, w1f, accRe[1][j], 0, 0, 0);
                accIm[0][j] = __builtin_amdgcn_mfma_f32_16x16x32_bf16(aIm0, w2f, accIm[0][j], 0, 0, 0);
                accIm[1][j] = __builtin_amdgcn_mfma_f32_16x16x32_bf16(aIm1, w2f, accIm[1][j], 0, 0, 0);
            }
        }
    }

    __syncthreads();                     // (2) all rotation reads of sGX/sGY complete
    // ---- tanh in place: gf -> sGX ----
#pragma unroll
    for (int nt = 0; nt < 2; nt++) {
        int col = nw + nt * 16 + r16;
#pragma unroll
        for (int mt = 0; mt < 2; mt++)
#pragma unroll
            for (int reg = 0; reg < 4; reg++) {
                int lrow = mw + mt * 16 + quad * 4 + reg;
                float gx = b2f(sGX[lrow][col]);
                float gy = b2f(sGY[lrow][col]);
                float v = tanhf(gx * accRe[mt][nt][reg] + gy * accIm[mt][nt][reg]);
                sGX[lrow][col] = f2b(v);
            }
    }
    __syncthreads();                     // (3) gf visible

    // ---- MLP stage 0: K=384 over concat(x, xd, gf); A direct-global / LDS, W0 direct ----
    f32x4 acc[2][2];
#pragma unroll
    for (int i = 0; i < 2; i++)
#pragma unroll
        for (int j = 0; j < 2; j++) acc[i][j] = (f32x4){0.f, 0.f, 0.f, 0.f};
#pragma unroll
    for (int kt = 0; kt < 6; kt++) {
        int kbase = kt * 64;
        int kloc = kbase & 127;
#pragma unroll
        for (int ks = 0; ks < 2; ks++) {
            int ko = ks * 32 + quad * 8;
            bf16x8 a0, a1;
            if (kt < 4) {
                const u16* Ap = (kt < 2) ? xg : xdg;
                a0 = *(const bf16x8*)(Ap + growBase + (size_t)(mw + r16) * 128 + kloc + ko);
                a1 = *(const bf16x8*)(Ap + growBase + (size_t)(mw + 16 + r16) * 128 + kloc + ko);
            } else {
                a0 = *(const bf16x8*)&sGX[mw + r16][kloc + ko];
                a1 = *(const bf16x8*)&sGX[mw + 16 + r16][kloc + ko];
            }
#pragma unroll
            for (int j = 0; j < 2; j++) {
                int n = nw + 16 * j + r16;
                bf16x8 bj = *(const bf16x8*)(W0 + (size_t)n * 384 + kbase + ko);
                acc[0][j] = __builtin_amdgcn_mfma_f32_16x16x32_bf16(a0, bj, acc[0][j], 0, 0, 0);
                acc[1][j] = __builtin_amdgcn_mfma_f32_16x16x32_bf16(a1, bj, acc[1][j], 0, 0, 0);
            }
        }
    }
    // h1 -> sH (bias + relu + bf16)
#pragma unroll
    for (int nt = 0; nt < 2; nt++) {
        int col = nw + nt * 16 + r16;
        float bv = b0[col];
#pragma unroll
        for (int mt = 0; mt < 2; mt++)
#pragma unroll
            for (int reg = 0; reg < 4; reg++) {
                int rl = mw + mt * 16 + quad * 4 + reg;
                sH[rl][col] = f2b(fmaxf(acc[mt][nt][reg] + bv, 0.f));
            }
    }
    __syncthreads();                     // (4) h1 visible

    // ---- stage 1: h2 = relu(h1 @ W1 + b1); A from sH, W1 direct ----
#pragma unroll
    for (int i = 0; i < 2; i++)
#pragma unroll
        for (int j = 0; j < 2; j++) acc[i][j] = (f32x4){0.f, 0.f, 0.f, 0.f};
#pragma unroll
    for (int kt = 0; kt < 2; kt++) {
#pragma unroll
        for (int ks = 0; ks < 2; ks++) {
            int ko = kt * 64 + ks * 32 + quad * 8;
            bf16x8 a0 = *(const bf16x8*)&sH[mw + r16][ko];
            bf16x8 a1 = *(const bf16x8*)&sH[mw + 16 + r16][ko];
#pragma unroll
            for (int j = 0; j < 2; j++) {
                int n = nw + 16 * j + r16;
                bf16x8 bj = *(const bf16x8*)(W1 + (size_t)n * 128 + ko);
                acc[0][j] = __builtin_amdgcn_mfma_f32_16x16x32_bf16(a0, bj, acc[0][j], 0, 0, 0);
                acc[1][j] = __builtin_amdgcn_mfma_f32_16x16x32_bf16(a1, bj, acc[1][j], 0, 0, 0);
            }
        }
    }
    __syncthreads();                     // (5) all stage-1 reads of h1 complete
    // h2 -> sH
#pragma unroll
    for (int nt = 0; nt < 2; nt++) {
        int col = nw + nt * 16 + r16;
        float bv = b1[col];
#pragma unroll
        for (int mt = 0; mt < 2; mt++)
#pragma unroll
            for (int reg = 0; reg < 4; reg++) {
                int rl = mw + mt * 16 + quad * 4 + reg;
                sH[rl][col] = f2b(fmaxf(acc[mt][nt][reg] + bv, 0.f));
            }
    }
    __syncthreads();                     // (6) h2 visible

    // ---- stage 2: out = h2 @ W2 + b2 + resid(x); A from sH, W2 direct ----
#pragma unroll
    for (int i = 0; i < 2; i++)
#pragma unroll
        for (int j = 0; j < 2; j++) acc[i][j] = (f32x4){0.f, 0.f, 0.f, 0.f};
#pragma unroll
    for (int kt = 0; kt < 2; kt++) {
#pragma unroll
        for (int ks = 0; ks < 2; ks++) {
            int ko = kt * 64 + ks * 32 + quad * 8;
            bf16x8 a0 = *(const bf16x8*)&sH[mw + r16][ko];
            bf16x8 a1 = *(const bf16x8*)&sH[mw + 16 + r16][ko];
#pragma unroll
            for (int j = 0; j < 2; j++) {
                int n = nw + 16 * j + r16;
                bf16x8 bj = *(const bf16x8*)(W2 + (size_t)n * 128 + ko);
                acc[0][j] = __builtin_amdgcn_mfma_f32_16x16x32_bf16(a0, bj, acc[0][j], 0, 0, 0);
                acc[1][j] = __builtin_amdgcn_mfma_f32_16x16x32_bf16(a1, bj, acc[1][j], 0, 0, 0);
            }
        }
    }
#pragma unroll
    for (int nt = 0; nt < 2; nt++) {
        int col = nw + nt * 16 + r16;
        float bv = b2[col];
#pragma unroll
        for (int mt = 0; mt < 2; mt++)
#pragma unroll
            for (int reg = 0; reg < 4; reg++) {
                int row = mw + mt * 16 + quad * 4 + reg;
                float v = acc[mt][nt][reg] + bv + b2f(xg[growBase + (size_t)row * 128 + col]);
                outp[growBase + (size_t)row * 128 + col] = f2b(v);
            }
    }
}

// ------------- last linear: out[m,0:3] = x[m,:] @ w_last + b_last -------------
__global__ __launch_bounds__(256) void last_linear_kern(
    const u16* __restrict__ x, const float* __restrict__ w,
    const float* __restrict__ bias, float* __restrict__ outp, int M)
{
    __shared__ float sw[128 * 3];
    int t = threadIdx.x;
    for (int i = t; i < 384; i += 256) sw[i] = w[i];
    __syncthreads();
    int wave = t >> 6;
    int lane = t & 63;
    int row = blockIdx.x * 4 + wave;
    if (row >= M) return;
    const u16* xr = x + (size_t)row * 128;
    float p0 = 0.f, p1 = 0.f, p2 = 0.f;
#pragma unroll
    for (int h = 0; h < 2; h++) {
        int c = lane + h * 64;
        float xv = b2f(xr[c]);
        p0 += xv * sw[c * 3 + 0];
        p1 += xv * sw[c * 3 + 1];
        p2 += xv * sw[c * 3 + 2];
    }
#pragma unroll
    for (int off = 32; off > 0; off >>= 1) {
        p0 += __shfl_xor(p0, off);
        p1 += __shfl_xor(p1, off);
        p2 += __shfl_xor(p2, off);
    }
    if (lane == 0) {
        float* o = outp + (size_t)row * 3;
        o[0] = p0 + bias[0];
        o[1] = p1 + bias[1];
        o[2] = p2 + bias[2];
    }
}

extern "C" void kernel_launch(void* const* d_in, const int* in_sizes, int n_in,
                              void* d_out, int out_size, void* d_ws, size_t ws_size,
                              hipStream_t stream)
{
    const float* x_in    = (const float*)d_in[0];
    const float* mass    = (const float*)d_in[1];
    const float* evals   = (const float*)d_in[2];
    const float* evecs   = (const float*)d_in[3];
    const int*   rows    = (const int*)  d_in[4];
    const int*   cols    = (const int*)  d_in[5];
    const float* gvx     = (const float*)d_in[6];
    const float* gvy     = (const float*)d_in[7];
    const float* w_first = (const float*)d_in[8];
    const float* b_first = (const float*)d_in[9];
    const float* dtimes  = (const float*)d_in[10];
    const float* A_re    = (const float*)d_in[11];
    const float* A_im    = (const float*)d_in[12];
    const float* w0      = (const float*)d_in[13];
    const float* b0      = (const float*)d_in[14];
    const float* w1      = (const float*)d_in[15];
    const float* b1      = (const float*)d_in[16];
    const float* w2      = (const float*)d_in[17];
    const float* b2      = (const float*)d_in[18];
    const float* w_last  = (const float*)d_in[19];
    const float* b_last  = (const float*)d_in[20];
    float* outp = (float*)d_out;

    const size_t SZ = (size_t)B_ * N_ * 128;   // 20,480,000 elements
    const size_t NZ = (size_t)N_ * 128;        //  5,120,000 elements

    // workspace layout (~174 MB)
    u16* P0 = (u16*)d_ws;                      // 41 MB  (x ping-pong)
    u16* P1 = P0 + SZ;                         // 41 MB  (xd ping-pong)
    u16* GF = P1 + SZ;                         // 41 MB  (gX/gY slots 0-1)
    float* SC = (float*)(GF + SZ);             // 41 MB  partials / gX/gY slots 2-3 (disjoint lifetimes)
    u16* ys_t = (u16*)(SC + 8388608);          // 128 KB in SC tail (dead before spmm writes slots 2-3)
    u16* WP0 = (u16*)(SC + 2 * NZ);            // packed transposed bf16 weights
    u16* WP1 = WP0 + 4 * 49152;
    u16* WP2 = WP1 + 4 * 16384;
    u16* WR1 = WP2 + 4 * 16384;                // 4 x [128][256] rotation packs
    u16* WR2 = WR1 + 4 * 32768;
    int* rowptr = (int*)(WR2 + 4 * 32768);     // N+1 (padded to 40004)
    int* nextp  = rowptr + 40004;              // N (histogram counts, then cursors)
    int* scols  = nextp + N_;                  // E sorted cols
    float* svx  = (float*)(scols + E_);        // [B][E] sorted vals
    float* svy  = svx + (size_t)B_ * E_;

    u16* x  = P0;
    u16* xd = P1;
    const int M = B_ * N_;                     // 160000

    // --- CSR build (pattern shared across blocks & X/Y) ---
    int* bTot  = (int*)SC;          // NB_SCAN block totals (transient, pre-loop)
    int* bOff  = bTot + 512;
    int* sperm = bTot + 1024;       // E edge permutation (transient, pre-loop)
    hipMemsetAsync(nextp, 0, N_ * sizeof(int), stream);
    hist_kern<<<dim3((E_ + 255) / 256), 256, 0, stream>>>(rows, nextp);
    scan1_kern<<<dim3(NB_SCAN), 256, 0, stream>>>(nextp, rowptr, bTot);
    scan2_kern<<<dim3(1), 256, 0, stream>>>(bTot, bOff, rowptr + N_);
    scan3_kern<<<dim3(NB_SCAN), 256, 0, stream>>>(rowptr, nextp, bOff);
    scatter_idx_kern<<<dim3((E_ + 255) / 256), 256, 0, stream>>>(
        rows, cols, nextp, scols, sperm);
    gather_vals_kern<<<dim3((E_ + 255) / 256), 256, 0, stream>>>(
        sperm, gvx, gvy, svx, svy);

    // --- weight packing (once per launch) ---
    pack_w_kern<<<dim3(192, 1, 4), 256, 0, stream>>>(w0, WP0, 384);
    pack_w_kern<<<dim3(64, 1, 4), 256, 0, stream>>>(w1, WP1, 128);
    pack_w_kern<<<dim3(64, 1, 4), 256, 0, stream>>>(w2, WP2, 128);
    pack_rot_kern<<<dim3(128, 1, 4), 256, 0, stream>>>(A_re, A_im, WR1, WR2);

    first_linear_kern<<<dim3(M * 16 / 256), 256, 0, stream>>>(x_in, w_first, b_first, x, M);

    // gX/gY slots: z<2 in GF, z>=2 in SC (partials/ys_t dead by the time spmm writes)
    u16* GXY0 = GF;
    u16* GXY1 = (u16*)SC;

    for (int i = 0; i < 4; i++) {
        // --- spectral diffusion ---
        spec_stage1_mfma_kern<<<dim3(128, B_), 256, 0, stream>>>(x, mass, evecs, SC);
        spec_stage2_coef_kern<<<dim3(B_ * 128), 128, 0, stream>>>(
            SC, evals, dtimes + (size_t)i * 128, ys_t);
        diffuse_gemm_kern<<<dim3(N_ / 64, 1, B_), 256, 0, stream>>>(evecs, ys_t, xd);
        // --- sparse gradients (all batches, one dispatch) ---
        spmm_csr_kern<<<dim3(N_ / 4, 1, B_), 256, 0, stream>>>(
            rowptr, scols, svx, svy, xd, GXY0, GXY1);
        // --- fused rotate+tanh+MLP+residual (all batches, one dispatch, 512 thr) ---
        mlp_rot_fused_kern<<<dim3(N_ / 64, 1, B_), 512, 0, stream>>>(
            x, xd, GXY0, GXY1,
            WR1 + (size_t)i * 32768, WR2 + (size_t)i * 32768,
            WP0 + (size_t)i * 49152, WP1 + (size_t)i * 16384, WP2 + (size_t)i * 16384,
            b0 + (size_t)i * 128, b1 + (size_t)i * 128, b2 + (size_t)i * 128,
            xd);
        u16* tmp = x; x = xd; xd = tmp;
    }

    last_linear_kern<<<dim3(M / 4), 256, 0, stream>>>(x, w_last, b_last, outp, M);
}

// Round 9
// 1203.090 us; speedup vs baseline: 1.3969x; 1.3969x over previous
//
#include <hip/hip_runtime.h>

#define B_ 4
#define N_ 40000
#define E_ 240000
#define NB_SCAN ((N_ + 255) / 256)   // 157 scan blocks

typedef unsigned short u16;
typedef unsigned int u32;
typedef __attribute__((ext_vector_type(8))) short bf16x8;
typedef __attribute__((ext_vector_type(4))) float f32x4;

__device__ __forceinline__ float b2f(u16 h) {
    u32 u = ((u32)h) << 16;
    return __uint_as_float(u);
}
__device__ __forceinline__ u16 f2b(float f) {
    u32 u = __float_as_uint(f);
    u32 r = (u + 0x7fffu + ((u >> 16) & 1u)) >> 16;
    return (u16)r;
}

// ---------------- first linear: x = x_in @ w_first + b_first (bf16 out, 8 c/thread) ----------------
__global__ __launch_bounds__(256) void first_linear_kern(
    const float* __restrict__ x_in, const float* __restrict__ w,
    const float* __restrict__ bias, u16* __restrict__ xout, int M)
{
    __shared__ float sw[6 * 128];
    __shared__ float sb[128];
    int t = threadIdx.x;
    for (int i = t; i < 768; i += 256) sw[i] = w[i];
    if (t < 128) sb[t] = bias[t];
    __syncthreads();
    int idx = blockIdx.x * 256 + t;   // = row*16 + cg
    int row = idx >> 4;
    int cg = (idx & 15) * 8;
    if (row >= M) return;
    const float* xr = x_in + (size_t)row * 6;
    float xv[6];
#pragma unroll
    for (int j = 0; j < 6; j++) xv[j] = xr[j];
    float acc[8];
#pragma unroll
    for (int i = 0; i < 8; i++) acc[i] = sb[cg + i];
#pragma unroll
    for (int j = 0; j < 6; j++)
#pragma unroll
        for (int i = 0; i < 8; i++) acc[i] += xv[j] * sw[j * 128 + cg + i];
    ushort4 h0, h1;
    h0.x = f2b(acc[0]); h0.y = f2b(acc[1]); h0.z = f2b(acc[2]); h0.w = f2b(acc[3]);
    h1.x = f2b(acc[4]); h1.y = f2b(acc[5]); h1.z = f2b(acc[6]); h1.w = f2b(acc[7]);
    uint4 pk;
    pk.x = (u32)h0.x | ((u32)h0.y << 16);
    pk.y = (u32)h0.z | ((u32)h0.w << 16);
    pk.z = (u32)h1.x | ((u32)h1.y << 16);
    pk.w = (u32)h1.z | ((u32)h1.w << 16);
    *(uint4*)(xout + (size_t)row * 128 + cg) = pk;
}

// ------------- weight pack: dst[n][k] = bf16(src[k][n]), per block i = blockIdx.z -------------
__global__ __launch_bounds__(256) void pack_w_kern(
    const float* __restrict__ src, u16* __restrict__ dst, int K)
{
    int i = blockIdx.z;
    src += (size_t)i * K * 128;
    dst += (size_t)i * K * 128;
    int idx = blockIdx.x * 256 + threadIdx.x;  // = n*K + k
    int n = idx / K;
    int k = idx % K;
    dst[idx] = f2b(src[(size_t)k * 128 + n]);
}

// ------------- rotation weight pack: WR1[n][k256] = [Are; -Aim]^T, WR2 = [Are; Aim]^T -------------
__global__ __launch_bounds__(256) void pack_rot_kern(
    const float* __restrict__ Are, const float* __restrict__ Aim,
    u16* __restrict__ WR1, u16* __restrict__ WR2)
{
    int i = blockIdx.z;
    const float* are = Are + (size_t)i * 16384;
    const float* aim = Aim + (size_t)i * 16384;
    int idx = blockIdx.x * 256 + threadIdx.x;  // 0..32767 = n*256 + k
    int n = idx >> 8;
    int k = idx & 255;
    float v1, v2;
    if (k < 128) { float a = are[(size_t)k * 128 + n]; v1 = a; v2 = a; }
    else         { float a = aim[(size_t)(k - 128) * 128 + n]; v1 = -a; v2 = a; }
    WR1[(size_t)i * 32768 + idx] = f2b(v1);
    WR2[(size_t)i * 32768 + idx] = f2b(v2);
}

// ------------- CSR build: histogram -> 3-phase parallel scan -> scatter idx -> gather vals -------------
__global__ __launch_bounds__(256) void hist_kern(const int* __restrict__ rows, int* count)
{
    int e = blockIdx.x * 256 + threadIdx.x;
    if (e < E_) atomicAdd(&count[rows[e]], 1);
}

// inclusive scan across a 256-thread block (4 waves, shfl-based)
__device__ __forceinline__ int block_incl_scan_256(int v, int t)
{
    __shared__ int wsum[4];
    int lane = t & 63;
    int wid = t >> 6;
    int x = v;
#pragma unroll
    for (int off = 1; off < 64; off <<= 1) {
        int y = __shfl_up(x, off);
        if (lane >= off) x += y;
    }
    if (lane == 63) wsum[wid] = x;
    __syncthreads();
    if (t == 0) {
        int s = 0;
#pragma unroll
        for (int i = 0; i < 4; i++) { int tm = wsum[i]; wsum[i] = s; s += tm; }
    }
    __syncthreads();
    return x + wsum[wid];
}

// phase 1: per-block exclusive scan of counts -> rowptr (partial), block totals
__global__ __launch_bounds__(256) void scan1_kern(
    const int* __restrict__ count, int* __restrict__ excl_out,
    int* __restrict__ blockTotals)
{
    int t = threadIdx.x;
    int g = blockIdx.x * 256 + t;
    int v = (g < N_) ? count[g] : 0;
    int incl = block_incl_scan_256(v, t);
    if (g < N_) excl_out[g] = incl - v;
    if (t == 255) blockTotals[blockIdx.x] = incl;
}

// phase 2: single-block scan of 157 block totals -> exclusive block offsets + grand total
__global__ __launch_bounds__(256) void scan2_kern(
    const int* __restrict__ blockTotals, int* __restrict__ blockOffs,
    int* __restrict__ totalOut)
{
    int t = threadIdx.x;
    int v = (t < NB_SCAN) ? blockTotals[t] : 0;
    int incl = block_incl_scan_256(v, t);
    if (t < NB_SCAN) blockOffs[t] = incl - v;
    if (t == 255) *totalOut = incl;   // = E_, written to rowptr[N_]
}

// phase 3: add block offsets; materialize rowptr + nextp cursors
__global__ __launch_bounds__(256) void scan3_kern(
    int* __restrict__ rowptr, int* __restrict__ nextp,
    const int* __restrict__ blockOffs)
{
    int t = threadIdx.x;
    int g = blockIdx.x * 256 + t;
    if (g >= N_) return;
    int v = rowptr[g] + blockOffs[blockIdx.x];
    rowptr[g] = v;
    nextp[g] = v;
}

// scatter only indices (2 scattered u32 writes per edge)
__global__ __launch_bounds__(256) void scatter_idx_kern(
    const int* __restrict__ rows, const int* __restrict__ cols,
    int* nextp, int* __restrict__ scols, int* __restrict__ sperm)
{
    int e = blockIdx.x * 256 + threadIdx.x;
    if (e >= E_) return;
    int r = rows[e];
    int pos = atomicAdd(&nextp[r], 1);
    scols[pos] = cols[e];
    sperm[pos] = e;
}

// gather values: coalesced writes, L2-cached random reads
__global__ __launch_bounds__(256) void gather_vals_kern(
    const int* __restrict__ sperm,
    const float* __restrict__ gvx, const float* __restrict__ gvy,
    float* __restrict__ svx, float* __restrict__ svy)
{
    int pos = blockIdx.x * 256 + threadIdx.x;
    if (pos >= E_) return;
    int e = sperm[pos];
#pragma unroll
    for (int b = 0; b < B_; b++) {
        svx[(size_t)b * E_ + pos] = gvx[(size_t)b * E_ + e];
        svy[(size_t)b * E_ + pos] = gvy[(size_t)b * E_ + e];
    }
}

// ------------- CSR dual spMM (all batches via z), bf16 packed out, edge-unrolled x2 -------------
__global__ __launch_bounds__(256) void spmm_csr_kern(
    const int* __restrict__ rowptr, const int* __restrict__ scols,
    const float* __restrict__ svx, const float* __restrict__ svy,
    const u16* __restrict__ xd, u16* __restrict__ gXY0, u16* __restrict__ gXY1)
{
    const size_t NZ = (size_t)N_ * 128;
    int z = blockIdx.z;
    const float* svx_b = svx + (size_t)z * E_;
    const float* svy_b = svy + (size_t)z * E_;
    const u16* xd_b = xd + (size_t)z * NZ;
    u16* base = (z < 2) ? (gXY0 + (size_t)z * 2 * NZ) : (gXY1 + (size_t)(z - 2) * 2 * NZ);
    u16* gXh = base;
    u16* gYh = base + NZ;

    int t = threadIdx.x;
    int r = blockIdx.x * 4 + (t >> 6);
    int c2 = (t & 63) * 2;
    int beg = rowptr[r], end = rowptr[r + 1];
    float ax0 = 0.f, ax1 = 0.f, ay0 = 0.f, ay1 = 0.f;
    int j = beg;
    for (; j + 1 < end; j += 2) {
        int ca = scols[j], cb = scols[j + 1];
        u32 xwa = *(const u32*)(xd_b + (size_t)ca * 128 + c2);
        u32 xwb = *(const u32*)(xd_b + (size_t)cb * 128 + c2);
        float vxa = svx_b[j], vya = svy_b[j];
        float vxb = svx_b[j + 1], vyb = svy_b[j + 1];
        float xa0 = b2f((u16)(xwa & 0xffffu)), xa1 = b2f((u16)(xwa >> 16));
        float xb0 = b2f((u16)(xwb & 0xffffu)), xb1 = b2f((u16)(xwb >> 16));
        ax0 += vxa * xa0; ax1 += vxa * xa1;
        ay0 += vya * xa0; ay1 += vya * xa1;
        ax0 += vxb * xb0; ax1 += vxb * xb1;
        ay0 += vyb * xb0; ay1 += vyb * xb1;
    }
    if (j < end) {
        int col = scols[j];
        u32 xw = *(const u32*)(xd_b + (size_t)col * 128 + c2);
        float x0 = b2f((u16)(xw & 0xffffu));
        float x1 = b2f((u16)(xw >> 16));
        float vx = svx_b[j], vy = svy_b[j];
        ax0 += vx * x0; ax1 += vx * x1;
        ay0 += vy * x0; ay1 += vy * x1;
    }
    u32 px = (u32)f2b(ax0) | ((u32)f2b(ax1) << 16);
    u32 py = (u32)f2b(ay0) | ((u32)f2b(ay1) << 16);
    *(u32*)(gXh + (size_t)r * 128 + c2) = px;
    *(u32*)(gYh + (size_t)r * 128 + c2) = py;
}

// ------------- spectral projection stage 1: MFMA over transposed LDS tiles -------------
__global__ __launch_bounds__(256) void spec_stage1_mfma_kern(
    const u16* __restrict__ x, const float* __restrict__ mass,
    const float* __restrict__ evecs, float* __restrict__ partials)
{
    __shared__ __align__(16) u16 sEVh[128][40];
    __shared__ __align__(16) u16 sEVl[128][40];
    __shared__ __align__(16) u16 sXM[128][40];
    int b = blockIdx.y;
    int pb = blockIdx.x;
    const u16* xb = x + (size_t)b * N_ * 128;
    const float* mb = mass + (size_t)b * N_;
    const float* eb = evecs + (size_t)b * N_ * 128;
    float* dst = partials + ((size_t)b * 128 + pb) * 16384;

    int t = threadIdx.x;
    int wv = t >> 6;
    int lane = t & 63;
    int quad = lane >> 4;
    int r16 = lane & 15;
    int kb = wv * 32;
    int kc = (t & 63) * 2;
    int nh = wv;

    f32x4 acc[2][8];
#pragma unroll
    for (int i = 0; i < 2; i++)
#pragma unroll
        for (int j = 0; j < 8; j++) acc[i][j] = (f32x4){0.f, 0.f, 0.f, 0.f};

    for (int ch = pb; ch < N_ / 32; ch += 128) {
        int nbase = ch * 32 + nh * 8;
        float4 m0 = *(const float4*)(mb + nbase);
        float4 m1 = *(const float4*)(mb + nbase + 4);
        float mm[8] = {m0.x, m0.y, m0.z, m0.w, m1.x, m1.y, m1.z, m1.w};
        u32 eh0[4], eh1[4], el0[4], el1[4], xq0[4], xq1[4];
#pragma unroll
        for (int jp = 0; jp < 4; jp++) {
            eh0[jp] = 0; eh1[jp] = 0; el0[jp] = 0;
            el1[jp] = 0; xq0[jp] = 0; xq1[jp] = 0;
        }
#pragma unroll
        for (int j = 0; j < 8; j++) {
            float2 e = *(const float2*)(eb + (size_t)(nbase + j) * 128 + kc);
            u32 xw = *(const u32*)(xb + (size_t)(nbase + j) * 128 + kc);
            u16 h0 = f2b(e.x);
            u16 h1 = f2b(e.y);
            u16 l0 = f2b(e.x - b2f(h0));
            u16 l1 = f2b(e.y - b2f(h1));
            u16 q0 = f2b(b2f((u16)(xw & 0xffffu)) * mm[j]);
            u16 q1 = f2b(b2f((u16)(xw >> 16)) * mm[j]);
            int sh = (j & 1) * 16;
            int jp = j >> 1;
            eh0[jp] |= ((u32)h0) << sh; eh1[jp] |= ((u32)h1) << sh;
            el0[jp] |= ((u32)l0) << sh; el1[jp] |= ((u32)l1) << sh;
            xq0[jp] |= ((u32)q0) << sh; xq1[jp] |= ((u32)q1) << sh;
        }
        __syncthreads();
        *(uint4*)&sEVh[kc][nh * 8]     = make_uint4(eh0[0], eh0[1], eh0[2], eh0[3]);
        *(uint4*)&sEVh[kc + 1][nh * 8] = make_uint4(eh1[0], eh1[1], eh1[2], eh1[3]);
        *(uint4*)&sEVl[kc][nh * 8]     = make_uint4(el0[0], el0[1], el0[2], el0[3]);
        *(uint4*)&sEVl[kc + 1][nh * 8] = make_uint4(el1[0], el1[1], el1[2], el1[3]);
        *(uint4*)&sXM[kc][nh * 8]      = make_uint4(xq0[0], xq0[1], xq0[2], xq0[3]);
        *(uint4*)&sXM[kc + 1][nh * 8]  = make_uint4(xq1[0], xq1[1], xq1[2], xq1[3]);
        __syncthreads();

        bf16x8 ah0 = *(const bf16x8*)&sEVh[kb + r16][quad * 8];
        bf16x8 ah1 = *(const bf16x8*)&sEVh[kb + 16 + r16][quad * 8];
        bf16x8 al0 = *(const bf16x8*)&sEVl[kb + r16][quad * 8];
        bf16x8 al1 = *(const bf16x8*)&sEVl[kb + 16 + r16][quad * 8];
#pragma unroll
        for (int nt = 0; nt < 8; nt++) {
            bf16x8 bx = *(const bf16x8*)&sXM[nt * 16 + r16][quad * 8];
            acc[0][nt] = __builtin_amdgcn_mfma_f32_16x16x32_bf16(ah0, bx, acc[0][nt], 0, 0, 0);
            acc[1][nt] = __builtin_amdgcn_mfma_f32_16x16x32_bf16(ah1, bx, acc[1][nt], 0, 0, 0);
            acc[0][nt] = __builtin_amdgcn_mfma_f32_16x16x32_bf16(al0, bx, acc[0][nt], 0, 0, 0);
            acc[1][nt] = __builtin_amdgcn_mfma_f32_16x16x32_bf16(al1, bx, acc[1][nt], 0, 0, 0);
        }
    }

#pragma unroll
    for (int mt = 0; mt < 2; mt++)
#pragma unroll
        for (int nt = 0; nt < 8; nt++)
#pragma unroll
            for (int reg = 0; reg < 4; reg++) {
                int kk = kb + mt * 16 + quad * 4 + reg;
                int cc = nt * 16 + r16;
                dst[(size_t)kk * 128 + cc] = acc[mt][nt][reg];
            }
}

// ------------- stage 2 + coefficients, TRANSPOSED bf16 out: ys_t[b][c][k] -------------
__global__ __launch_bounds__(128) void spec_stage2_coef_kern(
    const float* __restrict__ partials, const float* __restrict__ evals,
    const float* __restrict__ dt, u16* __restrict__ ys_t)
{
    int b = blockIdx.x >> 7;
    int k = blockIdx.x & 127;
    int c = threadIdx.x;
    const float* p = partials + (size_t)b * 128 * 16384 + (size_t)k * 128 + c;
    float s = 0.f;
#pragma unroll 8
    for (int pb = 0; pb < 128; pb++) s += p[(size_t)pb * 16384];
    float co = expf(-evals[b * 128 + k] * dt[c]);
    ys_t[((size_t)b * 128 + c) * 128 + k] = f2b(s * co);
}

// ------------- MFMA GEMM: out[m,0:128] = A[m,:KK] @ W (bf16 out); AF32 path for evecs ------
template <int KK, bool AF32>
__global__ __launch_bounds__(256) void mgemm_kern(
    const void* __restrict__ A0v,
    const u16* __restrict__ Wp, u16* __restrict__ outp,
    size_t aBatch, size_t wBatch, size_t oBatch)
{
    __shared__ u16 sA[64][72];
    __shared__ u16 sB[128][72];
    int z = blockIdx.z;
    const u16* Wb = Wp + wBatch * (size_t)z;
    size_t aOff = aBatch * (size_t)z;
    size_t oOff = oBatch * (size_t)z;

    int t = threadIdx.x;
    int m0 = blockIdx.x * 64;
    int wv = t >> 6;
    int lane = t & 63;
    int quad = lane >> 4;
    int r16 = lane & 15;
    int mw = (wv & 1) * 32;
    int nw = (wv >> 1) * 64;

    f32x4 acc[2][4];
#pragma unroll
    for (int i = 0; i < 2; i++)
#pragma unroll
        for (int j = 0; j < 4; j++) acc[i][j] = (f32x4){0.f, 0.f, 0.f, 0.f};

#pragma unroll 1
    for (int kt = 0; kt < KK / 64; kt++) {
        int kbase = kt * 64;
        __syncthreads();
        if (AF32) {
            const float* Af = (const float*)A0v + aOff;
#pragma unroll
            for (int p = 0; p < 4; p++) {
                int idx = p * 256 + t;
                int row = idx >> 4;
                int seg = idx & 15;
                float4 v = *(const float4*)(Af + (size_t)(m0 + row) * 128 + kbase + seg * 4);
                ushort4 h;
                h.x = f2b(v.x); h.y = f2b(v.y); h.z = f2b(v.z); h.w = f2b(v.w);
                *(ushort4*)&sA[row][seg * 4] = h;
            }
        } else {
            const u16* Ah = (const u16*)A0v + aOff;
#pragma unroll
            for (int p = 0; p < 2; p++) {
                int idx = p * 256 + t;
                int row = idx >> 3;
                int seg = idx & 7;
                *(uint4*)&sA[row][seg * 8] =
                    *(const uint4*)(Ah + (size_t)(m0 + row) * 128 + kbase + seg * 8);
            }
        }
        {
#pragma unroll
            for (int p = 0; p < 4; p++) {
                int idx = p * 256 + t;
                int n = idx >> 3;
                int seg = idx & 7;
                *(uint4*)&sB[n][seg * 8] =
                    *(const uint4*)(Wb + (size_t)n * KK + kbase + seg * 8);
            }
        }
        __syncthreads();

#pragma unroll
        for (int ks = 0; ks < 2; ks++) {
            int ko = ks * 32 + quad * 8;
            bf16x8 a0 = *(const bf16x8*)&sA[mw + r16][ko];
            bf16x8 a1 = *(const bf16x8*)&sA[mw + 16 + r16][ko];
            bf16x8 b0 = *(const bf16x8*)&sB[nw + r16][ko];
            bf16x8 b1 = *(const bf16x8*)&sB[nw + 16 + r16][ko];
            bf16x8 b2 = *(const bf16x8*)&sB[nw + 32 + r16][ko];
            bf16x8 b3 = *(const bf16x8*)&sB[nw + 48 + r16][ko];
            acc[0][0] = __builtin_amdgcn_mfma_f32_16x16x32_bf16(a0, b0, acc[0][0], 0, 0, 0);
            acc[0][1] = __builtin_amdgcn_mfma_f32_16x16x32_bf16(a0, b1, acc[0][1], 0, 0, 0);
            acc[0][2] = __builtin_amdgcn_mfma_f32_16x16x32_bf16(a0, b2, acc[0][2], 0, 0, 0);
            acc[0][3] = __builtin_amdgcn_mfma_f32_16x16x32_bf16(a0, b3, acc[0][3], 0, 0, 0);
            acc[1][0] = __builtin_amdgcn_mfma_f32_16x16x32_bf16(a1, b0, acc[1][0], 0, 0, 0);
            acc[1][1] = __builtin_amdgcn_mfma_f32_16x16x32_bf16(a1, b1, acc[1][1], 0, 0, 0);
            acc[1][2] = __builtin_amdgcn_mfma_f32_16x16x32_bf16(a1, b2, acc[1][2], 0, 0, 0);
            acc[1][3] = __builtin_amdgcn_mfma_f32_16x16x32_bf16(a1, b3, acc[1][3], 0, 0, 0);
        }
    }

#pragma unroll
    for (int nt = 0; nt < 4; nt++) {
        int col = nw + nt * 16 + r16;
#pragma unroll
        for (int mt = 0; mt < 2; mt++) {
#pragma unroll
            for (int reg = 0; reg < 4; reg++) {
                int row = m0 + mw + mt * 16 + quad * 4 + reg;
                outp[oOff + (size_t)row * 128 + col] = f2b(acc[mt][nt][reg]);
            }
        }
    }
}

// ------------- FUSED rotation + tanh + 3-layer MiniMLP (512 threads, all batches via z) -------------
// 8 waves: 2(M) x 4(N), each wave computes 32x32 per stage. 80 KB LDS -> 2 blocks/CU x 8 waves
// = 4 waves/SIMD; 2 blocks/CU interleave across barriers.
__global__ __launch_bounds__(512) void mlp_rot_fused_kern(
    const u16* __restrict__ xg, const u16* __restrict__ xdg,
    const u16* __restrict__ gXY0, const u16* __restrict__ gXY1,
    const u16* __restrict__ WR1, const u16* __restrict__ WR2,
    const u16* __restrict__ W0, const u16* __restrict__ W1, const u16* __restrict__ W2,
    const float* __restrict__ b0, const float* __restrict__ b1, const float* __restrict__ b2,
    u16* __restrict__ outp)
{
    __shared__ u16 sGX[64][136];
    __shared__ u16 sGY[64][136];
    __shared__ u16 sB[128][72];
    __shared__ __align__(16) u16 sHbuf[9728];   // WR2 chunk view, then h1/h2 view
    __shared__ u16 sA[64][72];
#define HV(r, c) sHbuf[(r) * 152 + (c)]
#define WV(n, c) sHbuf[(n) * 72 + (c)]

    const size_t NZ = (size_t)N_ * 128;
    int z = blockIdx.z;                  // = batch
    const u16* gX = (z < 2) ? (gXY0 + (size_t)z * 2 * NZ) : (gXY1 + (size_t)(z - 2) * 2 * NZ);
    const u16* gY = gX + NZ;
    int m0n = blockIdx.x * 64;
    size_t growBase = ((size_t)z * N_ + m0n) * 128;

    int t = threadIdx.x;
    int wv = t >> 6;                     // 0..7
    int lane = t & 63;
    int quad = lane >> 4;
    int r16 = lane & 15;
    int mw = (wv & 1) * 32;              // 0 or 32
    int nw = (wv >> 1) * 32;             // 0,32,64,96

    // ---- stage gX, gY tiles (1024 uint4 each over 512 threads) ----
#pragma unroll
    for (int p = 0; p < 2; p++) {
        int idx = p * 512 + t;
        int row = idx >> 4;
        int seg = idx & 15;
        *(uint4*)&sGX[row][seg * 8] = *(const uint4*)(gX + (size_t)(m0n + row) * 128 + seg * 8);
        *(uint4*)&sGY[row][seg * 8] = *(const uint4*)(gY + (size_t)(m0n + row) * 128 + seg * 8);
    }

    f32x4 accRe[2][2], accIm[2][2];
#pragma unroll
    for (int i = 0; i < 2; i++)
#pragma unroll
        for (int j = 0; j < 2; j++) {
            accRe[i][j] = (f32x4){0.f, 0.f, 0.f, 0.f};
            accIm[i][j] = (f32x4){0.f, 0.f, 0.f, 0.f};
        }

    // ---- rotation: 4 x 64-k chunks; WR1 -> sB, WR2 -> sHbuf view ----
#pragma unroll 1
    for (int c = 0; c < 4; c++) {
        __syncthreads();   // c=0 also covers sGX/sGY staging
#pragma unroll
        for (int p = 0; p < 2; p++) {
            int idx = p * 512 + t;
            int n = idx >> 3;
            int seg = idx & 7;
            *(uint4*)&sB[n][seg * 8] = *(const uint4*)(WR1 + (size_t)n * 256 + c * 64 + seg * 8);
            *(uint4*)&WV(n, seg * 8) = *(const uint4*)(WR2 + (size_t)n * 256 + c * 64 + seg * 8);
        }
        __syncthreads();

        const u16 (*sRe)[136] = (c < 2) ? sGX : sGY;
        const u16 (*sIm)[136] = (c < 2) ? sGY : sGX;
        int kob = (c & 1) * 64;
#pragma unroll
        for (int ks = 0; ks < 2; ks++) {
            int ko = kob + ks * 32 + quad * 8;
            int kb = ks * 32 + quad * 8;
            bf16x8 aRe0 = *(const bf16x8*)&sRe[mw + r16][ko];
            bf16x8 aRe1 = *(const bf16x8*)&sRe[mw + 16 + r16][ko];
            bf16x8 aIm0 = *(const bf16x8*)&sIm[mw + r16][ko];
            bf16x8 aIm1 = *(const bf16x8*)&sIm[mw + 16 + r16][ko];
#pragma unroll
            for (int j = 0; j < 2; j++) {
                bf16x8 w1f = *(const bf16x8*)&sB[nw + 16 * j + r16][kb];
                bf16x8 w2f = *(const bf16x8*)&WV(nw + 16 * j + r16, kb);
                accRe[0][j] = __builtin_amdgcn_mfma_f32_16x16x32_bf16(aRe0, w1f, accRe[0][j], 0, 0, 0);
                accRe[1][j] = __builtin_amdgcn_mfma_f32_16x16x32_bf16(aRe1, w1f, accRe[1][j], 0, 0, 0);
                accIm[0][j] = __builtin_amdgcn_mfma_f32_16x16x32_bf16(aIm0, w2f, accIm[0][j], 0, 0, 0);
                accIm[1][j] = __builtin_amdgcn_mfma_f32_16x16x32_bf16(aIm1, w2f, accIm[1][j], 0, 0, 0);
            }
        }
    }

    // ---- tanh in place: gf -> sGX (each element owned by exactly one lane) ----
    __syncthreads();   // all fragment reads of sGX/sGY complete
#pragma unroll
    for (int nt = 0; nt < 2; nt++) {
        int col = nw + nt * 16 + r16;
#pragma unroll
        for (int mt = 0; mt < 2; mt++)
#pragma unroll
            for (int reg = 0; reg < 4; reg++) {
                int lrow = mw + mt * 16 + quad * 4 + reg;
                float gx = b2f(sGX[lrow][col]);
                float gy = b2f(sGY[lrow][col]);
                float v = tanhf(gx * accRe[mt][nt][reg] + gy * accIm[mt][nt][reg]);
                sGX[lrow][col] = f2b(v);
            }
    }

    // ---- MLP stage 0: K=384 over concat(x, xd, gf-from-LDS) ----
    f32x4 acc[2][2];
#pragma unroll
    for (int i = 0; i < 2; i++)
#pragma unroll
        for (int j = 0; j < 2; j++) acc[i][j] = (f32x4){0.f, 0.f, 0.f, 0.f};
#pragma unroll 1
    for (int kt = 0; kt < 6; kt++) {
        int kbase = kt * 64;
        int kloc = kbase & 127;
        __syncthreads();   // kt=0 covers tanh writes; also protects sA/sB reuse
        if (kt < 4) {
            const u16* Ap = (kt < 2) ? xg : xdg;
            {
                int row = t >> 3;        // 512 threads = 64 rows x 8 segs
                int seg = t & 7;
                *(uint4*)&sA[row][seg * 8] =
                    *(const uint4*)(Ap + growBase + (size_t)row * 128 + kloc + seg * 8);
            }
        }
#pragma unroll
        for (int p = 0; p < 2; p++) {
            int idx = p * 512 + t;
            int n = idx >> 3;
            int seg = idx & 7;
            *(uint4*)&sB[n][seg * 8] = *(const uint4*)(W0 + (size_t)n * 384 + kbase + seg * 8);
        }
        __syncthreads();
#pragma unroll
        for (int ks = 0; ks < 2; ks++) {
            int ko = ks * 32 + quad * 8;
            bf16x8 a0, a1;
            if (kt < 4) {
                a0 = *(const bf16x8*)&sA[mw + r16][ko];
                a1 = *(const bf16x8*)&sA[mw + 16 + r16][ko];
            } else {
                a0 = *(const bf16x8*)&sGX[mw + r16][kloc + ko];
                a1 = *(const bf16x8*)&sGX[mw + 16 + r16][kloc + ko];
            }
#pragma unroll
            for (int j = 0; j < 2; j++) {
                bf16x8 bj = *(const bf16x8*)&sB[nw + 16 * j + r16][ko];
                acc[0][j] = __builtin_amdgcn_mfma_f32_16x16x32_bf16(a0, bj, acc[0][j], 0, 0, 0);
                acc[1][j] = __builtin_amdgcn_mfma_f32_16x16x32_bf16(a1, bj, acc[1][j], 0, 0, 0);
            }
        }
    }
    // h1 -> sHbuf (bias + relu + bf16); WR2 chunks fully consumed
    __syncthreads();
#pragma unroll
    for (int nt = 0; nt < 2; nt++) {
        int col = nw + nt * 16 + r16;
        float bv = b0[col];
#pragma unroll
        for (int mt = 0; mt < 2; mt++)
#pragma unroll
            for (int reg = 0; reg < 4; reg++) {
                int rl = mw + mt * 16 + quad * 4 + reg;
                HV(rl, col) = f2b(fmaxf(acc[mt][nt][reg] + bv, 0.f));
            }
    }

    // ---- stage 1: h2 = relu(h1 @ W1 + b1) ----
#pragma unroll
    for (int i = 0; i < 2; i++)
#pragma unroll
        for (int j = 0; j < 2; j++) acc[i][j] = (f32x4){0.f, 0.f, 0.f, 0.f};
#pragma unroll 1
    for (int kt = 0; kt < 2; kt++) {
        int kbase = kt * 64;
        __syncthreads();   // kt=0 covers h1 writes
#pragma unroll
        for (int p = 0; p < 2; p++) {
            int idx = p * 512 + t;
            int n = idx >> 3;
            int seg = idx & 7;
            *(uint4*)&sB[n][seg * 8] = *(const uint4*)(W1 + (size_t)n * 128 + kbase + seg * 8);
        }
        __syncthreads();
#pragma unroll
        for (int ks = 0; ks < 2; ks++) {
            int ko = kbase + ks * 32 + quad * 8;
            int kb = ks * 32 + quad * 8;
            bf16x8 a0 = *(const bf16x8*)&HV(mw + r16, ko);
            bf16x8 a1 = *(const bf16x8*)&HV(mw + 16 + r16, ko);
#pragma unroll
            for (int j = 0; j < 2; j++) {
                bf16x8 bj = *(const bf16x8*)&sB[nw + 16 * j + r16][kb];
                acc[0][j] = __builtin_amdgcn_mfma_f32_16x16x32_bf16(a0, bj, acc[0][j], 0, 0, 0);
                acc[1][j] = __builtin_amdgcn_mfma_f32_16x16x32_bf16(a1, bj, acc[1][j], 0, 0, 0);
            }
        }
    }
    __syncthreads();   // all waves done reading h1
#pragma unroll
    for (int nt = 0; nt < 2; nt++) {
        int col = nw + nt * 16 + r16;
        float bv = b1[col];
#pragma unroll
        for (int mt = 0; mt < 2; mt++)
#pragma unroll
            for (int reg = 0; reg < 4; reg++) {
                int rl = mw + mt * 16 + quad * 4 + reg;
                HV(rl, col) = f2b(fmaxf(acc[mt][nt][reg] + bv, 0.f));
            }
    }

    // ---- stage 2: out = h2 @ W2 + b2 + resid(x) ----
#pragma unroll
    for (int i = 0; i < 2; i++)
#pragma unroll
        for (int j = 0; j < 2; j++) acc[i][j] = (f32x4){0.f, 0.f, 0.f, 0.f};
#pragma unroll 1
    for (int kt = 0; kt < 2; kt++) {
        int kbase = kt * 64;
        __syncthreads();   // kt=0 covers h2 writes
#pragma unroll
        for (int p = 0; p < 2; p++) {
            int idx = p * 512 + t;
            int n = idx >> 3;
            int seg = idx & 7;
            *(uint4*)&sB[n][seg * 8] = *(const uint4*)(W2 + (size_t)n * 128 + kbase + seg * 8);
        }
        __syncthreads();
#pragma unroll
        for (int ks = 0; ks < 2; ks++) {
            int ko = kbase + ks * 32 + quad * 8;
            int kb = ks * 32 + quad * 8;
            bf16x8 a0 = *(const bf16x8*)&HV(mw + r16, ko);
            bf16x8 a1 = *(const bf16x8*)&HV(mw + 16 + r16, ko);
#pragma unroll
            for (int j = 0; j < 2; j++) {
                bf16x8 bj = *(const bf16x8*)&sB[nw + 16 * j + r16][kb];
                acc[0][j] = __builtin_amdgcn_mfma_f32_16x16x32_bf16(a0, bj, acc[0][j], 0, 0, 0);
                acc[1][j] = __builtin_amdgcn_mfma_f32_16x16x32_bf16(a1, bj, acc[1][j], 0, 0, 0);
            }
        }
    }
#pragma unroll
    for (int nt = 0; nt < 2; nt++) {
        int col = nw + nt * 16 + r16;
        float bv = b2[col];
#pragma unroll
        for (int mt = 0; mt < 2; mt++)
#pragma unroll
            for (int reg = 0; reg < 4; reg++) {
                int row = mw + mt * 16 + quad * 4 + reg;
                float v = acc[mt][nt][reg] + bv + b2f(xg[growBase + (size_t)row * 128 + col]);
                outp[growBase + (size_t)row * 128 + col] = f2b(v);
            }
    }
#undef HV
#undef WV
}

// ------------- last linear: out[m,0:3] = x[m,:] @ w_last + b_last -------------
__global__ __launch_bounds__(256) void last_linear_kern(
    const u16* __restrict__ x, const float* __restrict__ w,
    const float* __restrict__ bias, float* __restrict__ outp, int M)
{
    __shared__ float sw[128 * 3];
    int t = threadIdx.x;
    for (int i = t; i < 384; i += 256) sw[i] = w[i];
    __syncthreads();
    int wave = t >> 6;
    int lane = t & 63;
    int row = blockIdx.x * 4 + wave;
    if (row >= M) return;
    const u16* xr = x + (size_t)row * 128;
    float p0 = 0.f, p1 = 0.f, p2 = 0.f;
#pragma unroll
    for (int h = 0; h < 2; h++) {
        int c = lane + h * 64;
        float xv = b2f(xr[c]);
        p0 += xv * sw[c * 3 + 0];
        p1 += xv * sw[c * 3 + 1];
        p2 += xv * sw[c * 3 + 2];
    }
#pragma unroll
    for (int off = 32; off > 0; off >>= 1) {
        p0 += __shfl_xor(p0, off);
        p1 += __shfl_xor(p1, off);
        p2 += __shfl_xor(p2, off);
    }
    if (lane == 0) {
        float* o = outp + (size_t)row * 3;
        o[0] = p0 + bias[0];
        o[1] = p1 + bias[1];
        o[2] = p2 + bias[2];
    }
}

extern "C" void kernel_launch(void* const* d_in, const int* in_sizes, int n_in,
                              void* d_out, int out_size, void* d_ws, size_t ws_size,
                              hipStream_t stream)
{
    const float* x_in    = (const float*)d_in[0];
    const float* mass    = (const float*)d_in[1];
    const float* evals   = (const float*)d_in[2];
    const float* evecs   = (const float*)d_in[3];
    const int*   rows    = (const int*)  d_in[4];
    const int*   cols    = (const int*)  d_in[5];
    const float* gvx     = (const float*)d_in[6];
    const float* gvy     = (const float*)d_in[7];
    const float* w_first = (const float*)d_in[8];
    const float* b_first = (const float*)d_in[9];
    const float* dtimes  = (const float*)d_in[10];
    const float* A_re    = (const float*)d_in[11];
    const float* A_im    = (const float*)d_in[12];
    const float* w0      = (const float*)d_in[13];
    const float* b0      = (const float*)d_in[14];
    const float* w1      = (const float*)d_in[15];
    const float* b1      = (const float*)d_in[16];
    const float* w2      = (const float*)d_in[17];
    const float* b2      = (const float*)d_in[18];
    const float* w_last  = (const float*)d_in[19];
    const float* b_last  = (const float*)d_in[20];
    float* outp = (float*)d_out;

    const size_t SZ = (size_t)B_ * N_ * 128;   // 20,480,000 elements
    const size_t NZ = (size_t)N_ * 128;        //  5,120,000 elements

    // workspace layout (~174 MB)
    u16* P0 = (u16*)d_ws;                      // 41 MB  (x ping-pong)
    u16* P1 = P0 + SZ;                         // 41 MB  (xd ping-pong)
    u16* GF = P1 + SZ;                         // 41 MB  (gX/gY slots 0-1)
    float* SC = (float*)(GF + SZ);             // 41 MB  partials / gX/gY slots 2-3 (disjoint lifetimes)
    u16* ys_t = (u16*)(SC + 8388608);          // 128 KB in SC tail (dead before spmm writes slots 2-3)
    u16* WP0 = (u16*)(SC + 2 * NZ);            // packed transposed bf16 weights
    u16* WP1 = WP0 + 4 * 49152;
    u16* WP2 = WP1 + 4 * 16384;
    u16* WR1 = WP2 + 4 * 16384;                // 4 x [128][256] rotation packs
    u16* WR2 = WR1 + 4 * 32768;
    int* rowptr = (int*)(WR2 + 4 * 32768);     // N+1 (padded to 40004)
    int* nextp  = rowptr + 40004;              // N (histogram counts, then cursors)
    int* scols  = nextp + N_;                  // E sorted cols
    float* svx  = (float*)(scols + E_);        // [B][E] sorted vals
    float* svy  = svx + (size_t)B_ * E_;

    u16* x  = P0;
    u16* xd = P1;
    const int M = B_ * N_;                     // 160000

    // --- CSR build (pattern shared across blocks & X/Y) ---
    int* bTot  = (int*)SC;          // NB_SCAN block totals (transient, pre-loop)
    int* bOff  = bTot + 512;
    int* sperm = bTot + 1024;       // E edge permutation (transient, pre-loop)
    hipMemsetAsync(nextp, 0, N_ * sizeof(int), stream);
    hist_kern<<<dim3((E_ + 255) / 256), 256, 0, stream>>>(rows, nextp);
    scan1_kern<<<dim3(NB_SCAN), 256, 0, stream>>>(nextp, rowptr, bTot);
    scan2_kern<<<dim3(1), 256, 0, stream>>>(bTot, bOff, rowptr + N_);
    scan3_kern<<<dim3(NB_SCAN), 256, 0, stream>>>(rowptr, nextp, bOff);
    scatter_idx_kern<<<dim3((E_ + 255) / 256), 256, 0, stream>>>(
        rows, cols, nextp, scols, sperm);
    gather_vals_kern<<<dim3((E_ + 255) / 256), 256, 0, stream>>>(
        sperm, gvx, gvy, svx, svy);

    // --- weight packing (once per launch) ---
    pack_w_kern<<<dim3(192, 1, 4), 256, 0, stream>>>(w0, WP0, 384);
    pack_w_kern<<<dim3(64, 1, 4), 256, 0, stream>>>(w1, WP1, 128);
    pack_w_kern<<<dim3(64, 1, 4), 256, 0, stream>>>(w2, WP2, 128);
    pack_rot_kern<<<dim3(128, 1, 4), 256, 0, stream>>>(A_re, A_im, WR1, WR2);

    first_linear_kern<<<dim3(M * 16 / 256), 256, 0, stream>>>(x_in, w_first, b_first, x, M);

    // gX/gY slots: z<2 in GF, z>=2 in SC (partials/ys_t dead by the time spmm writes)
    u16* GXY0 = GF;
    u16* GXY1 = (u16*)SC;

    for (int i = 0; i < 4; i++) {
        // --- spectral diffusion ---
        spec_stage1_mfma_kern<<<dim3(128, B_), 256, 0, stream>>>(x, mass, evecs, SC);
        spec_stage2_coef_kern<<<dim3(B_ * 128), 128, 0, stream>>>(
            SC, evals, dtimes + (size_t)i * 128, ys_t);
        mgemm_kern<128, true><<<dim3(N_ / 64, 1, B_), 256, 0, stream>>>(
            evecs, ys_t, xd, NZ, (size_t)128 * 128, NZ);
        // --- sparse gradients (all batches, one dispatch) ---
        spmm_csr_kern<<<dim3(N_ / 4, 1, B_), 256, 0, stream>>>(
            rowptr, scols, svx, svy, xd, GXY0, GXY1);
        // --- fused rotate+tanh+MLP+residual (all batches, one dispatch, 512 thr) ---
        mlp_rot_fused_kern<<<dim3(N_ / 64, 1, B_), 512, 0, stream>>>(
            x, xd, GXY0, GXY1,
            WR1 + (size_t)i * 32768, WR2 + (size_t)i * 32768,
            WP0 + (size_t)i * 49152, WP1 + (size_t)i * 16384, WP2 + (size_t)i * 16384,
            b0 + (size_t)i * 128, b1 + (size_t)i * 128, b2 + (size_t)i * 128,
            xd);
        u16* tmp = x; x = xd; xd = tmp;
    }

    last_linear_kern<<<dim3(M / 4), 256, 0, stream>>>(x, w_last, b_last, outp, M);
}

// Round 11
// 1172.814 us; speedup vs baseline: 1.4330x; 1.0258x over previous
//
#include <hip/hip_runtime.h>

#define B_ 4
#define N_ 40000
#define E_ 240000
#define NB_SCAN ((N_ + 255) / 256)   // 157 scan blocks

typedef unsigned short u16;
typedef unsigned int u32;
typedef __attribute__((ext_vector_type(8))) short bf16x8;
typedef __attribute__((ext_vector_type(4))) float f32x4;

__device__ __forceinline__ float b2f(u16 h) {
    u32 u = ((u32)h) << 16;
    return __uint_as_float(u);
}
__device__ __forceinline__ u16 f2b(float f) {
    u32 u = __float_as_uint(f);
    u32 r = (u + 0x7fffu + ((u >> 16) & 1u)) >> 16;
    return (u16)r;
}
// fast tanh: clamped exp form; abs err <= ~1e-6 (far below bf16 rounding)
__device__ __forceinline__ float fast_tanh(float x) {
    float cx = fminf(fmaxf(x, -9.f), 9.f);
    float e = __expf(2.f * cx);
    return (e - 1.f) / (e + 1.f);
}

// ---------------- first linear: x = x_in @ w_first + b_first (bf16 out, 8 c/thread) ----------------
__global__ __launch_bounds__(256) void first_linear_kern(
    const float* __restrict__ x_in, const float* __restrict__ w,
    const float* __restrict__ bias, u16* __restrict__ xout, int M)
{
    __shared__ float sw[6 * 128];
    __shared__ float sb[128];
    int t = threadIdx.x;
    for (int i = t; i < 768; i += 256) sw[i] = w[i];
    if (t < 128) sb[t] = bias[t];
    __syncthreads();
    int idx = blockIdx.x * 256 + t;   // = row*16 + cg
    int row = idx >> 4;
    int cg = (idx & 15) * 8;
    if (row >= M) return;
    const float* xr = x_in + (size_t)row * 6;
    float xv[6];
#pragma unroll
    for (int j = 0; j < 6; j++) xv[j] = xr[j];
    float acc[8];
#pragma unroll
    for (int i = 0; i < 8; i++) acc[i] = sb[cg + i];
#pragma unroll
    for (int j = 0; j < 6; j++)
#pragma unroll
        for (int i = 0; i < 8; i++) acc[i] += xv[j] * sw[j * 128 + cg + i];
    ushort4 h0, h1;
    h0.x = f2b(acc[0]); h0.y = f2b(acc[1]); h0.z = f2b(acc[2]); h0.w = f2b(acc[3]);
    h1.x = f2b(acc[4]); h1.y = f2b(acc[5]); h1.z = f2b(acc[6]); h1.w = f2b(acc[7]);
    uint4 pk;
    pk.x = (u32)h0.x | ((u32)h0.y << 16);
    pk.y = (u32)h0.z | ((u32)h0.w << 16);
    pk.z = (u32)h1.x | ((u32)h1.y << 16);
    pk.w = (u32)h1.z | ((u32)h1.w << 16);
    *(uint4*)(xout + (size_t)row * 128 + cg) = pk;
}

// ------------- weight pack: dst[n][k] = bf16(src[k][n]), per block i = blockIdx.z -------------
__global__ __launch_bounds__(256) void pack_w_kern(
    const float* __restrict__ src, u16* __restrict__ dst, int K)
{
    int i = blockIdx.z;
    src += (size_t)i * K * 128;
    dst += (size_t)i * K * 128;
    int idx = blockIdx.x * 256 + threadIdx.x;  // = n*K + k
    int n = idx / K;
    int k = idx % K;
    dst[idx] = f2b(src[(size_t)k * 128 + n]);
}

// ------------- rotation weight pack: WR1[n][k256] = [Are; -Aim]^T, WR2 = [Are; Aim]^T -------------
__global__ __launch_bounds__(256) void pack_rot_kern(
    const float* __restrict__ Are, const float* __restrict__ Aim,
    u16* __restrict__ WR1, u16* __restrict__ WR2)
{
    int i = blockIdx.z;
    const float* are = Are + (size_t)i * 16384;
    const float* aim = Aim + (size_t)i * 16384;
    int idx = blockIdx.x * 256 + threadIdx.x;  // 0..32767 = n*256 + k
    int n = idx >> 8;
    int k = idx & 255;
    float v1, v2;
    if (k < 128) { float a = are[(size_t)k * 128 + n]; v1 = a; v2 = a; }
    else         { float a = aim[(size_t)(k - 128) * 128 + n]; v1 = -a; v2 = a; }
    WR1[(size_t)i * 32768 + idx] = f2b(v1);
    WR2[(size_t)i * 32768 + idx] = f2b(v2);
}

// ------------- CSR build: histogram -> 3-phase parallel scan -> scatter idx -> gather vals -------------
__global__ __launch_bounds__(256) void hist_kern(const int* __restrict__ rows, int* count)
{
    int e = blockIdx.x * 256 + threadIdx.x;
    if (e < E_) atomicAdd(&count[rows[e]], 1);
}

// inclusive scan across a 256-thread block (4 waves, shfl-based)
__device__ __forceinline__ int block_incl_scan_256(int v, int t)
{
    __shared__ int wsum[4];
    int lane = t & 63;
    int wid = t >> 6;
    int x = v;
#pragma unroll
    for (int off = 1; off < 64; off <<= 1) {
        int y = __shfl_up(x, off);
        if (lane >= off) x += y;
    }
    if (lane == 63) wsum[wid] = x;
    __syncthreads();
    if (t == 0) {
        int s = 0;
#pragma unroll
        for (int i = 0; i < 4; i++) { int tm = wsum[i]; wsum[i] = s; s += tm; }
    }
    __syncthreads();
    return x + wsum[wid];
}

// phase 1: per-block exclusive scan of counts -> rowptr (partial), block totals
__global__ __launch_bounds__(256) void scan1_kern(
    const int* __restrict__ count, int* __restrict__ excl_out,
    int* __restrict__ blockTotals)
{
    int t = threadIdx.x;
    int g = blockIdx.x * 256 + t;
    int v = (g < N_) ? count[g] : 0;
    int incl = block_incl_scan_256(v, t);
    if (g < N_) excl_out[g] = incl - v;
    if (t == 255) blockTotals[blockIdx.x] = incl;
}

// phase 2: single-block scan of 157 block totals -> exclusive block offsets + grand total
__global__ __launch_bounds__(256) void scan2_kern(
    const int* __restrict__ blockTotals, int* __restrict__ blockOffs,
    int* __restrict__ totalOut)
{
    int t = threadIdx.x;
    int v = (t < NB_SCAN) ? blockTotals[t] : 0;
    int incl = block_incl_scan_256(v, t);
    if (t < NB_SCAN) blockOffs[t] = incl - v;
    if (t == 255) *totalOut = incl;   // = E_, written to rowptr[N_]
}

// phase 3: add block offsets; materialize rowptr + nextp cursors
__global__ __launch_bounds__(256) void scan3_kern(
    int* __restrict__ rowptr, int* __restrict__ nextp,
    const int* __restrict__ blockOffs)
{
    int t = threadIdx.x;
    int g = blockIdx.x * 256 + t;
    if (g >= N_) return;
    int v = rowptr[g] + blockOffs[blockIdx.x];
    rowptr[g] = v;
    nextp[g] = v;
}

// scatter only indices (2 scattered u32 writes per edge)
__global__ __launch_bounds__(256) void scatter_idx_kern(
    const int* __restrict__ rows, const int* __restrict__ cols,
    int* nextp, int* __restrict__ scols, int* __restrict__ sperm)
{
    int e = blockIdx.x * 256 + threadIdx.x;
    if (e >= E_) return;
    int r = rows[e];
    int pos = atomicAdd(&nextp[r], 1);
    scols[pos] = cols[e];
    sperm[pos] = e;
}

// gather values: coalesced writes, L2-cached random reads
__global__ __launch_bounds__(256) void gather_vals_kern(
    const int* __restrict__ sperm,
    const float* __restrict__ gvx, const float* __restrict__ gvy,
    float* __restrict__ svx, float* __restrict__ svy)
{
    int pos = blockIdx.x * 256 + threadIdx.x;
    if (pos >= E_) return;
    int e = sperm[pos];
#pragma unroll
    for (int b = 0; b < B_; b++) {
        svx[(size_t)b * E_ + pos] = gvx[(size_t)b * E_ + e];
        svy[(size_t)b * E_ + pos] = gvy[(size_t)b * E_ + e];
    }
}

// ------------- CSR dual spMM (all batches via z), bf16 packed out, edge-unrolled x2 -------------
__global__ __launch_bounds__(256) void spmm_csr_kern(
    const int* __restrict__ rowptr, const int* __restrict__ scols,
    const float* __restrict__ svx, const float* __restrict__ svy,
    const u16* __restrict__ xd, u16* __restrict__ gXY0, u16* __restrict__ gXY1)
{
    const size_t NZ = (size_t)N_ * 128;
    int z = blockIdx.z;
    const float* svx_b = svx + (size_t)z * E_;
    const float* svy_b = svy + (size_t)z * E_;
    const u16* xd_b = xd + (size_t)z * NZ;
    u16* base = (z < 2) ? (gXY0 + (size_t)z * 2 * NZ) : (gXY1 + (size_t)(z - 2) * 2 * NZ);
    u16* gXh = base;
    u16* gYh = base + NZ;

    int t = threadIdx.x;
    int r = blockIdx.x * 4 + (t >> 6);
    int c2 = (t & 63) * 2;
    int beg = rowptr[r], end = rowptr[r + 1];
    float ax0 = 0.f, ax1 = 0.f, ay0 = 0.f, ay1 = 0.f;
    int j = beg;
    for (; j + 1 < end; j += 2) {
        int ca = scols[j], cb = scols[j + 1];
        u32 xwa = *(const u32*)(xd_b + (size_t)ca * 128 + c2);
        u32 xwb = *(const u32*)(xd_b + (size_t)cb * 128 + c2);
        float vxa = svx_b[j], vya = svy_b[j];
        float vxb = svx_b[j + 1], vyb = svy_b[j + 1];
        float xa0 = b2f((u16)(xwa & 0xffffu)), xa1 = b2f((u16)(xwa >> 16));
        float xb0 = b2f((u16)(xwb & 0xffffu)), xb1 = b2f((u16)(xwb >> 16));
        ax0 += vxa * xa0; ax1 += vxa * xa1;
        ay0 += vya * xa0; ay1 += vya * xa1;
        ax0 += vxb * xb0; ax1 += vxb * xb1;
        ay0 += vyb * xb0; ay1 += vyb * xb1;
    }
    if (j < end) {
        int col = scols[j];
        u32 xw = *(const u32*)(xd_b + (size_t)col * 128 + c2);
        float x0 = b2f((u16)(xw & 0xffffu));
        float x1 = b2f((u16)(xw >> 16));
        float vx = svx_b[j], vy = svy_b[j];
        ax0 += vx * x0; ax1 += vx * x1;
        ay0 += vy * x0; ay1 += vy * x1;
    }
    u32 px = (u32)f2b(ax0) | ((u32)f2b(ax1) << 16);
    u32 py = (u32)f2b(ay0) | ((u32)f2b(ay1) << 16);
    *(u32*)(gXh + (size_t)r * 128 + c2) = px;
    *(u32*)(gYh + (size_t)r * 128 + c2) = py;
}

// ------------- spectral projection stage 1: MFMA over transposed LDS tiles -------------
__global__ __launch_bounds__(256) void spec_stage1_mfma_kern(
    const u16* __restrict__ x, const float* __restrict__ mass,
    const float* __restrict__ evecs, float* __restrict__ partials)
{
    __shared__ __align__(16) u16 sEVh[128][40];
    __shared__ __align__(16) u16 sEVl[128][40];
    __shared__ __align__(16) u16 sXM[128][40];
    int b = blockIdx.y;
    int pb = blockIdx.x;
    const u16* xb = x + (size_t)b * N_ * 128;
    const float* mb = mass + (size_t)b * N_;
    const float* eb = evecs + (size_t)b * N_ * 128;
    float* dst = partials + ((size_t)b * 128 + pb) * 16384;

    int t = threadIdx.x;
    int wv = t >> 6;
    int lane = t & 63;
    int quad = lane >> 4;
    int r16 = lane & 15;
    int kb = wv * 32;
    int kc = (t & 63) * 2;
    int nh = wv;

    f32x4 acc[2][8];
#pragma unroll
    for (int i = 0; i < 2; i++)
#pragma unroll
        for (int j = 0; j < 8; j++) acc[i][j] = (f32x4){0.f, 0.f, 0.f, 0.f};

    for (int ch = pb; ch < N_ / 32; ch += 128) {
        int nbase = ch * 32 + nh * 8;
        float4 m0 = *(const float4*)(mb + nbase);
        float4 m1 = *(const float4*)(mb + nbase + 4);
        float mm[8] = {m0.x, m0.y, m0.z, m0.w, m1.x, m1.y, m1.z, m1.w};
        u32 eh0[4], eh1[4], el0[4], el1[4], xq0[4], xq1[4];
#pragma unroll
        for (int jp = 0; jp < 4; jp++) {
            eh0[jp] = 0; eh1[jp] = 0; el0[jp] = 0;
            el1[jp] = 0; xq0[jp] = 0; xq1[jp] = 0;
        }
#pragma unroll
        for (int j = 0; j < 8; j++) {
            float2 e = *(const float2*)(eb + (size_t)(nbase + j) * 128 + kc);
            u32 xw = *(const u32*)(xb + (size_t)(nbase + j) * 128 + kc);
            u16 h0 = f2b(e.x);
            u16 h1 = f2b(e.y);
            u16 l0 = f2b(e.x - b2f(h0));
            u16 l1 = f2b(e.y - b2f(h1));
            u16 q0 = f2b(b2f((u16)(xw & 0xffffu)) * mm[j]);
            u16 q1 = f2b(b2f((u16)(xw >> 16)) * mm[j]);
            int sh = (j & 1) * 16;
            int jp = j >> 1;
            eh0[jp] |= ((u32)h0) << sh; eh1[jp] |= ((u32)h1) << sh;
            el0[jp] |= ((u32)l0) << sh; el1[jp] |= ((u32)l1) << sh;
            xq0[jp] |= ((u32)q0) << sh; xq1[jp] |= ((u32)q1) << sh;
        }
        __syncthreads();
        *(uint4*)&sEVh[kc][nh * 8]     = make_uint4(eh0[0], eh0[1], eh0[2], eh0[3]);
        *(uint4*)&sEVh[kc + 1][nh * 8] = make_uint4(eh1[0], eh1[1], eh1[2], eh1[3]);
        *(uint4*)&sEVl[kc][nh * 8]     = make_uint4(el0[0], el0[1], el0[2], el0[3]);
        *(uint4*)&sEVl[kc + 1][nh * 8] = make_uint4(el1[0], el1[1], el1[2], el1[3]);
        *(uint4*)&sXM[kc][nh * 8]      = make_uint4(xq0[0], xq0[1], xq0[2], xq0[3]);
        *(uint4*)&sXM[kc + 1][nh * 8]  = make_uint4(xq1[0], xq1[1], xq1[2], xq1[3]);
        __syncthreads();

        bf16x8 ah0 = *(const bf16x8*)&sEVh[kb + r16][quad * 8];
        bf16x8 ah1 = *(const bf16x8*)&sEVh[kb + 16 + r16][quad * 8];
        bf16x8 al0 = *(const bf16x8*)&sEVl[kb + r16][quad * 8];
        bf16x8 al1 = *(const bf16x8*)&sEVl[kb + 16 + r16][quad * 8];
#pragma unroll
        for (int nt = 0; nt < 8; nt++) {
            bf16x8 bx = *(const bf16x8*)&sXM[nt * 16 + r16][quad * 8];
            acc[0][nt] = __builtin_amdgcn_mfma_f32_16x16x32_bf16(ah0, bx, acc[0][nt], 0, 0, 0);
            acc[1][nt] = __builtin_amdgcn_mfma_f32_16x16x32_bf16(ah1, bx, acc[1][nt], 0, 0, 0);
            acc[0][nt] = __builtin_amdgcn_mfma_f32_16x16x32_bf16(al0, bx, acc[0][nt], 0, 0, 0);
            acc[1][nt] = __builtin_amdgcn_mfma_f32_16x16x32_bf16(al1, bx, acc[1][nt], 0, 0, 0);
        }
    }

#pragma unroll
    for (int mt = 0; mt < 2; mt++)
#pragma unroll
        for (int nt = 0; nt < 8; nt++)
#pragma unroll
            for (int reg = 0; reg < 4; reg++) {
                int kk = kb + mt * 16 + quad * 4 + reg;
                int cc = nt * 16 + r16;
                dst[(size_t)kk * 128 + cc] = acc[mt][nt][reg];
            }
}

// ------------- stage 2 + coefficients (512 thr, 4-way pb-split): ys_t[b][c][k] bf16 -------------
__global__ __launch_bounds__(512) void spec_stage2_coef_kern(
    const float* __restrict__ partials, const float* __restrict__ evals,
    const float* __restrict__ dt, u16* __restrict__ ys_t)
{
    __shared__ float red[4][128];
    int b = blockIdx.x >> 7;
    int k = blockIdx.x & 127;
    int c = threadIdx.x & 127;
    int g = threadIdx.x >> 7;   // 0..3
    const float* p = partials + (size_t)b * 128 * 16384 + (size_t)k * 128 + c;
    float s = 0.f;
#pragma unroll 8
    for (int pb = g; pb < 128; pb += 4) s += p[(size_t)pb * 16384];
    red[g][c] = s;
    __syncthreads();
    if (g == 0) {
        float tot = (red[0][c] + red[1][c]) + (red[2][c] + red[3][c]);
        float co = expf(-evals[b * 128 + k] * dt[c]);
        ys_t[((size_t)b * 128 + c) * 128 + k] = f2b(tot * co);
    }
}

// ------------- MFMA GEMM: out[m,0:128] = A[m,:KK] @ W (bf16 out); AF32 path for evecs ------
template <int KK, bool AF32>
__global__ __launch_bounds__(256) void mgemm_kern(
    const void* __restrict__ A0v,
    const u16* __restrict__ Wp, u16* __restrict__ outp,
    size_t aBatch, size_t wBatch, size_t oBatch)
{
    __shared__ u16 sA[64][72];
    __shared__ u16 sB[128][72];
    int z = blockIdx.z;
    const u16* Wb = Wp + wBatch * (size_t)z;
    size_t aOff = aBatch * (size_t)z;
    size_t oOff = oBatch * (size_t)z;

    int t = threadIdx.x;
    int m0 = blockIdx.x * 64;
    int wv = t >> 6;
    int lane = t & 63;
    int quad = lane >> 4;
    int r16 = lane & 15;
    int mw = (wv & 1) * 32;
    int nw = (wv >> 1) * 64;

    f32x4 acc[2][4];
#pragma unroll
    for (int i = 0; i < 2; i++)
#pragma unroll
        for (int j = 0; j < 4; j++) acc[i][j] = (f32x4){0.f, 0.f, 0.f, 0.f};

#pragma unroll 1
    for (int kt = 0; kt < KK / 64; kt++) {
        int kbase = kt * 64;
        __syncthreads();
        if (AF32) {
            const float* Af = (const float*)A0v + aOff;
#pragma unroll
            for (int p = 0; p < 4; p++) {
                int idx = p * 256 + t;
                int row = idx >> 4;
                int seg = idx & 15;
                float4 v = *(const float4*)(Af + (size_t)(m0 + row) * 128 + kbase + seg * 4);
                ushort4 h;
                h.x = f2b(v.x); h.y = f2b(v.y); h.z = f2b(v.z); h.w = f2b(v.w);
                *(ushort4*)&sA[row][seg * 4] = h;
            }
        } else {
            const u16* Ah = (const u16*)A0v + aOff;
#pragma unroll
            for (int p = 0; p < 2; p++) {
                int idx = p * 256 + t;
                int row = idx >> 3;
                int seg = idx & 7;
                *(uint4*)&sA[row][seg * 8] =
                    *(const uint4*)(Ah + (size_t)(m0 + row) * 128 + kbase + seg * 8);
            }
        }
        {
#pragma unroll
            for (int p = 0; p < 4; p++) {
                int idx = p * 256 + t;
                int n = idx >> 3;
                int seg = idx & 7;
                *(uint4*)&sB[n][seg * 8] =
                    *(const uint4*)(Wb + (size_t)n * KK + kbase + seg * 8);
            }
        }
        __syncthreads();

#pragma unroll
        for (int ks = 0; ks < 2; ks++) {
            int ko = ks * 32 + quad * 8;
            bf16x8 a0 = *(const bf16x8*)&sA[mw + r16][ko];
            bf16x8 a1 = *(const bf16x8*)&sA[mw + 16 + r16][ko];
            bf16x8 b0 = *(const bf16x8*)&sB[nw + r16][ko];
            bf16x8 b1 = *(const bf16x8*)&sB[nw + 16 + r16][ko];
            bf16x8 b2 = *(const bf16x8*)&sB[nw + 32 + r16][ko];
            bf16x8 b3 = *(const bf16x8*)&sB[nw + 48 + r16][ko];
            acc[0][0] = __builtin_amdgcn_mfma_f32_16x16x32_bf16(a0, b0, acc[0][0], 0, 0, 0);
            acc[0][1] = __builtin_amdgcn_mfma_f32_16x16x32_bf16(a0, b1, acc[0][1], 0, 0, 0);
            acc[0][2] = __builtin_amdgcn_mfma_f32_16x16x32_bf16(a0, b2, acc[0][2], 0, 0, 0);
            acc[0][3] = __builtin_amdgcn_mfma_f32_16x16x32_bf16(a0, b3, acc[0][3], 0, 0, 0);
            acc[1][0] = __builtin_amdgcn_mfma_f32_16x16x32_bf16(a1, b0, acc[1][0], 0, 0, 0);
            acc[1][1] = __builtin_amdgcn_mfma_f32_16x16x32_bf16(a1, b1, acc[1][1], 0, 0, 0);
            acc[1][2] = __builtin_amdgcn_mfma_f32_16x16x32_bf16(a1, b2, acc[1][2], 0, 0, 0);
            acc[1][3] = __builtin_amdgcn_mfma_f32_16x16x32_bf16(a1, b3, acc[1][3], 0, 0, 0);
        }
    }

#pragma unroll
    for (int nt = 0; nt < 4; nt++) {
        int col = nw + nt * 16 + r16;
#pragma unroll
        for (int mt = 0; mt < 2; mt++) {
#pragma unroll
            for (int reg = 0; reg < 4; reg++) {
                int row = m0 + mw + mt * 16 + quad * 4 + reg;
                outp[oOff + (size_t)row * 128 + col] = f2b(acc[mt][nt][reg]);
            }
        }
    }
}

// ------------- FUSED rotation + tanh + 3-layer MiniMLP (512 threads, reg-prefetch staging) -------------
// Same barrier skeleton as the 1214-us version; all staging global loads issued one phase early
// into registers so L2 latency hides under the previous phase's MFMA.
__global__ __launch_bounds__(512) void mlp_rot_fused_kern(
    const u16* __restrict__ xg, const u16* __restrict__ xdg,
    const u16* __restrict__ gXY0, const u16* __restrict__ gXY1,
    const u16* __restrict__ WR1, const u16* __restrict__ WR2,
    const u16* __restrict__ W0, const u16* __restrict__ W1, const u16* __restrict__ W2,
    const float* __restrict__ b0, const float* __restrict__ b1, const float* __restrict__ b2,
    u16* __restrict__ outp)
{
    __shared__ u16 sGX[64][136];
    __shared__ u16 sGY[64][136];
    __shared__ u16 sB[128][72];
    __shared__ __align__(16) u16 sHbuf[9728];   // WR2 chunk view, then h1/h2 view
    __shared__ u16 sA[64][72];
#define HV(r, c) sHbuf[(r) * 152 + (c)]
#define WV(n, c) sHbuf[(n) * 72 + (c)]

    const size_t NZ = (size_t)N_ * 128;
    int z = blockIdx.z;                  // = batch
    const u16* gX = (z < 2) ? (gXY0 + (size_t)z * 2 * NZ) : (gXY1 + (size_t)(z - 2) * 2 * NZ);
    const u16* gY = gX + NZ;
    int m0n = blockIdx.x * 64;
    size_t growBase = ((size_t)z * N_ + m0n) * 128;

    int t = threadIdx.x;
    int wv = t >> 6;                     // 0..7
    int lane = t & 63;
    int quad = lane >> 4;
    int r16 = lane & 15;
    int mw = (wv & 1) * 32;              // 0 or 32
    int nw = (wv >> 1) * 32;             // 0,32,64,96

    // staging thread mapping: each thread owns rows n8 and n8+64, 8 u16 at sg8
    int n8 = t >> 3;                     // 0..63
    int sg8 = (t & 7) * 8;               // 0..56

    // ---- prefetch rotation chunk 0 weights into registers ----
    const u16* w1base  = WR1 + (size_t)n8 * 256 + sg8;
    const u16* w1base2 = WR1 + (size_t)(n8 + 64) * 256 + sg8;
    const u16* w2base  = WR2 + (size_t)n8 * 256 + sg8;
    const u16* w2base2 = WR2 + (size_t)(n8 + 64) * 256 + sg8;
    uint4 r1a = *(const uint4*)(w1base);
    uint4 r1b = *(const uint4*)(w1base2);
    uint4 r2a = *(const uint4*)(w2base);
    uint4 r2b = *(const uint4*)(w2base2);

    // ---- stage gX, gY tiles ----
#pragma unroll
    for (int p = 0; p < 2; p++) {
        int idx = p * 512 + t;
        int row = idx >> 4;
        int seg = idx & 15;
        *(uint4*)&sGX[row][seg * 8] = *(const uint4*)(gX + (size_t)(m0n + row) * 128 + seg * 8);
        *(uint4*)&sGY[row][seg * 8] = *(const uint4*)(gY + (size_t)(m0n + row) * 128 + seg * 8);
    }

    f32x4 accRe[2][2], accIm[2][2];
#pragma unroll
    for (int i = 0; i < 2; i++)
#pragma unroll
        for (int j = 0; j < 2; j++) {
            accRe[i][j] = (f32x4){0.f, 0.f, 0.f, 0.f};
            accIm[i][j] = (f32x4){0.f, 0.f, 0.f, 0.f};
        }

    // ---- rotation: 4 x 64-k chunks; write staged regs, prefetch next chunk ----
#pragma unroll 1
    for (int c = 0; c < 4; c++) {
        __syncthreads();   // c=0: covers sGX/sGY staging; else: prev-chunk consumers done
        *(uint4*)&sB[n8][sg8]      = r1a;
        *(uint4*)&sB[n8 + 64][sg8] = r1b;
        *(uint4*)&WV(n8, sg8)      = r2a;
        *(uint4*)&WV(n8 + 64, sg8) = r2b;
        if (c < 3) {
            r1a = *(const uint4*)(w1base  + (c + 1) * 64);
            r1b = *(const uint4*)(w1base2 + (c + 1) * 64);
            r2a = *(const uint4*)(w2base  + (c + 1) * 64);
            r2b = *(const uint4*)(w2base2 + (c + 1) * 64);
        }
        __syncthreads();

        const u16 (*sRe)[136] = (c < 2) ? sGX : sGY;
        const u16 (*sIm)[136] = (c < 2) ? sGY : sGX;
        int kob = (c & 1) * 64;
#pragma unroll
        for (int ks = 0; ks < 2; ks++) {
            int ko = kob + ks * 32 + quad * 8;
            int kb = ks * 32 + quad * 8;
            bf16x8 aRe0 = *(const bf16x8*)&sRe[mw + r16][ko];
            bf16x8 aRe1 = *(const bf16x8*)&sRe[mw + 16 + r16][ko];
            bf16x8 aIm0 = *(const bf16x8*)&sIm[mw + r16][ko];
            bf16x8 aIm1 = *(const bf16x8*)&sIm[mw + 16 + r16][ko];
#pragma unroll
            for (int j = 0; j < 2; j++) {
                bf16x8 w1f = *(const bf16x8*)&sB[nw + 16 * j + r16][kb];
                bf16x8 w2f = *(const bf16x8*)&WV(nw + 16 * j + r16, kb);
                accRe[0][j] = __builtin_amdgcn_mfma_f32_16x16x32_bf16(aRe0, w1f, accRe[0][j], 0, 0, 0);
                accRe[1][j] = __builtin_amdgcn_mfma_f32_16x16x32_bf16(aRe1, w1f, accRe[1][j], 0, 0, 0);
                accIm[0][j] = __builtin_amdgcn_mfma_f32_16x16x32_bf16(aIm0, w2f, accIm[0][j], 0, 0, 0);
                accIm[1][j] = __builtin_amdgcn_mfma_f32_16x16x32_bf16(aIm1, w2f, accIm[1][j], 0, 0, 0);
            }
        }
    }

    // ---- prefetch W0 kt=0 + x kt=0 (in flight across tanh phase) ----
    const u16* w0base  = W0 + (size_t)n8 * 384 + sg8;
    const u16* w0base2 = W0 + (size_t)(n8 + 64) * 384 + sg8;
    const u16* xbase  = xg  + growBase + (size_t)n8 * 128 + sg8;
    const u16* xdbase = xdg + growBase + (size_t)n8 * 128 + sg8;
    uint4 rB0 = *(const uint4*)(w0base);
    uint4 rB1 = *(const uint4*)(w0base2);
    uint4 rA  = *(const uint4*)(xbase);

    // ---- tanh in place: gf -> sGX (each element owned by exactly one lane) ----
    __syncthreads();   // all fragment reads of sGX/sGY complete
#pragma unroll
    for (int nt = 0; nt < 2; nt++) {
        int col = nw + nt * 16 + r16;
#pragma unroll
        for (int mt = 0; mt < 2; mt++)
#pragma unroll
            for (int reg = 0; reg < 4; reg++) {
                int lrow = mw + mt * 16 + quad * 4 + reg;
                float gx = b2f(sGX[lrow][col]);
                float gy = b2f(sGY[lrow][col]);
                float v = fast_tanh(gx * accRe[mt][nt][reg] + gy * accIm[mt][nt][reg]);
                sGX[lrow][col] = f2b(v);
            }
    }

    // ---- MLP stage 0: K=384 over concat(x, xd, gf-from-LDS), reg-prefetched staging ----
    f32x4 acc[2][2];
#pragma unroll
    for (int i = 0; i < 2; i++)
#pragma unroll
        for (int j = 0; j < 2; j++) acc[i][j] = (f32x4){0.f, 0.f, 0.f, 0.f};
#pragma unroll 1
    for (int kt = 0; kt < 6; kt++) {
        int kloc = (kt * 64) & 127;
        __syncthreads();   // kt=0 covers tanh writes; else prev-chunk consumers done
        if (kt < 4) *(uint4*)&sA[n8][sg8] = rA;
        *(uint4*)&sB[n8][sg8]      = rB0;
        *(uint4*)&sB[n8 + 64][sg8] = rB1;
        if (kt < 5) {
            rB0 = *(const uint4*)(w0base  + (kt + 1) * 64);
            rB1 = *(const uint4*)(w0base2 + (kt + 1) * 64);
        } else {
            rB0 = *(const uint4*)(W1 + (size_t)n8 * 128 + sg8);          // W1 chunk 0
            rB1 = *(const uint4*)(W1 + (size_t)(n8 + 64) * 128 + sg8);
        }
        if (kt < 3) {
            const u16* nbp = (kt + 1 < 2) ? xbase : xdbase;
            rA = *(const uint4*)(nbp + (((kt + 1) * 64) & 127));
        }
        __syncthreads();
#pragma unroll
        for (int ks = 0; ks < 2; ks++) {
            int ko = ks * 32 + quad * 8;
            bf16x8 a0, a1;
            if (kt < 4) {
                a0 = *(const bf16x8*)&sA[mw + r16][ko];
                a1 = *(const bf16x8*)&sA[mw + 16 + r16][ko];
            } else {
                a0 = *(const bf16x8*)&sGX[mw + r16][kloc + ko];
                a1 = *(const bf16x8*)&sGX[mw + 16 + r16][kloc + ko];
            }
#pragma unroll
            for (int j = 0; j < 2; j++) {
                bf16x8 bj = *(const bf16x8*)&sB[nw + 16 * j + r16][ko];
                acc[0][j] = __builtin_amdgcn_mfma_f32_16x16x32_bf16(a0, bj, acc[0][j], 0, 0, 0);
                acc[1][j] = __builtin_amdgcn_mfma_f32_16x16x32_bf16(a1, bj, acc[1][j], 0, 0, 0);
            }
        }
    }
    // h1 -> sHbuf (bias + relu + bf16); WR2 chunks fully consumed
    __syncthreads();
#pragma unroll
    for (int nt = 0; nt < 2; nt++) {
        int col = nw + nt * 16 + r16;
        float bv = b0[col];
#pragma unroll
        for (int mt = 0; mt < 2; mt++)
#pragma unroll
            for (int reg = 0; reg < 4; reg++) {
                int rl = mw + mt * 16 + quad * 4 + reg;
                HV(rl, col) = f2b(fmaxf(acc[mt][nt][reg] + bv, 0.f));
            }
    }

    // ---- stage 1: h2 = relu(h1 @ W1 + b1), reg-prefetched W1/W2 ----
#pragma unroll
    for (int i = 0; i < 2; i++)
#pragma unroll
        for (int j = 0; j < 2; j++) acc[i][j] = (f32x4){0.f, 0.f, 0.f, 0.f};
#pragma unroll 1
    for (int kt = 0; kt < 2; kt++) {
        __syncthreads();   // kt=0 covers h1 writes
        *(uint4*)&sB[n8][sg8]      = rB0;
        *(uint4*)&sB[n8 + 64][sg8] = rB1;
        if (kt == 0) {
            rB0 = *(const uint4*)(W1 + (size_t)n8 * 128 + 64 + sg8);     // W1 chunk 1
            rB1 = *(const uint4*)(W1 + (size_t)(n8 + 64) * 128 + 64 + sg8);
        } else {
            rB0 = *(const uint4*)(W2 + (size_t)n8 * 128 + sg8);          // W2 chunk 0
            rB1 = *(const uint4*)(W2 + (size_t)(n8 + 64) * 128 + sg8);
        }
        __syncthreads();
#pragma unroll
        for (int ks = 0; ks < 2; ks++) {
            int ko = kt * 64 + ks * 32 + quad * 8;
            int kb = ks * 32 + quad * 8;
            bf16x8 a0 = *(const bf16x8*)&HV(mw + r16, ko);
            bf16x8 a1 = *(const bf16x8*)&HV(mw + 16 + r16, ko);
#pragma unroll
            for (int j = 0; j < 2; j++) {
                bf16x8 bj = *(const bf16x8*)&sB[nw + 16 * j + r16][kb];
                acc[0][j] = __builtin_amdgcn_mfma_f32_16x16x32_bf16(a0, bj, acc[0][j], 0, 0, 0);
                acc[1][j] = __builtin_amdgcn_mfma_f32_16x16x32_bf16(a1, bj, acc[1][j], 0, 0, 0);
            }
        }
    }
    __syncthreads();   // all waves done reading h1
#pragma unroll
    for (int nt = 0; nt < 2; nt++) {
        int col = nw + nt * 16 + r16;
        float bv = b1[col];
#pragma unroll
        for (int mt = 0; mt < 2; mt++)
#pragma unroll
            for (int reg = 0; reg < 4; reg++) {
                int rl = mw + mt * 16 + quad * 4 + reg;
                HV(rl, col) = f2b(fmaxf(acc[mt][nt][reg] + bv, 0.f));
            }
    }

    // ---- stage 2: out = h2 @ W2 + b2 + resid(x) ----
#pragma unroll
    for (int i = 0; i < 2; i++)
#pragma unroll
        for (int j = 0; j < 2; j++) acc[i][j] = (f32x4){0.f, 0.f, 0.f, 0.f};
#pragma unroll 1
    for (int kt = 0; kt < 2; kt++) {
        __syncthreads();   // kt=0 covers h2 writes
        *(uint4*)&sB[n8][sg8]      = rB0;
        *(uint4*)&sB[n8 + 64][sg8] = rB1;
        if (kt == 0) {
            rB0 = *(const uint4*)(W2 + (size_t)n8 * 128 + 64 + sg8);     // W2 chunk 1
            rB1 = *(const uint4*)(W2 + (size_t)(n8 + 64) * 128 + 64 + sg8);
        }
        __syncthreads();
#pragma unroll
        for (int ks = 0; ks < 2; ks++) {
            int ko = kt * 64 + ks * 32 + quad * 8;
            int kb = ks * 32 + quad * 8;
            bf16x8 a0 = *(const bf16x8*)&HV(mw + r16, ko);
            bf16x8 a1 = *(const bf16x8*)&HV(mw + 16 + r16, ko);
#pragma unroll
            for (int j = 0; j < 2; j++) {
                bf16x8 bj = *(const bf16x8*)&sB[nw + 16 * j + r16][kb];
                acc[0][j] = __builtin_amdgcn_mfma_f32_16x16x32_bf16(a0, bj, acc[0][j], 0, 0, 0);
                acc[1][j] = __builtin_amdgcn_mfma_f32_16x16x32_bf16(a1, bj, acc[1][j], 0, 0, 0);
            }
        }
    }
#pragma unroll
    for (int nt = 0; nt < 2; nt++) {
        int col = nw + nt * 16 + r16;
        float bv = b2[col];
#pragma unroll
        for (int mt = 0; mt < 2; mt++)
#pragma unroll
            for (int reg = 0; reg < 4; reg++) {
                int row = mw + mt * 16 + quad * 4 + reg;
                float v = acc[mt][nt][reg] + bv + b2f(xg[growBase + (size_t)row * 128 + col]);
                outp[growBase + (size_t)row * 128 + col] = f2b(v);
            }
    }
#undef HV
#undef WV
}

// ------------- last linear: out[m,0:3] = x[m,:] @ w_last + b_last -------------
__global__ __launch_bounds__(256) void last_linear_kern(
    const u16* __restrict__ x, const float* __restrict__ w,
    const float* __restrict__ bias, float* __restrict__ outp, int M)
{
    __shared__ float sw[128 * 3];
    int t = threadIdx.x;
    for (int i = t; i < 384; i += 256) sw[i] = w[i];
    __syncthreads();
    int wave = t >> 6;
    int lane = t & 63;
    int row = blockIdx.x * 4 + wave;
    if (row >= M) return;
    const u16* xr = x + (size_t)row * 128;
    float p0 = 0.f, p1 = 0.f, p2 = 0.f;
#pragma unroll
    for (int h = 0; h < 2; h++) {
        int c = lane + h * 64;
        float xv = b2f(xr[c]);
        p0 += xv * sw[c * 3 + 0];
        p1 += xv * sw[c * 3 + 1];
        p2 += xv * sw[c * 3 + 2];
    }
#pragma unroll
    for (int off = 32; off > 0; off >>= 1) {
        p0 += __shfl_xor(p0, off);
        p1 += __shfl_xor(p1, off);
        p2 += __shfl_xor(p2, off);
    }
    if (lane == 0) {
        float* o = outp + (size_t)row * 3;
        o[0] = p0 + bias[0];
        o[1] = p1 + bias[1];
        o[2] = p2 + bias[2];
    }
}

extern "C" void kernel_launch(void* const* d_in, const int* in_sizes, int n_in,
                              void* d_out, int out_size, void* d_ws, size_t ws_size,
                              hipStream_t stream)
{
    const float* x_in    = (const float*)d_in[0];
    const float* mass    = (const float*)d_in[1];
    const float* evals   = (const float*)d_in[2];
    const float* evecs   = (const float*)d_in[3];
    const int*   rows    = (const int*)  d_in[4];
    const int*   cols    = (const int*)  d_in[5];
    const float* gvx     = (const float*)d_in[6];
    const float* gvy     = (const float*)d_in[7];
    const float* w_first = (const float*)d_in[8];
    const float* b_first = (const float*)d_in[9];
    const float* dtimes  = (const float*)d_in[10];
    const float* A_re    = (const float*)d_in[11];
    const float* A_im    = (const float*)d_in[12];
    const float* w0      = (const float*)d_in[13];
    const float* b0      = (const float*)d_in[14];
    const float* w1      = (const float*)d_in[15];
    const float* b1      = (const float*)d_in[16];
    const float* w2      = (const float*)d_in[17];
    const float* b2      = (const float*)d_in[18];
    const float* w_last  = (const float*)d_in[19];
    const float* b_last  = (const float*)d_in[20];
    float* outp = (float*)d_out;

    const size_t SZ = (size_t)B_ * N_ * 128;   // 20,480,000 elements
    const size_t NZ = (size_t)N_ * 128;        //  5,120,000 elements

    // workspace layout (~174 MB)
    u16* P0 = (u16*)d_ws;                      // 41 MB  (x ping-pong)
    u16* P1 = P0 + SZ;                         // 41 MB  (xd ping-pong)
    u16* GF = P1 + SZ;                         // 41 MB  (gX/gY slots 0-1)
    float* SC = (float*)(GF + SZ);             // 41 MB  partials / gX/gY slots 2-3 (disjoint lifetimes)
    u16* ys_t = (u16*)(SC + 8388608);          // 128 KB in SC tail (dead before spmm writes slots 2-3)
    u16* WP0 = (u16*)(SC + 2 * NZ);            // packed transposed bf16 weights
    u16* WP1 = WP0 + 4 * 49152;
    u16* WP2 = WP1 + 4 * 16384;
    u16* WR1 = WP2 + 4 * 16384;                // 4 x [128][256] rotation packs
    u16* WR2 = WR1 + 4 * 32768;
    int* rowptr = (int*)(WR2 + 4 * 32768);     // N+1 (padded to 40004)
    int* nextp  = rowptr + 40004;              // N (histogram counts, then cursors)
    int* scols  = nextp + N_;                  // E sorted cols
    float* svx  = (float*)(scols + E_);        // [B][E] sorted vals
    float* svy  = svx + (size_t)B_ * E_;

    u16* x  = P0;
    u16* xd = P1;
    const int M = B_ * N_;                     // 160000

    // --- CSR build (pattern shared across blocks & X/Y) ---
    int* bTot  = (int*)SC;          // NB_SCAN block totals (transient, pre-loop)
    int* bOff  = bTot + 512;
    int* sperm = bTot + 1024;       // E edge permutation (transient, pre-loop)
    hipMemsetAsync(nextp, 0, N_ * sizeof(int), stream);
    hist_kern<<<dim3((E_ + 255) / 256), 256, 0, stream>>>(rows, nextp);
    scan1_kern<<<dim3(NB_SCAN), 256, 0, stream>>>(nextp, rowptr, bTot);
    scan2_kern<<<dim3(1), 256, 0, stream>>>(bTot, bOff, rowptr + N_);
    scan3_kern<<<dim3(NB_SCAN), 256, 0, stream>>>(rowptr, nextp, bOff);
    scatter_idx_kern<<<dim3((E_ + 255) / 256), 256, 0, stream>>>(
        rows, cols, nextp, scols, sperm);
    gather_vals_kern<<<dim3((E_ + 255) / 256), 256, 0, stream>>>(
        sperm, gvx, gvy, svx, svy);

    // --- weight packing (once per launch) ---
    pack_w_kern<<<dim3(192, 1, 4), 256, 0, stream>>>(w0, WP0, 384);
    pack_w_kern<<<dim3(64, 1, 4), 256, 0, stream>>>(w1, WP1, 128);
    pack_w_kern<<<dim3(64, 1, 4), 256, 0, stream>>>(w2, WP2, 128);
    pack_rot_kern<<<dim3(128, 1, 4), 256, 0, stream>>>(A_re, A_im, WR1, WR2);

    first_linear_kern<<<dim3(M * 16 / 256), 256, 0, stream>>>(x_in, w_first, b_first, x, M);

    // gX/gY slots: z<2 in GF, z>=2 in SC (partials/ys_t dead by the time spmm writes)
    u16* GXY0 = GF;
    u16* GXY1 = (u16*)SC;

    for (int i = 0; i < 4; i++) {
        // --- spectral diffusion ---
        spec_stage1_mfma_kern<<<dim3(128, B_), 256, 0, stream>>>(x, mass, evecs, SC);
        spec_stage2_coef_kern<<<dim3(B_ * 128), 512, 0, stream>>>(
            SC, evals, dtimes + (size_t)i * 128, ys_t);
        mgemm_kern<128, true><<<dim3(N_ / 64, 1, B_), 256, 0, stream>>>(
            evecs, ys_t, xd, NZ, (size_t)128 * 128, NZ);
        // --- sparse gradients (all batches, one dispatch) ---
        spmm_csr_kern<<<dim3(N_ / 4, 1, B_), 256, 0, stream>>>(
            rowptr, scols, svx, svy, xd, GXY0, GXY1);
        // --- fused rotate+tanh+MLP+residual (all batches, one dispatch, 512 thr) ---
        mlp_rot_fused_kern<<<dim3(N_ / 64, 1, B_), 512, 0, stream>>>(
            x, xd, GXY0, GXY1,
            WR1 + (size_t)i * 32768, WR2 + (size_t)i * 32768,
            WP0 + (size_t)i * 49152, WP1 + (size_t)i * 16384, WP2 + (size_t)i * 16384,
            b0 + (size_t)i * 128, b1 + (size_t)i * 128, b2 + (size_t)i * 128,
            xd);
        u16* tmp = x; x = xd; xd = tmp;
    }

    last_linear_kern<<<dim3(M / 4), 256, 0, stream>>>(x, w_last, b_last, outp, M);
}

// Round 12
// 1136.638 us; speedup vs baseline: 1.4786x; 1.0318x over previous
//
#include <hip/hip_runtime.h>

#define B_ 4
#define N_ 40000
#define E_ 240000
#define NB_SCAN ((N_ + 255) / 256)   // 157 scan blocks

typedef unsigned short u16;
typedef unsigned int u32;
typedef __attribute__((ext_vector_type(8))) short bf16x8;
typedef __attribute__((ext_vector_type(4))) float f32x4;

__device__ __forceinline__ float b2f(u16 h) {
    u32 u = ((u32)h) << 16;
    return __uint_as_float(u);
}
__device__ __forceinline__ u16 f2b(float f) {
    u32 u = __float_as_uint(f);
    u32 r = (u + 0x7fffu + ((u >> 16) & 1u)) >> 16;
    return (u16)r;
}
// fast tanh: clamped exp form; abs err <= ~1e-6 (far below bf16 rounding)
__device__ __forceinline__ float fast_tanh(float x) {
    float cx = fminf(fmaxf(x, -9.f), 9.f);
    float e = __expf(2.f * cx);
    return (e - 1.f) / (e + 1.f);
}

// ---------------- first linear: x = x_in @ w_first + b_first (bf16 out, 8 c/thread) ----------------
__global__ __launch_bounds__(256) void first_linear_kern(
    const float* __restrict__ x_in, const float* __restrict__ w,
    const float* __restrict__ bias, u16* __restrict__ xout, int M)
{
    __shared__ float sw[6 * 128];
    __shared__ float sb[128];
    int t = threadIdx.x;
    for (int i = t; i < 768; i += 256) sw[i] = w[i];
    if (t < 128) sb[t] = bias[t];
    __syncthreads();
    int idx = blockIdx.x * 256 + t;   // = row*16 + cg
    int row = idx >> 4;
    int cg = (idx & 15) * 8;
    if (row >= M) return;
    const float* xr = x_in + (size_t)row * 6;
    float xv[6];
#pragma unroll
    for (int j = 0; j < 6; j++) xv[j] = xr[j];
    float acc[8];
#pragma unroll
    for (int i = 0; i < 8; i++) acc[i] = sb[cg + i];
#pragma unroll
    for (int j = 0; j < 6; j++)
#pragma unroll
        for (int i = 0; i < 8; i++) acc[i] += xv[j] * sw[j * 128 + cg + i];
    ushort4 h0, h1;
    h0.x = f2b(acc[0]); h0.y = f2b(acc[1]); h0.z = f2b(acc[2]); h0.w = f2b(acc[3]);
    h1.x = f2b(acc[4]); h1.y = f2b(acc[5]); h1.z = f2b(acc[6]); h1.w = f2b(acc[7]);
    uint4 pk;
    pk.x = (u32)h0.x | ((u32)h0.y << 16);
    pk.y = (u32)h0.z | ((u32)h0.w << 16);
    pk.z = (u32)h1.x | ((u32)h1.y << 16);
    pk.w = (u32)h1.z | ((u32)h1.w << 16);
    *(uint4*)(xout + (size_t)row * 128 + cg) = pk;
}

// ------------- weight pack: dst[n][k] = bf16(src[k][n]), per block i = blockIdx.z -------------
__global__ __launch_bounds__(256) void pack_w_kern(
    const float* __restrict__ src, u16* __restrict__ dst, int K)
{
    int i = blockIdx.z;
    src += (size_t)i * K * 128;
    dst += (size_t)i * K * 128;
    int idx = blockIdx.x * 256 + threadIdx.x;  // = n*K + k
    int n = idx / K;
    int k = idx % K;
    dst[idx] = f2b(src[(size_t)k * 128 + n]);
}

// ------------- rotation weight pack: WR1[n][k256] = [Are; -Aim]^T, WR2 = [Are; Aim]^T -------------
__global__ __launch_bounds__(256) void pack_rot_kern(
    const float* __restrict__ Are, const float* __restrict__ Aim,
    u16* __restrict__ WR1, u16* __restrict__ WR2)
{
    int i = blockIdx.z;
    const float* are = Are + (size_t)i * 16384;
    const float* aim = Aim + (size_t)i * 16384;
    int idx = blockIdx.x * 256 + threadIdx.x;  // 0..32767 = n*256 + k
    int n = idx >> 8;
    int k = idx & 255;
    float v1, v2;
    if (k < 128) { float a = are[(size_t)k * 128 + n]; v1 = a; v2 = a; }
    else         { float a = aim[(size_t)(k - 128) * 128 + n]; v1 = -a; v2 = a; }
    WR1[(size_t)i * 32768 + idx] = f2b(v1);
    WR2[(size_t)i * 32768 + idx] = f2b(v2);
}

// ------------- CSR build: histogram -> 3-phase parallel scan -> scatter idx -> gather vals -------------
__global__ __launch_bounds__(256) void hist_kern(const int* __restrict__ rows, int* count)
{
    int e = blockIdx.x * 256 + threadIdx.x;
    if (e < E_) atomicAdd(&count[rows[e]], 1);
}

// inclusive scan across a 256-thread block (4 waves, shfl-based)
__device__ __forceinline__ int block_incl_scan_256(int v, int t)
{
    __shared__ int wsum[4];
    int lane = t & 63;
    int wid = t >> 6;
    int x = v;
#pragma unroll
    for (int off = 1; off < 64; off <<= 1) {
        int y = __shfl_up(x, off);
        if (lane >= off) x += y;
    }
    if (lane == 63) wsum[wid] = x;
    __syncthreads();
    if (t == 0) {
        int s = 0;
#pragma unroll
        for (int i = 0; i < 4; i++) { int tm = wsum[i]; wsum[i] = s; s += tm; }
    }
    __syncthreads();
    return x + wsum[wid];
}

// phase 1: per-block exclusive scan of counts -> rowptr (partial), block totals
__global__ __launch_bounds__(256) void scan1_kern(
    const int* __restrict__ count, int* __restrict__ excl_out,
    int* __restrict__ blockTotals)
{
    int t = threadIdx.x;
    int g = blockIdx.x * 256 + t;
    int v = (g < N_) ? count[g] : 0;
    int incl = block_incl_scan_256(v, t);
    if (g < N_) excl_out[g] = incl - v;
    if (t == 255) blockTotals[blockIdx.x] = incl;
}

// phase 2: single-block scan of 157 block totals -> exclusive block offsets + grand total
__global__ __launch_bounds__(256) void scan2_kern(
    const int* __restrict__ blockTotals, int* __restrict__ blockOffs,
    int* __restrict__ totalOut)
{
    int t = threadIdx.x;
    int v = (t < NB_SCAN) ? blockTotals[t] : 0;
    int incl = block_incl_scan_256(v, t);
    if (t < NB_SCAN) blockOffs[t] = incl - v;
    if (t == 255) *totalOut = incl;   // = E_, written to rowptr[N_]
}

// phase 3: add block offsets; materialize rowptr + nextp cursors
__global__ __launch_bounds__(256) void scan3_kern(
    int* __restrict__ rowptr, int* __restrict__ nextp,
    const int* __restrict__ blockOffs)
{
    int t = threadIdx.x;
    int g = blockIdx.x * 256 + t;
    if (g >= N_) return;
    int v = rowptr[g] + blockOffs[blockIdx.x];
    rowptr[g] = v;
    nextp[g] = v;
}

// scatter only indices (2 scattered u32 writes per edge)
__global__ __launch_bounds__(256) void scatter_idx_kern(
    const int* __restrict__ rows, const int* __restrict__ cols,
    int* nextp, int* __restrict__ scols, int* __restrict__ sperm)
{
    int e = blockIdx.x * 256 + threadIdx.x;
    if (e >= E_) return;
    int r = rows[e];
    int pos = atomicAdd(&nextp[r], 1);
    scols[pos] = cols[e];
    sperm[pos] = e;
}

// gather values: coalesced writes, L2-cached random reads
__global__ __launch_bounds__(256) void gather_vals_kern(
    const int* __restrict__ sperm,
    const float* __restrict__ gvx, const float* __restrict__ gvy,
    float* __restrict__ svx, float* __restrict__ svy)
{
    int pos = blockIdx.x * 256 + threadIdx.x;
    if (pos >= E_) return;
    int e = sperm[pos];
#pragma unroll
    for (int b = 0; b < B_; b++) {
        svx[(size_t)b * E_ + pos] = gvx[(size_t)b * E_ + e];
        svy[(size_t)b * E_ + pos] = gvy[(size_t)b * E_ + e];
    }
}

// ------------- CSR dual spMM (all batches via z), bf16 packed out, edge-unrolled x4 -------------
__global__ __launch_bounds__(256) void spmm_csr_kern(
    const int* __restrict__ rowptr, const int* __restrict__ scols,
    const float* __restrict__ svx, const float* __restrict__ svy,
    const u16* __restrict__ xd, u16* __restrict__ gXY0, u16* __restrict__ gXY1)
{
    const size_t NZ = (size_t)N_ * 128;
    int z = blockIdx.z;
    const float* svx_b = svx + (size_t)z * E_;
    const float* svy_b = svy + (size_t)z * E_;
    const u16* xd_b = xd + (size_t)z * NZ;
    u16* base = (z < 2) ? (gXY0 + (size_t)z * 2 * NZ) : (gXY1 + (size_t)(z - 2) * 2 * NZ);
    u16* gXh = base;
    u16* gYh = base + NZ;

    int t = threadIdx.x;
    int r = blockIdx.x * 4 + (t >> 6);
    int c2 = (t & 63) * 2;
    int beg = rowptr[r], end = rowptr[r + 1];
    float ax0 = 0.f, ax1 = 0.f, ay0 = 0.f, ay1 = 0.f;
    int j = beg;
    for (; j + 3 < end; j += 4) {
        int ca = scols[j], cb = scols[j + 1], cc = scols[j + 2], cd = scols[j + 3];
        u32 xwa = *(const u32*)(xd_b + (size_t)ca * 128 + c2);
        u32 xwb = *(const u32*)(xd_b + (size_t)cb * 128 + c2);
        u32 xwc = *(const u32*)(xd_b + (size_t)cc * 128 + c2);
        u32 xwd = *(const u32*)(xd_b + (size_t)cd * 128 + c2);
        float vxa = svx_b[j],     vya = svy_b[j];
        float vxb = svx_b[j + 1], vyb = svy_b[j + 1];
        float vxc = svx_b[j + 2], vyc = svy_b[j + 2];
        float vxd = svx_b[j + 3], vyd = svy_b[j + 3];
        float xa0 = b2f((u16)(xwa & 0xffffu)), xa1 = b2f((u16)(xwa >> 16));
        float xb0 = b2f((u16)(xwb & 0xffffu)), xb1 = b2f((u16)(xwb >> 16));
        float xc0 = b2f((u16)(xwc & 0xffffu)), xc1 = b2f((u16)(xwc >> 16));
        float xd0 = b2f((u16)(xwd & 0xffffu)), xd1 = b2f((u16)(xwd >> 16));
        ax0 += vxa * xa0; ax1 += vxa * xa1;
        ay0 += vya * xa0; ay1 += vya * xa1;
        ax0 += vxb * xb0; ax1 += vxb * xb1;
        ay0 += vyb * xb0; ay1 += vyb * xb1;
        ax0 += vxc * xc0; ax1 += vxc * xc1;
        ay0 += vyc * xc0; ay1 += vyc * xc1;
        ax0 += vxd * xd0; ax1 += vxd * xd1;
        ay0 += vyd * xd0; ay1 += vyd * xd1;
    }
    for (; j < end; j++) {
        int col = scols[j];
        u32 xw = *(const u32*)(xd_b + (size_t)col * 128 + c2);
        float x0 = b2f((u16)(xw & 0xffffu));
        float x1 = b2f((u16)(xw >> 16));
        float vx = svx_b[j], vy = svy_b[j];
        ax0 += vx * x0; ax1 += vx * x1;
        ay0 += vy * x0; ay1 += vy * x1;
    }
    u32 px = (u32)f2b(ax0) | ((u32)f2b(ax1) << 16);
    u32 py = (u32)f2b(ay0) | ((u32)f2b(ay1) << 16);
    *(u32*)(gXh + (size_t)r * 128 + c2) = px;
    *(u32*)(gYh + (size_t)r * 128 + c2) = py;
}

// ------------- spectral projection stage 1: MFMA over transposed LDS tiles -------------
__global__ __launch_bounds__(256) void spec_stage1_mfma_kern(
    const u16* __restrict__ x, const float* __restrict__ mass,
    const float* __restrict__ evecs, float* __restrict__ partials)
{
    __shared__ __align__(16) u16 sEVh[128][40];
    __shared__ __align__(16) u16 sEVl[128][40];
    __shared__ __align__(16) u16 sXM[128][40];
    int b = blockIdx.y;
    int pb = blockIdx.x;
    const u16* xb = x + (size_t)b * N_ * 128;
    const float* mb = mass + (size_t)b * N_;
    const float* eb = evecs + (size_t)b * N_ * 128;
    float* dst = partials + ((size_t)b * 128 + pb) * 16384;

    int t = threadIdx.x;
    int wv = t >> 6;
    int lane = t & 63;
    int quad = lane >> 4;
    int r16 = lane & 15;
    int kb = wv * 32;
    int kc = (t & 63) * 2;
    int nh = wv;

    f32x4 acc[2][8];
#pragma unroll
    for (int i = 0; i < 2; i++)
#pragma unroll
        for (int j = 0; j < 8; j++) acc[i][j] = (f32x4){0.f, 0.f, 0.f, 0.f};

    for (int ch = pb; ch < N_ / 32; ch += 128) {
        int nbase = ch * 32 + nh * 8;
        float4 m0 = *(const float4*)(mb + nbase);
        float4 m1 = *(const float4*)(mb + nbase + 4);
        float mm[8] = {m0.x, m0.y, m0.z, m0.w, m1.x, m1.y, m1.z, m1.w};
        u32 eh0[4], eh1[4], el0[4], el1[4], xq0[4], xq1[4];
#pragma unroll
        for (int jp = 0; jp < 4; jp++) {
            eh0[jp] = 0; eh1[jp] = 0; el0[jp] = 0;
            el1[jp] = 0; xq0[jp] = 0; xq1[jp] = 0;
        }
#pragma unroll
        for (int j = 0; j < 8; j++) {
            float2 e = *(const float2*)(eb + (size_t)(nbase + j) * 128 + kc);
            u32 xw = *(const u32*)(xb + (size_t)(nbase + j) * 128 + kc);
            u16 h0 = f2b(e.x);
            u16 h1 = f2b(e.y);
            u16 l0 = f2b(e.x - b2f(h0));
            u16 l1 = f2b(e.y - b2f(h1));
            u16 q0 = f2b(b2f((u16)(xw & 0xffffu)) * mm[j]);
            u16 q1 = f2b(b2f((u16)(xw >> 16)) * mm[j]);
            int sh = (j & 1) * 16;
            int jp = j >> 1;
            eh0[jp] |= ((u32)h0) << sh; eh1[jp] |= ((u32)h1) << sh;
            el0[jp] |= ((u32)l0) << sh; el1[jp] |= ((u32)l1) << sh;
            xq0[jp] |= ((u32)q0) << sh; xq1[jp] |= ((u32)q1) << sh;
        }
        __syncthreads();
        *(uint4*)&sEVh[kc][nh * 8]     = make_uint4(eh0[0], eh0[1], eh0[2], eh0[3]);
        *(uint4*)&sEVh[kc + 1][nh * 8] = make_uint4(eh1[0], eh1[1], eh1[2], eh1[3]);
        *(uint4*)&sEVl[kc][nh * 8]     = make_uint4(el0[0], el0[1], el0[2], el0[3]);
        *(uint4*)&sEVl[kc + 1][nh * 8] = make_uint4(el1[0], el1[1], el1[2], el1[3]);
        *(uint4*)&sXM[kc][nh * 8]      = make_uint4(xq0[0], xq0[1], xq0[2], xq0[3]);
        *(uint4*)&sXM[kc + 1][nh * 8]  = make_uint4(xq1[0], xq1[1], xq1[2], xq1[3]);
        __syncthreads();

        bf16x8 ah0 = *(const bf16x8*)&sEVh[kb + r16][quad * 8];
        bf16x8 ah1 = *(const bf16x8*)&sEVh[kb + 16 + r16][quad * 8];
        bf16x8 al0 = *(const bf16x8*)&sEVl[kb + r16][quad * 8];
        bf16x8 al1 = *(const bf16x8*)&sEVl[kb + 16 + r16][quad * 8];
        __builtin_amdgcn_s_setprio(1);
#pragma unroll
        for (int nt = 0; nt < 8; nt++) {
            bf16x8 bx = *(const bf16x8*)&sXM[nt * 16 + r16][quad * 8];
            acc[0][nt] = __builtin_amdgcn_mfma_f32_16x16x32_bf16(ah0, bx, acc[0][nt], 0, 0, 0);
            acc[1][nt] = __builtin_amdgcn_mfma_f32_16x16x32_bf16(ah1, bx, acc[1][nt], 0, 0, 0);
            acc[0][nt] = __builtin_amdgcn_mfma_f32_16x16x32_bf16(al0, bx, acc[0][nt], 0, 0, 0);
            acc[1][nt] = __builtin_amdgcn_mfma_f32_16x16x32_bf16(al1, bx, acc[1][nt], 0, 0, 0);
        }
        __builtin_amdgcn_s_setprio(0);
    }

#pragma unroll
    for (int mt = 0; mt < 2; mt++)
#pragma unroll
        for (int nt = 0; nt < 8; nt++)
#pragma unroll
            for (int reg = 0; reg < 4; reg++) {
                int kk = kb + mt * 16 + quad * 4 + reg;
                int cc = nt * 16 + r16;
                dst[(size_t)kk * 128 + cc] = acc[mt][nt][reg];
            }
}

// ------------- stage 2 + coefficients (512 thr, 4-way pb-split): ys_t[b][c][k] bf16 -------------
__global__ __launch_bounds__(512) void spec_stage2_coef_kern(
    const float* __restrict__ partials, const float* __restrict__ evals,
    const float* __restrict__ dt, u16* __restrict__ ys_t)
{
    __shared__ float red[4][128];
    int b = blockIdx.x >> 7;
    int k = blockIdx.x & 127;
    int c = threadIdx.x & 127;
    int g = threadIdx.x >> 7;   // 0..3
    const float* p = partials + (size_t)b * 128 * 16384 + (size_t)k * 128 + c;
    float s = 0.f;
#pragma unroll 8
    for (int pb = g; pb < 128; pb += 4) s += p[(size_t)pb * 16384];
    red[g][c] = s;
    __syncthreads();
    if (g == 0) {
        float tot = (red[0][c] + red[1][c]) + (red[2][c] + red[3][c]);
        float co = expf(-evals[b * 128 + k] * dt[c]);
        ys_t[((size_t)b * 128 + c) * 128 + k] = f2b(tot * co);
    }
}

// ------------- MFMA GEMM: out[m,0:128] = A[m,:KK] @ W (bf16 out); AF32 path for evecs ------
template <int KK, bool AF32>
__global__ __launch_bounds__(256) void mgemm_kern(
    const void* __restrict__ A0v,
    const u16* __restrict__ Wp, u16* __restrict__ outp,
    size_t aBatch, size_t wBatch, size_t oBatch)
{
    __shared__ u16 sA[64][72];
    __shared__ u16 sB[128][72];
    int z = blockIdx.z;
    const u16* Wb = Wp + wBatch * (size_t)z;
    size_t aOff = aBatch * (size_t)z;
    size_t oOff = oBatch * (size_t)z;

    int t = threadIdx.x;
    int m0 = blockIdx.x * 64;
    int wv = t >> 6;
    int lane = t & 63;
    int quad = lane >> 4;
    int r16 = lane & 15;
    int mw = (wv & 1) * 32;
    int nw = (wv >> 1) * 64;

    f32x4 acc[2][4];
#pragma unroll
    for (int i = 0; i < 2; i++)
#pragma unroll
        for (int j = 0; j < 4; j++) acc[i][j] = (f32x4){0.f, 0.f, 0.f, 0.f};

#pragma unroll 1
    for (int kt = 0; kt < KK / 64; kt++) {
        int kbase = kt * 64;
        __syncthreads();
        if (AF32) {
            const float* Af = (const float*)A0v + aOff;
#pragma unroll
            for (int p = 0; p < 4; p++) {
                int idx = p * 256 + t;
                int row = idx >> 4;
                int seg = idx & 15;
                float4 v = *(const float4*)(Af + (size_t)(m0 + row) * 128 + kbase + seg * 4);
                ushort4 h;
                h.x = f2b(v.x); h.y = f2b(v.y); h.z = f2b(v.z); h.w = f2b(v.w);
                *(ushort4*)&sA[row][seg * 4] = h;
            }
        } else {
            const u16* Ah = (const u16*)A0v + aOff;
#pragma unroll
            for (int p = 0; p < 2; p++) {
                int idx = p * 256 + t;
                int row = idx >> 3;
                int seg = idx & 7;
                *(uint4*)&sA[row][seg * 8] =
                    *(const uint4*)(Ah + (size_t)(m0 + row) * 128 + kbase + seg * 8);
            }
        }
        {
#pragma unroll
            for (int p = 0; p < 4; p++) {
                int idx = p * 256 + t;
                int n = idx >> 3;
                int seg = idx & 7;
                *(uint4*)&sB[n][seg * 8] =
                    *(const uint4*)(Wb + (size_t)n * KK + kbase + seg * 8);
            }
        }
        __syncthreads();

        __builtin_amdgcn_s_setprio(1);
#pragma unroll
        for (int ks = 0; ks < 2; ks++) {
            int ko = ks * 32 + quad * 8;
            bf16x8 a0 = *(const bf16x8*)&sA[mw + r16][ko];
            bf16x8 a1 = *(const bf16x8*)&sA[mw + 16 + r16][ko];
            bf16x8 b0 = *(const bf16x8*)&sB[nw + r16][ko];
            bf16x8 b1 = *(const bf16x8*)&sB[nw + 16 + r16][ko];
            bf16x8 b2 = *(const bf16x8*)&sB[nw + 32 + r16][ko];
            bf16x8 b3 = *(const bf16x8*)&sB[nw + 48 + r16][ko];
            acc[0][0] = __builtin_amdgcn_mfma_f32_16x16x32_bf16(a0, b0, acc[0][0], 0, 0, 0);
            acc[0][1] = __builtin_amdgcn_mfma_f32_16x16x32_bf16(a0, b1, acc[0][1], 0, 0, 0);
            acc[0][2] = __builtin_amdgcn_mfma_f32_16x16x32_bf16(a0, b2, acc[0][2], 0, 0, 0);
            acc[0][3] = __builtin_amdgcn_mfma_f32_16x16x32_bf16(a0, b3, acc[0][3], 0, 0, 0);
            acc[1][0] = __builtin_amdgcn_mfma_f32_16x16x32_bf16(a1, b0, acc[1][0], 0, 0, 0);
            acc[1][1] = __builtin_amdgcn_mfma_f32_16x16x32_bf16(a1, b1, acc[1][1], 0, 0, 0);
            acc[1][2] = __builtin_amdgcn_mfma_f32_16x16x32_bf16(a1, b2, acc[1][2], 0, 0, 0);
            acc[1][3] = __builtin_amdgcn_mfma_f32_16x16x32_bf16(a1, b3, acc[1][3], 0, 0, 0);
        }
        __builtin_amdgcn_s_setprio(0);
    }

#pragma unroll
    for (int nt = 0; nt < 4; nt++) {
        int col = nw + nt * 16 + r16;
#pragma unroll
        for (int mt = 0; mt < 2; mt++) {
#pragma unroll
            for (int reg = 0; reg < 4; reg++) {
                int row = m0 + mw + mt * 16 + quad * 4 + reg;
                outp[oOff + (size_t)row * 128 + col] = f2b(acc[mt][nt][reg]);
            }
        }
    }
}

// ------------- FUSED rotation + tanh + 3-layer MiniMLP (512 threads, reg-prefetch + setprio) -------------
__global__ __launch_bounds__(512) void mlp_rot_fused_kern(
    const u16* __restrict__ xg, const u16* __restrict__ xdg,
    const u16* __restrict__ gXY0, const u16* __restrict__ gXY1,
    const u16* __restrict__ WR1, const u16* __restrict__ WR2,
    const u16* __restrict__ W0, const u16* __restrict__ W1, const u16* __restrict__ W2,
    const float* __restrict__ b0, const float* __restrict__ b1, const float* __restrict__ b2,
    u16* __restrict__ outp)
{
    __shared__ u16 sGX[64][136];
    __shared__ u16 sGY[64][136];
    __shared__ u16 sB[128][72];
    __shared__ __align__(16) u16 sHbuf[9728];   // WR2 chunk view, then h1/h2 view
    __shared__ u16 sA[64][72];
#define HV(r, c) sHbuf[(r) * 152 + (c)]
#define WV(n, c) sHbuf[(n) * 72 + (c)]

    const size_t NZ = (size_t)N_ * 128;
    int z = blockIdx.z;                  // = batch
    const u16* gX = (z < 2) ? (gXY0 + (size_t)z * 2 * NZ) : (gXY1 + (size_t)(z - 2) * 2 * NZ);
    const u16* gY = gX + NZ;
    int m0n = blockIdx.x * 64;
    size_t growBase = ((size_t)z * N_ + m0n) * 128;

    int t = threadIdx.x;
    int wv = t >> 6;                     // 0..7
    int lane = t & 63;
    int quad = lane >> 4;
    int r16 = lane & 15;
    int mw = (wv & 1) * 32;              // 0 or 32
    int nw = (wv >> 1) * 32;             // 0,32,64,96

    // staging thread mapping: each thread owns rows n8 and n8+64, 8 u16 at sg8
    int n8 = t >> 3;                     // 0..63
    int sg8 = (t & 7) * 8;               // 0..56

    // ---- prefetch rotation chunk 0 weights into registers ----
    const u16* w1base  = WR1 + (size_t)n8 * 256 + sg8;
    const u16* w1base2 = WR1 + (size_t)(n8 + 64) * 256 + sg8;
    const u16* w2base  = WR2 + (size_t)n8 * 256 + sg8;
    const u16* w2base2 = WR2 + (size_t)(n8 + 64) * 256 + sg8;
    uint4 r1a = *(const uint4*)(w1base);
    uint4 r1b = *(const uint4*)(w1base2);
    uint4 r2a = *(const uint4*)(w2base);
    uint4 r2b = *(const uint4*)(w2base2);

    // ---- stage gX, gY tiles ----
#pragma unroll
    for (int p = 0; p < 2; p++) {
        int idx = p * 512 + t;
        int row = idx >> 4;
        int seg = idx & 15;
        *(uint4*)&sGX[row][seg * 8] = *(const uint4*)(gX + (size_t)(m0n + row) * 128 + seg * 8);
        *(uint4*)&sGY[row][seg * 8] = *(const uint4*)(gY + (size_t)(m0n + row) * 128 + seg * 8);
    }

    f32x4 accRe[2][2], accIm[2][2];
#pragma unroll
    for (int i = 0; i < 2; i++)
#pragma unroll
        for (int j = 0; j < 2; j++) {
            accRe[i][j] = (f32x4){0.f, 0.f, 0.f, 0.f};
            accIm[i][j] = (f32x4){0.f, 0.f, 0.f, 0.f};
        }

    // ---- rotation: 4 x 64-k chunks; write staged regs, prefetch next chunk ----
#pragma unroll 1
    for (int c = 0; c < 4; c++) {
        __syncthreads();   // c=0: covers sGX/sGY staging; else: prev-chunk consumers done
        *(uint4*)&sB[n8][sg8]      = r1a;
        *(uint4*)&sB[n8 + 64][sg8] = r1b;
        *(uint4*)&WV(n8, sg8)      = r2a;
        *(uint4*)&WV(n8 + 64, sg8) = r2b;
        if (c < 3) {
            r1a = *(const uint4*)(w1base  + (c + 1) * 64);
            r1b = *(const uint4*)(w1base2 + (c + 1) * 64);
            r2a = *(const uint4*)(w2base  + (c + 1) * 64);
            r2b = *(const uint4*)(w2base2 + (c + 1) * 64);
        }
        __syncthreads();

        const u16 (*sRe)[136] = (c < 2) ? sGX : sGY;
        const u16 (*sIm)[136] = (c < 2) ? sGY : sGX;
        int kob = (c & 1) * 64;
        __builtin_amdgcn_s_setprio(1);
#pragma unroll
        for (int ks = 0; ks < 2; ks++) {
            int ko = kob + ks * 32 + quad * 8;
            int kb = ks * 32 + quad * 8;
            bf16x8 aRe0 = *(const bf16x8*)&sRe[mw + r16][ko];
            bf16x8 aRe1 = *(const bf16x8*)&sRe[mw + 16 + r16][ko];
            bf16x8 aIm0 = *(const bf16x8*)&sIm[mw + r16][ko];
            bf16x8 aIm1 = *(const bf16x8*)&sIm[mw + 16 + r16][ko];
#pragma unroll
            for (int j = 0; j < 2; j++) {
                bf16x8 w1f = *(const bf16x8*)&sB[nw + 16 * j + r16][kb];
                bf16x8 w2f = *(const bf16x8*)&WV(nw + 16 * j + r16, kb);
                accRe[0][j] = __builtin_amdgcn_mfma_f32_16x16x32_bf16(aRe0, w1f, accRe[0][j], 0, 0, 0);
                accRe[1][j] = __builtin_amdgcn_mfma_f32_16x16x32_bf16(aRe1, w1f, accRe[1][j], 0, 0, 0);
                accIm[0][j] = __builtin_amdgcn_mfma_f32_16x16x32_bf16(aIm0, w2f, accIm[0][j], 0, 0, 0);
                accIm[1][j] = __builtin_amdgcn_mfma_f32_16x16x32_bf16(aIm1, w2f, accIm[1][j], 0, 0, 0);
            }
        }
        __builtin_amdgcn_s_setprio(0);
    }

    // ---- prefetch W0 kt=0 + x kt=0 (in flight across tanh phase) ----
    const u16* w0base  = W0 + (size_t)n8 * 384 + sg8;
    const u16* w0base2 = W0 + (size_t)(n8 + 64) * 384 + sg8;
    const u16* xbase  = xg  + growBase + (size_t)n8 * 128 + sg8;
    const u16* xdbase = xdg + growBase + (size_t)n8 * 128 + sg8;
    uint4 rB0 = *(const uint4*)(w0base);
    uint4 rB1 = *(const uint4*)(w0base2);
    uint4 rA  = *(const uint4*)(xbase);

    // ---- tanh in place: gf -> sGX (each element owned by exactly one lane) ----
    __syncthreads();   // all fragment reads of sGX/sGY complete
#pragma unroll
    for (int nt = 0; nt < 2; nt++) {
        int col = nw + nt * 16 + r16;
#pragma unroll
        for (int mt = 0; mt < 2; mt++)
#pragma unroll
            for (int reg = 0; reg < 4; reg++) {
                int lrow = mw + mt * 16 + quad * 4 + reg;
                float gx = b2f(sGX[lrow][col]);
                float gy = b2f(sGY[lrow][col]);
                float v = fast_tanh(gx * accRe[mt][nt][reg] + gy * accIm[mt][nt][reg]);
                sGX[lrow][col] = f2b(v);
            }
    }

    // ---- MLP stage 0: K=384 over concat(x, xd, gf-from-LDS), reg-prefetched staging ----
    f32x4 acc[2][2];
#pragma unroll
    for (int i = 0; i < 2; i++)
#pragma unroll
        for (int j = 0; j < 2; j++) acc[i][j] = (f32x4){0.f, 0.f, 0.f, 0.f};
#pragma unroll 1
    for (int kt = 0; kt < 6; kt++) {
        int kloc = (kt * 64) & 127;
        __syncthreads();   // kt=0 covers tanh writes; else prev-chunk consumers done
        if (kt < 4) *(uint4*)&sA[n8][sg8] = rA;
        *(uint4*)&sB[n8][sg8]      = rB0;
        *(uint4*)&sB[n8 + 64][sg8] = rB1;
        if (kt < 5) {
            rB0 = *(const uint4*)(w0base  + (kt + 1) * 64);
            rB1 = *(const uint4*)(w0base2 + (kt + 1) * 64);
        } else {
            rB0 = *(const uint4*)(W1 + (size_t)n8 * 128 + sg8);          // W1 chunk 0
            rB1 = *(const uint4*)(W1 + (size_t)(n8 + 64) * 128 + sg8);
        }
        if (kt < 3) {
            const u16* nbp = (kt + 1 < 2) ? xbase : xdbase;
            rA = *(const uint4*)(nbp + (((kt + 1) * 64) & 127));
        }
        __syncthreads();
        __builtin_amdgcn_s_setprio(1);
#pragma unroll
        for (int ks = 0; ks < 2; ks++) {
            int ko = ks * 32 + quad * 8;
            bf16x8 a0, a1;
            if (kt < 4) {
                a0 = *(const bf16x8*)&sA[mw + r16][ko];
                a1 = *(const bf16x8*)&sA[mw + 16 + r16][ko];
            } else {
                a0 = *(const bf16x8*)&sGX[mw + r16][kloc + ko];
                a1 = *(const bf16x8*)&sGX[mw + 16 + r16][kloc + ko];
            }
#pragma unroll
            for (int j = 0; j < 2; j++) {
                bf16x8 bj = *(const bf16x8*)&sB[nw + 16 * j + r16][ko];
                acc[0][j] = __builtin_amdgcn_mfma_f32_16x16x32_bf16(a0, bj, acc[0][j], 0, 0, 0);
                acc[1][j] = __builtin_amdgcn_mfma_f32_16x16x32_bf16(a1, bj, acc[1][j], 0, 0, 0);
            }
        }
        __builtin_amdgcn_s_setprio(0);
    }
    // h1 -> sHbuf (bias + relu + bf16); WR2 chunks fully consumed
    __syncthreads();
#pragma unroll
    for (int nt = 0; nt < 2; nt++) {
        int col = nw + nt * 16 + r16;
        float bv = b0[col];
#pragma unroll
        for (int mt = 0; mt < 2; mt++)
#pragma unroll
            for (int reg = 0; reg < 4; reg++) {
                int rl = mw + mt * 16 + quad * 4 + reg;
                HV(rl, col) = f2b(fmaxf(acc[mt][nt][reg] + bv, 0.f));
            }
    }

    // ---- stage 1: h2 = relu(h1 @ W1 + b1), reg-prefetched W1/W2 ----
#pragma unroll
    for (int i = 0; i < 2; i++)
#pragma unroll
        for (int j = 0; j < 2; j++) acc[i][j] = (f32x4){0.f, 0.f, 0.f, 0.f};
#pragma unroll 1
    for (int kt = 0; kt < 2; kt++) {
        __syncthreads();   // kt=0 covers h1 writes
        *(uint4*)&sB[n8][sg8]      = rB0;
        *(uint4*)&sB[n8 + 64][sg8] = rB1;
        if (kt == 0) {
            rB0 = *(const uint4*)(W1 + (size_t)n8 * 128 + 64 + sg8);     // W1 chunk 1
            rB1 = *(const uint4*)(W1 + (size_t)(n8 + 64) * 128 + 64 + sg8);
        } else {
            rB0 = *(const uint4*)(W2 + (size_t)n8 * 128 + sg8);          // W2 chunk 0
            rB1 = *(const uint4*)(W2 + (size_t)(n8 + 64) * 128 + sg8);
        }
        __syncthreads();
        __builtin_amdgcn_s_setprio(1);
#pragma unroll
        for (int ks = 0; ks < 2; ks++) {
            int ko = kt * 64 + ks * 32 + quad * 8;
            int kb = ks * 32 + quad * 8;
            bf16x8 a0 = *(const bf16x8*)&HV(mw + r16, ko);
            bf16x8 a1 = *(const bf16x8*)&HV(mw + 16 + r16, ko);
#pragma unroll
            for (int j = 0; j < 2; j++) {
                bf16x8 bj = *(const bf16x8*)&sB[nw + 16 * j + r16][kb];
                acc[0][j] = __builtin_amdgcn_mfma_f32_16x16x32_bf16(a0, bj, acc[0][j], 0, 0, 0);
                acc[1][j] = __builtin_amdgcn_mfma_f32_16x16x32_bf16(a1, bj, acc[1][j], 0, 0, 0);
            }
        }
        __builtin_amdgcn_s_setprio(0);
    }
    __syncthreads();   // all waves done reading h1
#pragma unroll
    for (int nt = 0; nt < 2; nt++) {
        int col = nw + nt * 16 + r16;
        float bv = b1[col];
#pragma unroll
        for (int mt = 0; mt < 2; mt++)
#pragma unroll
            for (int reg = 0; reg < 4; reg++) {
                int rl = mw + mt * 16 + quad * 4 + reg;
                HV(rl, col) = f2b(fmaxf(acc[mt][nt][reg] + bv, 0.f));
            }
    }

    // ---- stage 2: out = h2 @ W2 + b2 + resid(x) ----
#pragma unroll
    for (int i = 0; i < 2; i++)
#pragma unroll
        for (int j = 0; j < 2; j++) acc[i][j] = (f32x4){0.f, 0.f, 0.f, 0.f};
#pragma unroll 1
    for (int kt = 0; kt < 2; kt++) {
        __syncthreads();   // kt=0 covers h2 writes
        *(uint4*)&sB[n8][sg8]      = rB0;
        *(uint4*)&sB[n8 + 64][sg8] = rB1;
        if (kt == 0) {
            rB0 = *(const uint4*)(W2 + (size_t)n8 * 128 + 64 + sg8);     // W2 chunk 1
            rB1 = *(const uint4*)(W2 + (size_t)(n8 + 64) * 128 + 64 + sg8);
        }
        __syncthreads();
        __builtin_amdgcn_s_setprio(1);
#pragma unroll
        for (int ks = 0; ks < 2; ks++) {
            int ko = kt * 64 + ks * 32 + quad * 8;
            int kb = ks * 32 + quad * 8;
            bf16x8 a0 = *(const bf16x8*)&HV(mw + r16, ko);
            bf16x8 a1 = *(const bf16x8*)&HV(mw + 16 + r16, ko);
#pragma unroll
            for (int j = 0; j < 2; j++) {
                bf16x8 bj = *(const bf16x8*)&sB[nw + 16 * j + r16][kb];
                acc[0][j] = __builtin_amdgcn_mfma_f32_16x16x32_bf16(a0, bj, acc[0][j], 0, 0, 0);
                acc[1][j] = __builtin_amdgcn_mfma_f32_16x16x32_bf16(a1, bj, acc[1][j], 0, 0, 0);
            }
        }
        __builtin_amdgcn_s_setprio(0);
    }
#pragma unroll
    for (int nt = 0; nt < 2; nt++) {
        int col = nw + nt * 16 + r16;
        float bv = b2[col];
#pragma unroll
        for (int mt = 0; mt < 2; mt++)
#pragma unroll
            for (int reg = 0; reg < 4; reg++) {
                int row = mw + mt * 16 + quad * 4 + reg;
                float v = acc[mt][nt][reg] + bv + b2f(xg[growBase + (size_t)row * 128 + col]);
                outp[growBase + (size_t)row * 128 + col] = f2b(v);
            }
    }
#undef HV
#undef WV
}

// ------------- last linear: out[m,0:3] = x[m,:] @ w_last + b_last -------------
__global__ __launch_bounds__(256) void last_linear_kern(
    const u16* __restrict__ x, const float* __restrict__ w,
    const float* __restrict__ bias, float* __restrict__ outp, int M)
{
    __shared__ float sw[128 * 3];
    int t = threadIdx.x;
    for (int i = t; i < 384; i += 256) sw[i] = w[i];
    __syncthreads();
    int wave = t >> 6;
    int lane = t & 63;
    int row = blockIdx.x * 4 + wave;
    if (row >= M) return;
    const u16* xr = x + (size_t)row * 128;
    float p0 = 0.f, p1 = 0.f, p2 = 0.f;
#pragma unroll
    for (int h = 0; h < 2; h++) {
        int c = lane + h * 64;
        float xv = b2f(xr[c]);
        p0 += xv * sw[c * 3 + 0];
        p1 += xv * sw[c * 3 + 1];
        p2 += xv * sw[c * 3 + 2];
    }
#pragma unroll
    for (int off = 32; off > 0; off >>= 1) {
        p0 += __shfl_xor(p0, off);
        p1 += __shfl_xor(p1, off);
        p2 += __shfl_xor(p2, off);
    }
    if (lane == 0) {
        float* o = outp + (size_t)row * 3;
        o[0] = p0 + bias[0];
        o[1] = p1 + bias[1];
        o[2] = p2 + bias[2];
    }
}

extern "C" void kernel_launch(void* const* d_in, const int* in_sizes, int n_in,
                              void* d_out, int out_size, void* d_ws, size_t ws_size,
                              hipStream_t stream)
{
    const float* x_in    = (const float*)d_in[0];
    const float* mass    = (const float*)d_in[1];
    const float* evals   = (const float*)d_in[2];
    const float* evecs   = (const float*)d_in[3];
    const int*   rows    = (const int*)  d_in[4];
    const int*   cols    = (const int*)  d_in[5];
    const float* gvx     = (const float*)d_in[6];
    const float* gvy     = (const float*)d_in[7];
    const float* w_first = (const float*)d_in[8];
    const float* b_first = (const float*)d_in[9];
    const float* dtimes  = (const float*)d_in[10];
    const float* A_re    = (const float*)d_in[11];
    const float* A_im    = (const float*)d_in[12];
    const float* w0      = (const float*)d_in[13];
    const float* b0      = (const float*)d_in[14];
    const float* w1      = (const float*)d_in[15];
    const float* b1      = (const float*)d_in[16];
    const float* w2      = (const float*)d_in[17];
    const float* b2      = (const float*)d_in[18];
    const float* w_last  = (const float*)d_in[19];
    const float* b_last  = (const float*)d_in[20];
    float* outp = (float*)d_out;

    const size_t SZ = (size_t)B_ * N_ * 128;   // 20,480,000 elements
    const size_t NZ = (size_t)N_ * 128;        //  5,120,000 elements

    // workspace layout (~174 MB)
    u16* P0 = (u16*)d_ws;                      // 41 MB  (x ping-pong)
    u16* P1 = P0 + SZ;                         // 41 MB  (xd ping-pong)
    u16* GF = P1 + SZ;                         // 41 MB  (gX/gY slots 0-1)
    float* SC = (float*)(GF + SZ);             // 41 MB  partials / gX/gY slots 2-3 (disjoint lifetimes)
    u16* ys_t = (u16*)(SC + 8388608);          // 128 KB in SC tail (dead before spmm writes slots 2-3)
    u16* WP0 = (u16*)(SC + 2 * NZ);            // packed transposed bf16 weights
    u16* WP1 = WP0 + 4 * 49152;
    u16* WP2 = WP1 + 4 * 16384;
    u16* WR1 = WP2 + 4 * 16384;                // 4 x [128][256] rotation packs
    u16* WR2 = WR1 + 4 * 32768;
    int* rowptr = (int*)(WR2 + 4 * 32768);     // N+1 (padded to 40004)
    int* nextp  = rowptr + 40004;              // N (histogram counts, then cursors)
    int* scols  = nextp + N_;                  // E sorted cols
    float* svx  = (float*)(scols + E_);        // [B][E] sorted vals
    float* svy  = svx + (size_t)B_ * E_;

    u16* x  = P0;
    u16* xd = P1;
    const int M = B_ * N_;                     // 160000

    // --- CSR build (pattern shared across blocks & X/Y) ---
    int* bTot  = (int*)SC;          // NB_SCAN block totals (transient, pre-loop)
    int* bOff  = bTot + 512;
    int* sperm = bTot + 1024;       // E edge permutation (transient, pre-loop)
    hipMemsetAsync(nextp, 0, N_ * sizeof(int), stream);
    hist_kern<<<dim3((E_ + 255) / 256), 256, 0, stream>>>(rows, nextp);
    scan1_kern<<<dim3(NB_SCAN), 256, 0, stream>>>(nextp, rowptr, bTot);
    scan2_kern<<<dim3(1), 256, 0, stream>>>(bTot, bOff, rowptr + N_);
    scan3_kern<<<dim3(NB_SCAN), 256, 0, stream>>>(rowptr, nextp, bOff);
    scatter_idx_kern<<<dim3((E_ + 255) / 256), 256, 0, stream>>>(
        rows, cols, nextp, scols, sperm);
    gather_vals_kern<<<dim3((E_ + 255) / 256), 256, 0, stream>>>(
        sperm, gvx, gvy, svx, svy);

    // --- weight packing (once per launch) ---
    pack_w_kern<<<dim3(192, 1, 4), 256, 0, stream>>>(w0, WP0, 384);
    pack_w_kern<<<dim3(64, 1, 4), 256, 0, stream>>>(w1, WP1, 128);
    pack_w_kern<<<dim3(64, 1, 4), 256, 0, stream>>>(w2, WP2, 128);
    pack_rot_kern<<<dim3(128, 1, 4), 256, 0, stream>>>(A_re, A_im, WR1, WR2);

    first_linear_kern<<<dim3(M * 16 / 256), 256, 0, stream>>>(x_in, w_first, b_first, x, M);

    // gX/gY slots: z<2 in GF, z>=2 in SC (partials/ys_t dead by the time spmm writes)
    u16* GXY0 = GF;
    u16* GXY1 = (u16*)SC;

    for (int i = 0; i < 4; i++) {
        // --- spectral diffusion ---
        spec_stage1_mfma_kern<<<dim3(128, B_), 256, 0, stream>>>(x, mass, evecs, SC);
        spec_stage2_coef_kern<<<dim3(B_ * 128), 512, 0, stream>>>(
            SC, evals, dtimes + (size_t)i * 128, ys_t);
        mgemm_kern<128, true><<<dim3(N_ / 64, 1, B_), 256, 0, stream>>>(
            evecs, ys_t, xd, NZ, (size_t)128 * 128, NZ);
        // --- sparse gradients (all batches, one dispatch) ---
        spmm_csr_kern<<<dim3(N_ / 4, 1, B_), 256, 0, stream>>>(
            rowptr, scols, svx, svy, xd, GXY0, GXY1);
        // --- fused rotate+tanh+MLP+residual (all batches, one dispatch, 512 thr) ---
        mlp_rot_fused_kern<<<dim3(N_ / 64, 1, B_), 512, 0, stream>>>(
            x, xd, GXY0, GXY1,
            WR1 + (size_t)i * 32768, WR2 + (size_t)i * 32768,
            WP0 + (size_t)i * 49152, WP1 + (size_t)i * 16384, WP2 + (size_t)i * 16384,
            b0 + (size_t)i * 128, b1 + (size_t)i * 128, b2 + (size_t)i * 128,
            xd);
        u16* tmp = x; x = xd; xd = tmp;
    }

    last_linear_kern<<<dim3(M / 4), 256, 0, stream>>>(x, w_last, b_last, outp, M);
}

// Round 13
// 1131.094 us; speedup vs baseline: 1.4859x; 1.0049x over previous
//
#include <hip/hip_runtime.h>

#define B_ 4
#define N_ 40000
#define E_ 240000
#define NB_SCAN ((N_ + 255) / 256)   // 157 scan blocks

typedef unsigned short u16;
typedef unsigned int u32;
typedef __attribute__((ext_vector_type(8))) short bf16x8;
typedef __attribute__((ext_vector_type(4))) float f32x4;

__device__ __forceinline__ float b2f(u16 h) {
    u32 u = ((u32)h) << 16;
    return __uint_as_float(u);
}
__device__ __forceinline__ u16 f2b(float f) {
    u32 u = __float_as_uint(f);
    u32 r = (u + 0x7fffu + ((u >> 16) & 1u)) >> 16;
    return (u16)r;
}
// fast tanh: clamped exp form; abs err <= ~1e-6 (far below bf16 rounding)
__device__ __forceinline__ float fast_tanh(float x) {
    float cx = fminf(fmaxf(x, -9.f), 9.f);
    float e = __expf(2.f * cx);
    return (e - 1.f) / (e + 1.f);
}

// ---------------- first linear: x = x_in @ w_first + b_first (bf16 out, 8 c/thread) ----------------
__global__ __launch_bounds__(256) void first_linear_kern(
    const float* __restrict__ x_in, const float* __restrict__ w,
    const float* __restrict__ bias, u16* __restrict__ xout, int M)
{
    __shared__ float sw[6 * 128];
    __shared__ float sb[128];
    int t = threadIdx.x;
    for (int i = t; i < 768; i += 256) sw[i] = w[i];
    if (t < 128) sb[t] = bias[t];
    __syncthreads();
    int idx = blockIdx.x * 256 + t;   // = row*16 + cg
    int row = idx >> 4;
    int cg = (idx & 15) * 8;
    if (row >= M) return;
    const float* xr = x_in + (size_t)row * 6;
    float xv[6];
#pragma unroll
    for (int j = 0; j < 6; j++) xv[j] = xr[j];
    float acc[8];
#pragma unroll
    for (int i = 0; i < 8; i++) acc[i] = sb[cg + i];
#pragma unroll
    for (int j = 0; j < 6; j++)
#pragma unroll
        for (int i = 0; i < 8; i++) acc[i] += xv[j] * sw[j * 128 + cg + i];
    ushort4 h0, h1;
    h0.x = f2b(acc[0]); h0.y = f2b(acc[1]); h0.z = f2b(acc[2]); h0.w = f2b(acc[3]);
    h1.x = f2b(acc[4]); h1.y = f2b(acc[5]); h1.z = f2b(acc[6]); h1.w = f2b(acc[7]);
    uint4 pk;
    pk.x = (u32)h0.x | ((u32)h0.y << 16);
    pk.y = (u32)h0.z | ((u32)h0.w << 16);
    pk.z = (u32)h1.x | ((u32)h1.y << 16);
    pk.w = (u32)h1.z | ((u32)h1.w << 16);
    *(uint4*)(xout + (size_t)row * 128 + cg) = pk;
}

// ------------- weight pack: dst[n][k] = bf16(src[k][n]), per block i = blockIdx.z -------------
__global__ __launch_bounds__(256) void pack_w_kern(
    const float* __restrict__ src, u16* __restrict__ dst, int K)
{
    int i = blockIdx.z;
    src += (size_t)i * K * 128;
    dst += (size_t)i * K * 128;
    int idx = blockIdx.x * 256 + threadIdx.x;  // = n*K + k
    int n = idx / K;
    int k = idx % K;
    dst[idx] = f2b(src[(size_t)k * 128 + n]);
}

// ------------- rotation weight pack: WR1[n][k256] = [Are; -Aim]^T, WR2 = [Are; Aim]^T -------------
__global__ __launch_bounds__(256) void pack_rot_kern(
    const float* __restrict__ Are, const float* __restrict__ Aim,
    u16* __restrict__ WR1, u16* __restrict__ WR2)
{
    int i = blockIdx.z;
    const float* are = Are + (size_t)i * 16384;
    const float* aim = Aim + (size_t)i * 16384;
    int idx = blockIdx.x * 256 + threadIdx.x;  // 0..32767 = n*256 + k
    int n = idx >> 8;
    int k = idx & 255;
    float v1, v2;
    if (k < 128) { float a = are[(size_t)k * 128 + n]; v1 = a; v2 = a; }
    else         { float a = aim[(size_t)(k - 128) * 128 + n]; v1 = -a; v2 = a; }
    WR1[(size_t)i * 32768 + idx] = f2b(v1);
    WR2[(size_t)i * 32768 + idx] = f2b(v2);
}

// ------------- CSR build: histogram -> 3-phase parallel scan -> scatter idx -> gather vals -------------
__global__ __launch_bounds__(256) void hist_kern(const int* __restrict__ rows, int* count)
{
    int e = blockIdx.x * 256 + threadIdx.x;
    if (e < E_) atomicAdd(&count[rows[e]], 1);
}

// inclusive scan across a 256-thread block (4 waves, shfl-based)
__device__ __forceinline__ int block_incl_scan_256(int v, int t)
{
    __shared__ int wsum[4];
    int lane = t & 63;
    int wid = t >> 6;
    int x = v;
#pragma unroll
    for (int off = 1; off < 64; off <<= 1) {
        int y = __shfl_up(x, off);
        if (lane >= off) x += y;
    }
    if (lane == 63) wsum[wid] = x;
    __syncthreads();
    if (t == 0) {
        int s = 0;
#pragma unroll
        for (int i = 0; i < 4; i++) { int tm = wsum[i]; wsum[i] = s; s += tm; }
    }
    __syncthreads();
    return x + wsum[wid];
}

// phase 1: per-block exclusive scan of counts -> rowptr (partial), block totals
__global__ __launch_bounds__(256) void scan1_kern(
    const int* __restrict__ count, int* __restrict__ excl_out,
    int* __restrict__ blockTotals)
{
    int t = threadIdx.x;
    int g = blockIdx.x * 256 + t;
    int v = (g < N_) ? count[g] : 0;
    int incl = block_incl_scan_256(v, t);
    if (g < N_) excl_out[g] = incl - v;
    if (t == 255) blockTotals[blockIdx.x] = incl;
}

// phase 2: single-block scan of 157 block totals -> exclusive block offsets + grand total
__global__ __launch_bounds__(256) void scan2_kern(
    const int* __restrict__ blockTotals, int* __restrict__ blockOffs,
    int* __restrict__ totalOut)
{
    int t = threadIdx.x;
    int v = (t < NB_SCAN) ? blockTotals[t] : 0;
    int incl = block_incl_scan_256(v, t);
    if (t < NB_SCAN) blockOffs[t] = incl - v;
    if (t == 255) *totalOut = incl;   // = E_, written to rowptr[N_]
}

// phase 3: add block offsets; materialize rowptr + nextp cursors
__global__ __launch_bounds__(256) void scan3_kern(
    int* __restrict__ rowptr, int* __restrict__ nextp,
    const int* __restrict__ blockOffs)
{
    int t = threadIdx.x;
    int g = blockIdx.x * 256 + t;
    if (g >= N_) return;
    int v = rowptr[g] + blockOffs[blockIdx.x];
    rowptr[g] = v;
    nextp[g] = v;
}

// scatter only indices (2 scattered u32 writes per edge)
__global__ __launch_bounds__(256) void scatter_idx_kern(
    const int* __restrict__ rows, const int* __restrict__ cols,
    int* nextp, int* __restrict__ scols, int* __restrict__ sperm)
{
    int e = blockIdx.x * 256 + threadIdx.x;
    if (e >= E_) return;
    int r = rows[e];
    int pos = atomicAdd(&nextp[r], 1);
    scols[pos] = cols[e];
    sperm[pos] = e;
}

// gather values: coalesced writes of PACKED bf16 (vx,vy) pairs; L2-cached random reads
__global__ __launch_bounds__(256) void gather_vals_kern(
    const int* __restrict__ sperm,
    const float* __restrict__ gvx, const float* __restrict__ gvy,
    u32* __restrict__ svp)
{
    int pos = blockIdx.x * 256 + threadIdx.x;
    if (pos >= E_) return;
    int e = sperm[pos];
#pragma unroll
    for (int b = 0; b < B_; b++) {
        float vx = gvx[(size_t)b * E_ + e];
        float vy = gvy[(size_t)b * E_ + e];
        svp[(size_t)b * E_ + pos] = (u32)f2b(vx) | ((u32)f2b(vy) << 16);
    }
}

// ------------- CSR dual spMM (all batches via z), bf16 packed vals + out, edge-unrolled x4 -------------
__global__ __launch_bounds__(256) void spmm_csr_kern(
    const int* __restrict__ rowptr, const int* __restrict__ scols,
    const u32* __restrict__ svp,
    const u16* __restrict__ xd, u16* __restrict__ gXY0, u16* __restrict__ gXY1)
{
    const size_t NZ = (size_t)N_ * 128;
    int z = blockIdx.z;
    const u32* svp_b = svp + (size_t)z * E_;
    const u16* xd_b = xd + (size_t)z * NZ;
    u16* base = (z < 2) ? (gXY0 + (size_t)z * 2 * NZ) : (gXY1 + (size_t)(z - 2) * 2 * NZ);
    u16* gXh = base;
    u16* gYh = base + NZ;

    int t = threadIdx.x;
    int r = blockIdx.x * 4 + (t >> 6);
    int c2 = (t & 63) * 2;
    int beg = rowptr[r], end = rowptr[r + 1];
    float ax0 = 0.f, ax1 = 0.f, ay0 = 0.f, ay1 = 0.f;
    int j = beg;
    for (; j + 3 < end; j += 4) {
        int ca = scols[j], cb = scols[j + 1], cc = scols[j + 2], cd = scols[j + 3];
        u32 xwa = *(const u32*)(xd_b + (size_t)ca * 128 + c2);
        u32 xwb = *(const u32*)(xd_b + (size_t)cb * 128 + c2);
        u32 xwc = *(const u32*)(xd_b + (size_t)cc * 128 + c2);
        u32 xwd = *(const u32*)(xd_b + (size_t)cd * 128 + c2);
        u32 sa = svp_b[j], sb = svp_b[j + 1], sc = svp_b[j + 2], sd = svp_b[j + 3];
        float vxa = b2f((u16)(sa & 0xffffu)), vya = b2f((u16)(sa >> 16));
        float vxb = b2f((u16)(sb & 0xffffu)), vyb = b2f((u16)(sb >> 16));
        float vxc = b2f((u16)(sc & 0xffffu)), vyc = b2f((u16)(sc >> 16));
        float vxd = b2f((u16)(sd & 0xffffu)), vyd = b2f((u16)(sd >> 16));
        float xa0 = b2f((u16)(xwa & 0xffffu)), xa1 = b2f((u16)(xwa >> 16));
        float xb0 = b2f((u16)(xwb & 0xffffu)), xb1 = b2f((u16)(xwb >> 16));
        float xc0 = b2f((u16)(xwc & 0xffffu)), xc1 = b2f((u16)(xwc >> 16));
        float xd0 = b2f((u16)(xwd & 0xffffu)), xd1 = b2f((u16)(xwd >> 16));
        ax0 += vxa * xa0; ax1 += vxa * xa1;
        ay0 += vya * xa0; ay1 += vya * xa1;
        ax0 += vxb * xb0; ax1 += vxb * xb1;
        ay0 += vyb * xb0; ay1 += vyb * xb1;
        ax0 += vxc * xc0; ax1 += vxc * xc1;
        ay0 += vyc * xc0; ay1 += vyc * xc1;
        ax0 += vxd * xd0; ax1 += vxd * xd1;
        ay0 += vyd * xd0; ay1 += vyd * xd1;
    }
    for (; j < end; j++) {
        int col = scols[j];
        u32 xw = *(const u32*)(xd_b + (size_t)col * 128 + c2);
        u32 sv = svp_b[j];
        float x0 = b2f((u16)(xw & 0xffffu));
        float x1 = b2f((u16)(xw >> 16));
        float vx = b2f((u16)(sv & 0xffffu)), vy = b2f((u16)(sv >> 16));
        ax0 += vx * x0; ax1 += vx * x1;
        ay0 += vy * x0; ay1 += vy * x1;
    }
    u32 px = (u32)f2b(ax0) | ((u32)f2b(ax1) << 16);
    u32 py = (u32)f2b(ay0) | ((u32)f2b(ay1) << 16);
    *(u32*)(gXh + (size_t)r * 128 + c2) = px;
    *(u32*)(gYh + (size_t)r * 128 + c2) = py;
}

// ------------- spectral projection stage 1: MFMA over transposed LDS tiles -------------
__global__ __launch_bounds__(256) void spec_stage1_mfma_kern(
    const u16* __restrict__ x, const float* __restrict__ mass,
    const float* __restrict__ evecs, float* __restrict__ partials)
{
    __shared__ __align__(16) u16 sEVh[128][40];
    __shared__ __align__(16) u16 sEVl[128][40];
    __shared__ __align__(16) u16 sXM[128][40];
    int b = blockIdx.y;
    int pb = blockIdx.x;
    const u16* xb = x + (size_t)b * N_ * 128;
    const float* mb = mass + (size_t)b * N_;
    const float* eb = evecs + (size_t)b * N_ * 128;
    float* dst = partials + ((size_t)b * 128 + pb) * 16384;

    int t = threadIdx.x;
    int wv = t >> 6;
    int lane = t & 63;
    int quad = lane >> 4;
    int r16 = lane & 15;
    int kb = wv * 32;
    int kc = (t & 63) * 2;
    int nh = wv;

    f32x4 acc[2][8];
#pragma unroll
    for (int i = 0; i < 2; i++)
#pragma unroll
        for (int j = 0; j < 8; j++) acc[i][j] = (f32x4){0.f, 0.f, 0.f, 0.f};

    for (int ch = pb; ch < N_ / 32; ch += 128) {
        int nbase = ch * 32 + nh * 8;
        float4 m0 = *(const float4*)(mb + nbase);
        float4 m1 = *(const float4*)(mb + nbase + 4);
        float mm[8] = {m0.x, m0.y, m0.z, m0.w, m1.x, m1.y, m1.z, m1.w};
        u32 eh0[4], eh1[4], el0[4], el1[4], xq0[4], xq1[4];
#pragma unroll
        for (int jp = 0; jp < 4; jp++) {
            eh0[jp] = 0; eh1[jp] = 0; el0[jp] = 0;
            el1[jp] = 0; xq0[jp] = 0; xq1[jp] = 0;
        }
#pragma unroll
        for (int j = 0; j < 8; j++) {
            float2 e = *(const float2*)(eb + (size_t)(nbase + j) * 128 + kc);
            u32 xw = *(const u32*)(xb + (size_t)(nbase + j) * 128 + kc);
            u16 h0 = f2b(e.x);
            u16 h1 = f2b(e.y);
            u16 l0 = f2b(e.x - b2f(h0));
            u16 l1 = f2b(e.y - b2f(h1));
            u16 q0 = f2b(b2f((u16)(xw & 0xffffu)) * mm[j]);
            u16 q1 = f2b(b2f((u16)(xw >> 16)) * mm[j]);
            int sh = (j & 1) * 16;
            int jp = j >> 1;
            eh0[jp] |= ((u32)h0) << sh; eh1[jp] |= ((u32)h1) << sh;
            el0[jp] |= ((u32)l0) << sh; el1[jp] |= ((u32)l1) << sh;
            xq0[jp] |= ((u32)q0) << sh; xq1[jp] |= ((u32)q1) << sh;
        }
        __syncthreads();
        *(uint4*)&sEVh[kc][nh * 8]     = make_uint4(eh0[0], eh0[1], eh0[2], eh0[3]);
        *(uint4*)&sEVh[kc + 1][nh * 8] = make_uint4(eh1[0], eh1[1], eh1[2], eh1[3]);
        *(uint4*)&sEVl[kc][nh * 8]     = make_uint4(el0[0], el0[1], el0[2], el0[3]);
        *(uint4*)&sEVl[kc + 1][nh * 8] = make_uint4(el1[0], el1[1], el1[2], el1[3]);
        *(uint4*)&sXM[kc][nh * 8]      = make_uint4(xq0[0], xq0[1], xq0[2], xq0[3]);
        *(uint4*)&sXM[kc + 1][nh * 8]  = make_uint4(xq1[0], xq1[1], xq1[2], xq1[3]);
        __syncthreads();

        bf16x8 ah0 = *(const bf16x8*)&sEVh[kb + r16][quad * 8];
        bf16x8 ah1 = *(const bf16x8*)&sEVh[kb + 16 + r16][quad * 8];
        bf16x8 al0 = *(const bf16x8*)&sEVl[kb + r16][quad * 8];
        bf16x8 al1 = *(const bf16x8*)&sEVl[kb + 16 + r16][quad * 8];
        __builtin_amdgcn_s_setprio(1);
#pragma unroll
        for (int nt = 0; nt < 8; nt++) {
            bf16x8 bx = *(const bf16x8*)&sXM[nt * 16 + r16][quad * 8];
            acc[0][nt] = __builtin_amdgcn_mfma_f32_16x16x32_bf16(ah0, bx, acc[0][nt], 0, 0, 0);
            acc[1][nt] = __builtin_amdgcn_mfma_f32_16x16x32_bf16(ah1, bx, acc[1][nt], 0, 0, 0);
            acc[0][nt] = __builtin_amdgcn_mfma_f32_16x16x32_bf16(al0, bx, acc[0][nt], 0, 0, 0);
            acc[1][nt] = __builtin_amdgcn_mfma_f32_16x16x32_bf16(al1, bx, acc[1][nt], 0, 0, 0);
        }
        __builtin_amdgcn_s_setprio(0);
    }

#pragma unroll
    for (int mt = 0; mt < 2; mt++)
#pragma unroll
        for (int nt = 0; nt < 8; nt++)
#pragma unroll
            for (int reg = 0; reg < 4; reg++) {
                int kk = kb + mt * 16 + quad * 4 + reg;
                int cc = nt * 16 + r16;
                dst[(size_t)kk * 128 + cc] = acc[mt][nt][reg];
            }
}

// ------------- stage 2 + coefficients (512 thr, 4-way pb-split): ys_t[b][c][k] bf16 -------------
__global__ __launch_bounds__(512) void spec_stage2_coef_kern(
    const float* __restrict__ partials, const float* __restrict__ evals,
    const float* __restrict__ dt, u16* __restrict__ ys_t)
{
    __shared__ float red[4][128];
    int b = blockIdx.x >> 7;
    int k = blockIdx.x & 127;
    int c = threadIdx.x & 127;
    int g = threadIdx.x >> 7;   // 0..3
    const float* p = partials + (size_t)b * 128 * 16384 + (size_t)k * 128 + c;
    float s = 0.f;
#pragma unroll 8
    for (int pb = g; pb < 128; pb += 4) s += p[(size_t)pb * 16384];
    red[g][c] = s;
    __syncthreads();
    if (g == 0) {
        float tot = (red[0][c] + red[1][c]) + (red[2][c] + red[3][c]);
        float co = expf(-evals[b * 128 + k] * dt[c]);
        ys_t[((size_t)b * 128 + c) * 128 + k] = f2b(tot * co);
    }
}

// ------------- MFMA GEMM: out[m,0:128] = A[m,:KK] @ W (bf16 out); AF32 path for evecs ------
template <int KK, bool AF32>
__global__ __launch_bounds__(256) void mgemm_kern(
    const void* __restrict__ A0v,
    const u16* __restrict__ Wp, u16* __restrict__ outp,
    size_t aBatch, size_t wBatch, size_t oBatch)
{
    __shared__ u16 sA[64][72];
    __shared__ u16 sB[128][72];
    int z = blockIdx.z;
    const u16* Wb = Wp + wBatch * (size_t)z;
    size_t aOff = aBatch * (size_t)z;
    size_t oOff = oBatch * (size_t)z;

    int t = threadIdx.x;
    int m0 = blockIdx.x * 64;
    int wv = t >> 6;
    int lane = t & 63;
    int quad = lane >> 4;
    int r16 = lane & 15;
    int mw = (wv & 1) * 32;
    int nw = (wv >> 1) * 64;

    f32x4 acc[2][4];
#pragma unroll
    for (int i = 0; i < 2; i++)
#pragma unroll
        for (int j = 0; j < 4; j++) acc[i][j] = (f32x4){0.f, 0.f, 0.f, 0.f};

#pragma unroll 1
    for (int kt = 0; kt < KK / 64; kt++) {
        int kbase = kt * 64;
        __syncthreads();
        if (AF32) {
            const float* Af = (const float*)A0v + aOff;
#pragma unroll
            for (int p = 0; p < 4; p++) {
                int idx = p * 256 + t;
                int row = idx >> 4;
                int seg = idx & 15;
                float4 v = *(const float4*)(Af + (size_t)(m0 + row) * 128 + kbase + seg * 4);
                ushort4 h;
                h.x = f2b(v.x); h.y = f2b(v.y); h.z = f2b(v.z); h.w = f2b(v.w);
                *(ushort4*)&sA[row][seg * 4] = h;
            }
        } else {
            const u16* Ah = (const u16*)A0v + aOff;
#pragma unroll
            for (int p = 0; p < 2; p++) {
                int idx = p * 256 + t;
                int row = idx >> 3;
                int seg = idx & 7;
                *(uint4*)&sA[row][seg * 8] =
                    *(const uint4*)(Ah + (size_t)(m0 + row) * 128 + kbase + seg * 8);
            }
        }
        {
#pragma unroll
            for (int p = 0; p < 4; p++) {
                int idx = p * 256 + t;
                int n = idx >> 3;
                int seg = idx & 7;
                *(uint4*)&sB[n][seg * 8] =
                    *(const uint4*)(Wb + (size_t)n * KK + kbase + seg * 8);
            }
        }
        __syncthreads();

        __builtin_amdgcn_s_setprio(1);
#pragma unroll
        for (int ks = 0; ks < 2; ks++) {
            int ko = ks * 32 + quad * 8;
            bf16x8 a0 = *(const bf16x8*)&sA[mw + r16][ko];
            bf16x8 a1 = *(const bf16x8*)&sA[mw + 16 + r16][ko];
            bf16x8 b0 = *(const bf16x8*)&sB[nw + r16][ko];
            bf16x8 b1 = *(const bf16x8*)&sB[nw + 16 + r16][ko];
            bf16x8 b2 = *(const bf16x8*)&sB[nw + 32 + r16][ko];
            bf16x8 b3 = *(const bf16x8*)&sB[nw + 48 + r16][ko];
            acc[0][0] = __builtin_amdgcn_mfma_f32_16x16x32_bf16(a0, b0, acc[0][0], 0, 0, 0);
            acc[0][1] = __builtin_amdgcn_mfma_f32_16x16x32_bf16(a0, b1, acc[0][1], 0, 0, 0);
            acc[0][2] = __builtin_amdgcn_mfma_f32_16x16x32_bf16(a0, b2, acc[0][2], 0, 0, 0);
            acc[0][3] = __builtin_amdgcn_mfma_f32_16x16x32_bf16(a0, b3, acc[0][3], 0, 0, 0);
            acc[1][0] = __builtin_amdgcn_mfma_f32_16x16x32_bf16(a1, b0, acc[1][0], 0, 0, 0);
            acc[1][1] = __builtin_amdgcn_mfma_f32_16x16x32_bf16(a1, b1, acc[1][1], 0, 0, 0);
            acc[1][2] = __builtin_amdgcn_mfma_f32_16x16x32_bf16(a1, b2, acc[1][2], 0, 0, 0);
            acc[1][3] = __builtin_amdgcn_mfma_f32_16x16x32_bf16(a1, b3, acc[1][3], 0, 0, 0);
        }
        __builtin_amdgcn_s_setprio(0);
    }

#pragma unroll
    for (int nt = 0; nt < 4; nt++) {
        int col = nw + nt * 16 + r16;
#pragma unroll
        for (int mt = 0; mt < 2; mt++) {
#pragma unroll
            for (int reg = 0; reg < 4; reg++) {
                int row = m0 + mw + mt * 16 + quad * 4 + reg;
                outp[oOff + (size_t)row * 128 + col] = f2b(acc[mt][nt][reg]);
            }
        }
    }
}

// ------------- FUSED rotation + tanh + 3-layer MiniMLP (512 threads, reg-prefetch + setprio) -------------
// x tile archived in sGY (dead after tanh) during stage0 kt=0/1; epilogue resid reads LDS.
__global__ __launch_bounds__(512) void mlp_rot_fused_kern(
    const u16* __restrict__ xg, const u16* __restrict__ xdg,
    const u16* __restrict__ gXY0, const u16* __restrict__ gXY1,
    const u16* __restrict__ WR1, const u16* __restrict__ WR2,
    const u16* __restrict__ W0, const u16* __restrict__ W1, const u16* __restrict__ W2,
    const float* __restrict__ b0, const float* __restrict__ b1, const float* __restrict__ b2,
    u16* __restrict__ outp)
{
    __shared__ u16 sGX[64][136];
    __shared__ u16 sGY[64][136];
    __shared__ u16 sB[128][72];
    __shared__ __align__(16) u16 sHbuf[9728];   // WR2 chunk view, then h1/h2 view
    __shared__ u16 sA[64][72];
#define HV(r, c) sHbuf[(r) * 152 + (c)]
#define WV(n, c) sHbuf[(n) * 72 + (c)]

    const size_t NZ = (size_t)N_ * 128;
    int z = blockIdx.z;                  // = batch
    const u16* gX = (z < 2) ? (gXY0 + (size_t)z * 2 * NZ) : (gXY1 + (size_t)(z - 2) * 2 * NZ);
    const u16* gY = gX + NZ;
    int m0n = blockIdx.x * 64;
    size_t growBase = ((size_t)z * N_ + m0n) * 128;

    int t = threadIdx.x;
    int wv = t >> 6;                     // 0..7
    int lane = t & 63;
    int quad = lane >> 4;
    int r16 = lane & 15;
    int mw = (wv & 1) * 32;              // 0 or 32
    int nw = (wv >> 1) * 32;             // 0,32,64,96

    // staging thread mapping: each thread owns rows n8 and n8+64, 8 u16 at sg8
    int n8 = t >> 3;                     // 0..63
    int sg8 = (t & 7) * 8;               // 0..56

    // ---- prefetch rotation chunk 0 weights into registers ----
    const u16* w1base  = WR1 + (size_t)n8 * 256 + sg8;
    const u16* w1base2 = WR1 + (size_t)(n8 + 64) * 256 + sg8;
    const u16* w2base  = WR2 + (size_t)n8 * 256 + sg8;
    const u16* w2base2 = WR2 + (size_t)(n8 + 64) * 256 + sg8;
    uint4 r1a = *(const uint4*)(w1base);
    uint4 r1b = *(const uint4*)(w1base2);
    uint4 r2a = *(const uint4*)(w2base);
    uint4 r2b = *(const uint4*)(w2base2);

    // ---- stage gX, gY tiles ----
#pragma unroll
    for (int p = 0; p < 2; p++) {
        int idx = p * 512 + t;
        int row = idx >> 4;
        int seg = idx & 15;
        *(uint4*)&sGX[row][seg * 8] = *(const uint4*)(gX + (size_t)(m0n + row) * 128 + seg * 8);
        *(uint4*)&sGY[row][seg * 8] = *(const uint4*)(gY + (size_t)(m0n + row) * 128 + seg * 8);
    }

    f32x4 accRe[2][2], accIm[2][2];
#pragma unroll
    for (int i = 0; i < 2; i++)
#pragma unroll
        for (int j = 0; j < 2; j++) {
            accRe[i][j] = (f32x4){0.f, 0.f, 0.f, 0.f};
            accIm[i][j] = (f32x4){0.f, 0.f, 0.f, 0.f};
        }

    // ---- rotation: 4 x 64-k chunks; write staged regs, prefetch next chunk ----
#pragma unroll 1
    for (int c = 0; c < 4; c++) {
        __syncthreads();   // c=0: covers sGX/sGY staging; else: prev-chunk consumers done
        *(uint4*)&sB[n8][sg8]      = r1a;
        *(uint4*)&sB[n8 + 64][sg8] = r1b;
        *(uint4*)&WV(n8, sg8)      = r2a;
        *(uint4*)&WV(n8 + 64, sg8) = r2b;
        if (c < 3) {
            r1a = *(const uint4*)(w1base  + (c + 1) * 64);
            r1b = *(const uint4*)(w1base2 + (c + 1) * 64);
            r2a = *(const uint4*)(w2base  + (c + 1) * 64);
            r2b = *(const uint4*)(w2base2 + (c + 1) * 64);
        }
        __syncthreads();

        const u16 (*sRe)[136] = (c < 2) ? sGX : sGY;
        const u16 (*sIm)[136] = (c < 2) ? sGY : sGX;
        int kob = (c & 1) * 64;
        __builtin_amdgcn_s_setprio(1);
#pragma unroll
        for (int ks = 0; ks < 2; ks++) {
            int ko = kob + ks * 32 + quad * 8;
            int kb = ks * 32 + quad * 8;
            bf16x8 aRe0 = *(const bf16x8*)&sRe[mw + r16][ko];
            bf16x8 aRe1 = *(const bf16x8*)&sRe[mw + 16 + r16][ko];
            bf16x8 aIm0 = *(const bf16x8*)&sIm[mw + r16][ko];
            bf16x8 aIm1 = *(const bf16x8*)&sIm[mw + 16 + r16][ko];
#pragma unroll
            for (int j = 0; j < 2; j++) {
                bf16x8 w1f = *(const bf16x8*)&sB[nw + 16 * j + r16][kb];
                bf16x8 w2f = *(const bf16x8*)&WV(nw + 16 * j + r16, kb);
                accRe[0][j] = __builtin_amdgcn_mfma_f32_16x16x32_bf16(aRe0, w1f, accRe[0][j], 0, 0, 0);
                accRe[1][j] = __builtin_amdgcn_mfma_f32_16x16x32_bf16(aRe1, w1f, accRe[1][j], 0, 0, 0);
                accIm[0][j] = __builtin_amdgcn_mfma_f32_16x16x32_bf16(aIm0, w2f, accIm[0][j], 0, 0, 0);
                accIm[1][j] = __builtin_amdgcn_mfma_f32_16x16x32_bf16(aIm1, w2f, accIm[1][j], 0, 0, 0);
            }
        }
        __builtin_amdgcn_s_setprio(0);
    }

    // ---- prefetch W0 kt=0 + x kt=0 (in flight across tanh phase) ----
    const u16* w0base  = W0 + (size_t)n8 * 384 + sg8;
    const u16* w0base2 = W0 + (size_t)(n8 + 64) * 384 + sg8;
    const u16* xbase  = xg  + growBase + (size_t)n8 * 128 + sg8;
    const u16* xdbase = xdg + growBase + (size_t)n8 * 128 + sg8;
    uint4 rB0 = *(const uint4*)(w0base);
    uint4 rB1 = *(const uint4*)(w0base2);
    uint4 rA  = *(const uint4*)(xbase);

    // ---- tanh in place: gf -> sGX (each element owned by exactly one lane) ----
    __syncthreads();   // all fragment reads of sGX/sGY complete
#pragma unroll
    for (int nt = 0; nt < 2; nt++) {
        int col = nw + nt * 16 + r16;
#pragma unroll
        for (int mt = 0; mt < 2; mt++)
#pragma unroll
            for (int reg = 0; reg < 4; reg++) {
                int lrow = mw + mt * 16 + quad * 4 + reg;
                float gx = b2f(sGX[lrow][col]);
                float gy = b2f(sGY[lrow][col]);
                float v = fast_tanh(gx * accRe[mt][nt][reg] + gy * accIm[mt][nt][reg]);
                sGX[lrow][col] = f2b(v);
            }
    }

    // ---- MLP stage 0: K=384 over concat(x, xd, gf-from-LDS), reg-prefetched staging ----
    // x chunks (kt=0,1) additionally archived into sGY for the residual epilogue.
    f32x4 acc[2][2];
#pragma unroll
    for (int i = 0; i < 2; i++)
#pragma unroll
        for (int j = 0; j < 2; j++) acc[i][j] = (f32x4){0.f, 0.f, 0.f, 0.f};
#pragma unroll 1
    for (int kt = 0; kt < 6; kt++) {
        int kloc = (kt * 64) & 127;
        __syncthreads();   // kt=0 covers tanh writes (incl. last sGY reads); else prev-chunk consumers done
        if (kt < 4) *(uint4*)&sA[n8][sg8] = rA;
        if (kt < 2) *(uint4*)&sGY[n8][kt * 64 + sg8] = rA;   // archive x tile (sGY dead after tanh)
        *(uint4*)&sB[n8][sg8]      = rB0;
        *(uint4*)&sB[n8 + 64][sg8] = rB1;
        if (kt < 5) {
            rB0 = *(const uint4*)(w0base  + (kt + 1) * 64);
            rB1 = *(const uint4*)(w0base2 + (kt + 1) * 64);
        } else {
            rB0 = *(const uint4*)(W1 + (size_t)n8 * 128 + sg8);          // W1 chunk 0
            rB1 = *(const uint4*)(W1 + (size_t)(n8 + 64) * 128 + sg8);
        }
        if (kt < 3) {
            const u16* nbp = (kt + 1 < 2) ? xbase : xdbase;
            rA = *(const uint4*)(nbp + (((kt + 1) * 64) & 127));
        }
        __syncthreads();
        __builtin_amdgcn_s_setprio(1);
#pragma unroll
        for (int ks = 0; ks < 2; ks++) {
            int ko = ks * 32 + quad * 8;
            bf16x8 a0, a1;
            if (kt < 4) {
                a0 = *(const bf16x8*)&sA[mw + r16][ko];
                a1 = *(const bf16x8*)&sA[mw + 16 + r16][ko];
            } else {
                a0 = *(const bf16x8*)&sGX[mw + r16][kloc + ko];
                a1 = *(const bf16x8*)&sGX[mw + 16 + r16][kloc + ko];
            }
#pragma unroll
            for (int j = 0; j < 2; j++) {
                bf16x8 bj = *(const bf16x8*)&sB[nw + 16 * j + r16][ko];
                acc[0][j] = __builtin_amdgcn_mfma_f32_16x16x32_bf16(a0, bj, acc[0][j], 0, 0, 0);
                acc[1][j] = __builtin_amdgcn_mfma_f32_16x16x32_bf16(a1, bj, acc[1][j], 0, 0, 0);
            }
        }
        __builtin_amdgcn_s_setprio(0);
    }
    // h1 -> sHbuf (bias + relu + bf16); WR2 chunks fully consumed
    __syncthreads();
#pragma unroll
    for (int nt = 0; nt < 2; nt++) {
        int col = nw + nt * 16 + r16;
        float bv = b0[col];
#pragma unroll
        for (int mt = 0; mt < 2; mt++)
#pragma unroll
            for (int reg = 0; reg < 4; reg++) {
                int rl = mw + mt * 16 + quad * 4 + reg;
                HV(rl, col) = f2b(fmaxf(acc[mt][nt][reg] + bv, 0.f));
            }
    }

    // ---- stage 1: h2 = relu(h1 @ W1 + b1), reg-prefetched W1/W2 ----
#pragma unroll
    for (int i = 0; i < 2; i++)
#pragma unroll
        for (int j = 0; j < 2; j++) acc[i][j] = (f32x4){0.f, 0.f, 0.f, 0.f};
#pragma unroll 1
    for (int kt = 0; kt < 2; kt++) {
        __syncthreads();   // kt=0 covers h1 writes
        *(uint4*)&sB[n8][sg8]      = rB0;
        *(uint4*)&sB[n8 + 64][sg8] = rB1;
        if (kt == 0) {
            rB0 = *(const uint4*)(W1 + (size_t)n8 * 128 + 64 + sg8);     // W1 chunk 1
            rB1 = *(const uint4*)(W1 + (size_t)(n8 + 64) * 128 + 64 + sg8);
        } else {
            rB0 = *(const uint4*)(W2 + (size_t)n8 * 128 + sg8);          // W2 chunk 0
            rB1 = *(const uint4*)(W2 + (size_t)(n8 + 64) * 128 + sg8);
        }
        __syncthreads();
        __builtin_amdgcn_s_setprio(1);
#pragma unroll
        for (int ks = 0; ks < 2; ks++) {
            int ko = kt * 64 + ks * 32 + quad * 8;
            int kb = ks * 32 + quad * 8;
            bf16x8 a0 = *(const bf16x8*)&HV(mw + r16, ko);
            bf16x8 a1 = *(const bf16x8*)&HV(mw + 16 + r16, ko);
#pragma unroll
            for (int j = 0; j < 2; j++) {
                bf16x8 bj = *(const bf16x8*)&sB[nw + 16 * j + r16][kb];
                acc[0][j] = __builtin_amdgcn_mfma_f32_16x16x32_bf16(a0, bj, acc[0][j], 0, 0, 0);
                acc[1][j] = __builtin_amdgcn_mfma_f32_16x16x32_bf16(a1, bj, acc[1][j], 0, 0, 0);
            }
        }
        __builtin_amdgcn_s_setprio(0);
    }
    __syncthreads();   // all waves done reading h1
#pragma unroll
    for (int nt = 0; nt < 2; nt++) {
        int col = nw + nt * 16 + r16;
        float bv = b1[col];
#pragma unroll
        for (int mt = 0; mt < 2; mt++)
#pragma unroll
            for (int reg = 0; reg < 4; reg++) {
                int rl = mw + mt * 16 + quad * 4 + reg;
                HV(rl, col) = f2b(fmaxf(acc[mt][nt][reg] + bv, 0.f));
            }
    }

    // ---- stage 2: out = h2 @ W2 + b2 + resid(x-from-LDS) ----
#pragma unroll
    for (int i = 0; i < 2; i++)
#pragma unroll
        for (int j = 0; j < 2; j++) acc[i][j] = (f32x4){0.f, 0.f, 0.f, 0.f};
#pragma unroll 1
    for (int kt = 0; kt < 2; kt++) {
        __syncthreads();   // kt=0 covers h2 writes
        *(uint4*)&sB[n8][sg8]      = rB0;
        *(uint4*)&sB[n8 + 64][sg8] = rB1;
        if (kt == 0) {
            rB0 = *(const uint4*)(W2 + (size_t)n8 * 128 + 64 + sg8);     // W2 chunk 1
            rB1 = *(const uint4*)(W2 + (size_t)(n8 + 64) * 128 + 64 + sg8);
        }
        __syncthreads();
        __builtin_amdgcn_s_setprio(1);
#pragma unroll
        for (int ks = 0; ks < 2; ks++) {
            int ko = kt * 64 + ks * 32 + quad * 8;
            int kb = ks * 32 + quad * 8;
            bf16x8 a0 = *(const bf16x8*)&HV(mw + r16, ko);
            bf16x8 a1 = *(const bf16x8*)&HV(mw + 16 + r16, ko);
#pragma unroll
            for (int j = 0; j < 2; j++) {
                bf16x8 bj = *(const bf16x8*)&sB[nw + 16 * j + r16][kb];
                acc[0][j] = __builtin_amdgcn_mfma_f32_16x16x32_bf16(a0, bj, acc[0][j], 0, 0, 0);
                acc[1][j] = __builtin_amdgcn_mfma_f32_16x16x32_bf16(a1, bj, acc[1][j], 0, 0, 0);
            }
        }
        __builtin_amdgcn_s_setprio(0);
    }
#pragma unroll
    for (int nt = 0; nt < 2; nt++) {
        int col = nw + nt * 16 + r16;
        float bv = b2[col];
#pragma unroll
        for (int mt = 0; mt < 2; mt++)
#pragma unroll
            for (int reg = 0; reg < 4; reg++) {
                int row = mw + mt * 16 + quad * 4 + reg;
                float v = acc[mt][nt][reg] + bv + b2f(sGY[row][col]);
                outp[growBase + (size_t)row * 128 + col] = f2b(v);
            }
    }
#undef HV
#undef WV
}

// ------------- last linear: out[m,0:3] = x[m,:] @ w_last + b_last -------------
__global__ __launch_bounds__(256) void last_linear_kern(
    const u16* __restrict__ x, const float* __restrict__ w,
    const float* __restrict__ bias, float* __restrict__ outp, int M)
{
    __shared__ float sw[128 * 3];
    int t = threadIdx.x;
    for (int i = t; i < 384; i += 256) sw[i] = w[i];
    __syncthreads();
    int wave = t >> 6;
    int lane = t & 63;
    int row = blockIdx.x * 4 + wave;
    if (row >= M) return;
    const u16* xr = x + (size_t)row * 128;
    float p0 = 0.f, p1 = 0.f, p2 = 0.f;
#pragma unroll
    for (int h = 0; h < 2; h++) {
        int c = lane + h * 64;
        float xv = b2f(xr[c]);
        p0 += xv * sw[c * 3 + 0];
        p1 += xv * sw[c * 3 + 1];
        p2 += xv * sw[c * 3 + 2];
    }
#pragma unroll
    for (int off = 32; off > 0; off >>= 1) {
        p0 += __shfl_xor(p0, off);
        p1 += __shfl_xor(p1, off);
        p2 += __shfl_xor(p2, off);
    }
    if (lane == 0) {
        float* o = outp + (size_t)row * 3;
        o[0] = p0 + bias[0];
        o[1] = p1 + bias[1];
        o[2] = p2 + bias[2];
    }
}

extern "C" void kernel_launch(void* const* d_in, const int* in_sizes, int n_in,
                              void* d_out, int out_size, void* d_ws, size_t ws_size,
                              hipStream_t stream)
{
    const float* x_in    = (const float*)d_in[0];
    const float* mass    = (const float*)d_in[1];
    const float* evals   = (const float*)d_in[2];
    const float* evecs   = (const float*)d_in[3];
    const int*   rows    = (const int*)  d_in[4];
    const int*   cols    = (const int*)  d_in[5];
    const float* gvx     = (const float*)d_in[6];
    const float* gvy     = (const float*)d_in[7];
    const float* w_first = (const float*)d_in[8];
    const float* b_first = (const float*)d_in[9];
    const float* dtimes  = (const float*)d_in[10];
    const float* A_re    = (const float*)d_in[11];
    const float* A_im    = (const float*)d_in[12];
    const float* w0      = (const float*)d_in[13];
    const float* b0      = (const float*)d_in[14];
    const float* w1      = (const float*)d_in[15];
    const float* b1      = (const float*)d_in[16];
    const float* w2      = (const float*)d_in[17];
    const float* b2      = (const float*)d_in[18];
    const float* w_last  = (const float*)d_in[19];
    const float* b_last  = (const float*)d_in[20];
    float* outp = (float*)d_out;

    const size_t SZ = (size_t)B_ * N_ * 128;   // 20,480,000 elements
    const size_t NZ = (size_t)N_ * 128;        //  5,120,000 elements

    // workspace layout (~174 MB)
    u16* P0 = (u16*)d_ws;                      // 41 MB  (x ping-pong)
    u16* P1 = P0 + SZ;                         // 41 MB  (xd ping-pong)
    u16* GF = P1 + SZ;                         // 41 MB  (gX/gY slots 0-1)
    float* SC = (float*)(GF + SZ);             // 41 MB  partials / gX/gY slots 2-3 (disjoint lifetimes)
    u16* ys_t = (u16*)(SC + 8388608);          // 128 KB in SC tail (dead before spmm writes slots 2-3)
    u16* WP0 = (u16*)(SC + 2 * NZ);            // packed transposed bf16 weights
    u16* WP1 = WP0 + 4 * 49152;
    u16* WP2 = WP1 + 4 * 16384;
    u16* WR1 = WP2 + 4 * 16384;                // 4 x [128][256] rotation packs
    u16* WR2 = WR1 + 4 * 32768;
    int* rowptr = (int*)(WR2 + 4 * 32768);     // N+1 (padded to 40004)
    int* nextp  = rowptr + 40004;              // N (histogram counts, then cursors)
    int* scols  = nextp + N_;                  // E sorted cols
    u32* svp    = (u32*)(scols + E_);          // [B][E] packed bf16 (vx,vy)

    u16* x  = P0;
    u16* xd = P1;
    const int M = B_ * N_;                     // 160000

    // --- CSR build (pattern shared across blocks & X/Y) ---
    int* bTot  = (int*)SC;          // NB_SCAN block totals (transient, pre-loop)
    int* bOff  = bTot + 512;
    int* sperm = bTot + 1024;       // E edge permutation (transient, pre-loop)
    hipMemsetAsync(nextp, 0, N_ * sizeof(int), stream);
    hist_kern<<<dim3((E_ + 255) / 256), 256, 0, stream>>>(rows, nextp);
    scan1_kern<<<dim3(NB_SCAN), 256, 0, stream>>>(nextp, rowptr, bTot);
    scan2_kern<<<dim3(1), 256, 0, stream>>>(bTot, bOff, rowptr + N_);
    scan3_kern<<<dim3(NB_SCAN), 256, 0, stream>>>(rowptr, nextp, bOff);
    scatter_idx_kern<<<dim3((E_ + 255) / 256), 256, 0, stream>>>(
        rows, cols, nextp, scols, sperm);
    gather_vals_kern<<<dim3((E_ + 255) / 256), 256, 0, stream>>>(
        sperm, gvx, gvy, svp);

    // --- weight packing (once per launch) ---
    pack_w_kern<<<dim3(192, 1, 4), 256, 0, stream>>>(w0, WP0, 384);
    pack_w_kern<<<dim3(64, 1, 4), 256, 0, stream>>>(w1, WP1, 128);
    pack_w_kern<<<dim3(64, 1, 4), 256, 0, stream>>>(w2, WP2, 128);
    pack_rot_kern<<<dim3(128, 1, 4), 256, 0, stream>>>(A_re, A_im, WR1, WR2);

    first_linear_kern<<<dim3(M * 16 / 256), 256, 0, stream>>>(x_in, w_first, b_first, x, M);

    // gX/gY slots: z<2 in GF, z>=2 in SC (partials/ys_t dead by the time spmm writes)
    u16* GXY0 = GF;
    u16* GXY1 = (u16*)SC;

    for (int i = 0; i < 4; i++) {
        // --- spectral diffusion ---
        spec_stage1_mfma_kern<<<dim3(128, B_), 256, 0, stream>>>(x, mass, evecs, SC);
        spec_stage2_coef_kern<<<dim3(B_ * 128), 512, 0, stream>>>(
            SC, evals, dtimes + (size_t)i * 128, ys_t);
        mgemm_kern<128, true><<<dim3(N_ / 64, 1, B_), 256, 0, stream>>>(
            evecs, ys_t, xd, NZ, (size_t)128 * 128, NZ);
        // --- sparse gradients (all batches, one dispatch) ---
        spmm_csr_kern<<<dim3(N_ / 4, 1, B_), 256, 0, stream>>>(
            rowptr, scols, svp, xd, GXY0, GXY1);
        // --- fused rotate+tanh+MLP+residual (all batches, one dispatch, 512 thr) ---
        mlp_rot_fused_kern<<<dim3(N_ / 64, 1, B_), 512, 0, stream>>>(
            x, xd, GXY0, GXY1,
            WR1 + (size_t)i * 32768, WR2 + (size_t)i * 32768,
            WP0 + (size_t)i * 49152, WP1 + (size_t)i * 16384, WP2 + (size_t)i * 16384,
            b0 + (size_t)i * 128, b1 + (size_t)i * 128, b2 + (size_t)i * 128,
            xd);
        u16* tmp = x; x = xd; xd = tmp;
    }

    last_linear_kern<<<dim3(M / 4), 256, 0, stream>>>(x, w_last, b_last, outp, M);
}